// Round 3
// baseline (11703.767 us; speedup 1.0000x reference)
//
#include <hip/hip_runtime.h>

constexpr int NN = 100000;   // nodes
constexpr int EE = 600000;   // edges
constexpr int DD = 128;
constexpr int HH = 8;

// ---------------- ws layout (float units) — total ~44.9M floats = 180 MB ----------------
constexpr long long OFF_Q    = 0;
constexpr long long OFF_K    = OFF_Q    + (long long)NN*DD;
constexpr long long OFF_V    = OFF_K    + (long long)NN*DD;
constexpr long long OFF_LOG  = OFF_V    + (long long)NN*DD;   // E*H logits, then ex in-place
constexpr long long OFF_SMAX = OFF_LOG  + (long long)EE*HH;
constexpr long long OFF_DEN  = OFF_SMAX + (long long)NN*HH;
constexpr long long OFF_T    = OFF_DEN  + (long long)NN*HH;   // per-node scalar t
constexpr long long OFF_U    = OFF_T    + (long long)NN;      // per-node u = t^2*||x||^2
constexpr long long OFF_ETM  = OFF_U    + (long long)NN;

__device__ inline unsigned encf(float f) {
    unsigned u = __float_as_uint(f);
    return (u & 0x80000000u) ? ~u : (u | 0x80000000u);
}
__device__ inline float decf(unsigned e) {
    return (e & 0x80000000u) ? __uint_as_float(e & 0x7fffffffu) : __uint_as_float(~e);
}
__device__ inline float gelu_exact(float v) {
    return 0.5f * v * (1.0f + erff(v * 0.70710678118654752440f));
}

// ---------------- init: zero accumulators (AGG lives in d_out) ----------------
__global__ __launch_bounds__(256) void k_zero(float* __restrict__ agg, float* __restrict__ den,
                                              unsigned* __restrict__ smax, int* __restrict__ etmax) {
    int stride = gridDim.x * 256;
    for (int i = blockIdx.x * 256 + threadIdx.x; i < NN * DD; i += stride) agg[i] = 0.0f;
    for (int i = blockIdx.x * 256 + threadIdx.x; i < NN * HH; i += stride) { den[i] = 0.0f; smax[i] = 0u; }
    if (blockIdx.x == 0 && threadIdx.x == 0) etmax[0] = 0;
}

// ---------------- max(edge_type) reduction ----------------
__global__ __launch_bounds__(256) void k_etmax(const int* __restrict__ etype, int* __restrict__ etmax) {
    int lmax = 0;
    int stride = gridDim.x * 256;
    for (int i = blockIdx.x * 256 + threadIdx.x; i < EE; i += stride) lmax = max(lmax, etype[i]);
    for (int m = 1; m < 64; m <<= 1) lmax = max(lmax, __shfl_xor(lmax, m));
    if ((threadIdx.x & 63) == 0) atomicMax(etmax, lmax);
}

// ---------------- QKV GEMM: x(N,128) @ {Wq,Wk,Wv} ----------------
__global__ __launch_bounds__(256) void k_qkv(const float* __restrict__ x,
                                             const float* __restrict__ Wq, const float* __restrict__ Wk,
                                             const float* __restrict__ Wv,
                                             float* __restrict__ Q, float* __restrict__ K, float* __restrict__ V) {
    __shared__ float Ast[32][72];   // [k][row]
    __shared__ float Bs[32][72];    // [k][col]
    int tid = threadIdx.x;
    int nt = blockIdx.y;            // 0..5
    int mat = nt >> 1;
    int colbase = (nt & 1) * 64;
    const float* W = (mat == 0) ? Wq : (mat == 1) ? Wk : Wv;
    float* Out = (mat == 0) ? Q : (mat == 1) ? K : V;
    int row0 = blockIdx.x * 64;
    int tx = tid & 15, ty = tid >> 4;
    float acc[4][4] = {};
    for (int k0 = 0; k0 < 128; k0 += 32) {
        {
            int r = tid >> 3;            // 0..31
            int c = (tid & 7) * 4;       // 0..28
            #pragma unroll
            for (int rr = 0; rr < 2; ++rr) {
                int lrow = r + rr * 32;
                int grow = row0 + lrow;
                float4 v = make_float4(0.f, 0.f, 0.f, 0.f);
                if (grow < NN) v = *(const float4*)&x[(long long)grow * 128 + k0 + c];
                Ast[c + 0][lrow] = v.x; Ast[c + 1][lrow] = v.y;
                Ast[c + 2][lrow] = v.z; Ast[c + 3][lrow] = v.w;
            }
            int kk = tid >> 4;           // 0..15
            int cc = (tid & 15) * 4;     // 0..60
            #pragma unroll
            for (int k2 = 0; k2 < 2; ++k2) {
                int kr = kk + k2 * 16;
                *(float4*)&Bs[kr][cc] = *(const float4*)&W[(k0 + kr) * 128 + colbase + cc];
            }
        }
        __syncthreads();
        #pragma unroll
        for (int kk = 0; kk < 32; ++kk) {
            float4 a = *(const float4*)&Ast[kk][ty * 4];
            float4 b = *(const float4*)&Bs[kk][tx * 4];
            float av[4] = {a.x, a.y, a.z, a.w};
            float bv[4] = {b.x, b.y, b.z, b.w};
            #pragma unroll
            for (int i = 0; i < 4; ++i)
                #pragma unroll
                for (int j = 0; j < 4; ++j) acc[i][j] += av[i] * bv[j];
        }
        __syncthreads();
    }
    #pragma unroll
    for (int i = 0; i < 4; ++i) {
        int grow = row0 + ty * 4 + i;
        if (grow < NN)
            *(float4*)&Out[(long long)grow * 128 + colbase + tx * 4] =
                make_float4(acc[i][0], acc[i][1], acc[i][2], acc[i][3]);
    }
}

// ---------------- per-node hyperbolic scalars: m_i = t_i * x_i ----------------
__global__ __launch_bounds__(256) void k_tu(const float* __restrict__ x, const float* __restrict__ c_mag,
                                            float* __restrict__ T, float* __restrict__ U) {
    int wid = threadIdx.x >> 6;
    int lane = threadIdx.x & 63;
    int row = blockIdx.x * 4 + wid;
    if (row >= NN) return;
    float c = -fabsf(c_mag[0]);
    float abs_c = fmaxf(fabsf(c), 1e-15f);
    float sq = sqrtf(abs_c);
    float2 xv = *(const float2*)&x[(long long)row * 128 + lane * 2];
    float s = xv.x * xv.x + xv.y * xv.y;
    for (int m = 1; m < 64; m <<= 1) s += __shfl_xor(s, m);
    float nt = sqrtf(s);                       // true ||x||
    float n = fmaxf(nt, 1e-15f);               // clamped (reference _expmap)
    float arg = sq * n;
    float f = ((c < 0.0f) ? tanhf(arg) : tanf(arg)) / arg;
    float norm = fabsf(f) * nt;                // ||expmap(x)||, unclamped (reference _proj)
    float maxnorm = (1.0f - 1e-5f) / sq;
    float scale = (norm > maxnorm) ? (maxnorm / norm) : 1.0f;
    float t = f * scale;
    if (lane == 0) { T[row] = t; U[row] = t * t * s; }
}

// ---------------- per-edge logits (+fused decay MLP) + segment max ----------------
__global__ __launch_bounds__(256) void k_logits(const float* __restrict__ Q, const float* __restrict__ K,
                                                const float* __restrict__ x, const float* __restrict__ T,
                                                const float* __restrict__ U, const float* __restrict__ temb,
                                                const int* __restrict__ eidx, const int* __restrict__ etype,
                                                const float* __restrict__ etime,
                                                const float* __restrict__ rel_q, const float* __restrict__ rel_k,
                                                const float* __restrict__ Wt, const float* __restrict__ bt,
                                                const float* __restrict__ Wd1, const float* __restrict__ bd1,
                                                const float* __restrict__ Wd2, const float* __restrict__ bd2,
                                                const float* __restrict__ dscale, const int* __restrict__ etmax,
                                                const float* __restrict__ hyp_beta,
                                                const float* __restrict__ logit_alpha,
                                                float* __restrict__ LOG, unsigned* __restrict__ SMAX) {
    __shared__ float Ts[32][32];
    __shared__ float Dec[32][8];
    __shared__ float Wd1s[128];     // [2][64]
    __shared__ float bd1s[64];
    __shared__ float Wd2s[512];     // [64][8]
    int tid = threadIdx.x;
    int eb0 = blockIdx.x * 32;
    {
        int er = tid >> 3;          // 0..31
        int c = (tid & 7) * 4;      // 0..28
        *(float4*)&Ts[er][c] = *(const float4*)&temb[(long long)(eb0 + er) * 32 + c];
        if (tid < 128) Wd1s[tid] = Wd1[tid];
        if (tid >= 128 && tid < 192) bd1s[tid - 128] = bd1[tid - 128];
        Wd2s[tid] = Wd2[tid];
        Wd2s[tid + 256] = Wd2[tid + 256];
    }
    __syncthreads();
    // ---- fused decay MLP: one thread per (edge, head) ----
    {
        int el = tid >> 3, hh = tid & 7;
        int e = eb0 + el;
        float denom_t = fmaxf(1.0f, (float)(etmax[0]) + 1.0f);
        float in0 = etime[e];
        float in1 = (float)etype[e] / denom_t;
        float acc = bd2[hh];
        #pragma unroll
        for (int j = 0; j < 64; ++j) {
            float hid = fmaxf(in0 * Wd1s[j] + in1 * Wd1s[64 + j] + bd1s[j], 0.0f);
            acc += hid * Wd2s[j * 8 + hh];
        }
        Dec[el][hh] = expf(dscale[hh] * tanhf(acc));
    }
    __syncthreads();
    int wid = tid >> 6, lane = tid & 63;
    int ew0 = eb0 + wid * 8;
    int d0 = lane * 2;
    int h = lane >> 3;
    float2 btv = *(const float2*)&bt[d0];
    float tpx[8], tpy[8];
    #pragma unroll
    for (int i = 0; i < 8; ++i) { tpx[i] = btv.x; tpy[i] = btv.y; }
    for (int t = 0; t < 32; ++t) {
        float2 w = *(const float2*)&Wt[t * 128 + d0];
        #pragma unroll
        for (int i = 0; i < 8; ++i) {
            float f = Ts[wid * 8 + i][t];
            tpx[i] += f * w.x; tpy[i] += f * w.y;
        }
    }
    float alpha = 1.0f / (1.0f + expf(-logit_alpha[h]));
    float beta = hyp_beta[h];
    #pragma unroll
    for (int i = 0; i < 8; ++i) {
        int e = ew0 + i;
        int src = eidx[e], dst = eidx[EE + e];
        int et = etype[e];
        float2 q = *(const float2*)&Q[(long long)dst * 128 + d0];
        float2 rq = *(const float2*)&rel_q[et * 128 + d0];
        float2 k = *(const float2*)&K[(long long)src * 128 + d0];
        float2 rk = *(const float2*)&rel_k[et * 128 + d0];
        float qx = q.x + rq.x, qy = q.y + rq.y;
        float kx = k.x + rk.x + tpx[i], ky = k.y + rk.y + tpy[i];
        float ep = qx * kx + qy * ky;
        ep += __shfl_xor(ep, 1); ep += __shfl_xor(ep, 2); ep += __shfl_xor(ep, 4);
        // hyperbolic: ||m_s - m_d||^2 = u_s + u_d - 2 t_s t_d <x_s, x_d>
        float2 xs = *(const float2*)&x[(long long)src * 128 + d0];
        float2 xd = *(const float2*)&x[(long long)dst * 128 + d0];
        float dp = xs.x * xd.x + xs.y * xd.y;
        for (int mm = 1; mm < 64; mm <<= 1) dp += __shfl_xor(dp, mm);
        float man2 = fmaxf(U[src] + U[dst] - 2.0f * T[src] * T[dst] * dp, 0.0f);
        float man = sqrtf(man2);
        float dec = Dec[wid * 8 + i][h];
        float eu = ep * 0.25f * dec;                 // / sqrt(16) then * decay
        float hyp = -beta * man * dec;
        float lg = alpha * eu + (1.0f - alpha) * hyp;
        if ((lane & 7) == 0) {
            LOG[(long long)e * 8 + h] = lg;
            atomicMax(&SMAX[dst * 8 + h], encf(lg));
        }
    }
}

// ---------------- exp + denom ----------------
__global__ __launch_bounds__(256) void k_exps(const int* __restrict__ eidx, float* __restrict__ LOG,
                                              const unsigned* __restrict__ SMAX, float* __restrict__ DEN) {
    int idx = blockIdx.x * 256 + threadIdx.x;
    if (idx >= EE * HH) return;
    int e = idx >> 3, h = idx & 7;
    int dst = eidx[EE + e];
    float mx = decf(SMAX[dst * 8 + h]);
    float ex = expf(LOG[idx] - mx);
    LOG[idx] = ex;
    unsafeAtomicAdd(&DEN[dst * 8 + h], ex);
}

// ---------------- weighted V aggregation (AGG lives in d_out) ----------------
__global__ __launch_bounds__(256) void k_agg(const int* __restrict__ eidx, const int* __restrict__ etype,
                                             const float* __restrict__ V, const float* __restrict__ rel_v,
                                             const float* __restrict__ EX, const float* __restrict__ DEN,
                                             float* __restrict__ AGG) {
    int wid = threadIdx.x >> 6, lane = threadIdx.x & 63;
    int e = blockIdx.x * 4 + wid;
    int src = eidx[e], dst = eidx[EE + e];
    int et = etype[e];
    int d0 = lane, d1 = lane + 64;
    int h0 = lane >> 4, h1 = h0 + 4;
    float a0 = EX[(long long)e * 8 + h0] / DEN[dst * 8 + h0];
    float a1 = EX[(long long)e * 8 + h1] / DEN[dst * 8 + h1];
    float v0 = V[(long long)src * 128 + d0] + rel_v[et * 128 + d0];
    float v1 = V[(long long)src * 128 + d1] + rel_v[et * 128 + d1];
    unsafeAtomicAdd(&AGG[(long long)dst * 128 + d0], v0 * a0);
    unsafeAtomicAdd(&AGG[(long long)dst * 128 + d1], v1 * a1);
}

// ---------------- out = agg@Wo + bo; y1 = LN(x+out). AGG and Y1 alias (same rows, in-place) ----------------
__global__ __launch_bounds__(256) void k_out_ln1(float* AGGY1,          // in: AGG, out: Y1 (same buffer = d_out)
                                                 const float* __restrict__ Wo,
                                                 const float* __restrict__ bo, const float* __restrict__ x,
                                                 const float* __restrict__ g1, const float* __restrict__ be1) {
    __shared__ float Ast[32][40];
    __shared__ float Bs[32][136];
    int tid = threadIdx.x;
    int row0 = blockIdx.x * 32;
    int tx = tid & 31, ty = tid >> 5;
    float acc[4][4] = {};
    for (int k0 = 0; k0 < 128; k0 += 32) {
        {
            int r = tid >> 3, c = (tid & 7) * 4;     // r 0..31
            float4 v = *(const float4*)&AGGY1[(long long)(row0 + r) * 128 + k0 + c];
            Ast[c + 0][r] = v.x; Ast[c + 1][r] = v.y; Ast[c + 2][r] = v.z; Ast[c + 3][r] = v.w;
            int kk = tid >> 5, cc = (tid & 31) * 4;  // kk 0..7
            #pragma unroll
            for (int k2 = 0; k2 < 4; ++k2) {
                int kr = kk + k2 * 8;
                *(float4*)&Bs[kr][cc] = *(const float4*)&Wo[(k0 + kr) * 128 + cc];
            }
        }
        __syncthreads();
        #pragma unroll
        for (int kk = 0; kk < 32; ++kk) {
            float4 a = *(const float4*)&Ast[kk][ty * 4];
            float4 b = *(const float4*)&Bs[kk][tx * 4];
            float av[4] = {a.x, a.y, a.z, a.w};
            float bv[4] = {b.x, b.y, b.z, b.w};
            #pragma unroll
            for (int i = 0; i < 4; ++i)
                #pragma unroll
                for (int j = 0; j < 4; ++j) acc[i][j] += av[i] * bv[j];
        }
        __syncthreads();
    }
    float4 bov = *(const float4*)&bo[tx * 4];
    float4 g = *(const float4*)&g1[tx * 4];
    float4 bb = *(const float4*)&be1[tx * 4];
    #pragma unroll
    for (int i = 0; i < 4; ++i) {
        int row = row0 + ty * 4 + i;
        float4 xv = *(const float4*)&x[(long long)row * 128 + tx * 4];
        float v0 = xv.x + acc[i][0] + bov.x;
        float v1 = xv.y + acc[i][1] + bov.y;
        float v2 = xv.z + acc[i][2] + bov.z;
        float v3 = xv.w + acc[i][3] + bov.w;
        float sum = v0 + v1 + v2 + v3;
        for (int m = 1; m < 32; m <<= 1) sum += __shfl_xor(sum, m);
        float mu = sum * (1.0f / 128.0f);
        float d0 = v0 - mu, d1 = v1 - mu, d2 = v2 - mu, d3 = v3 - mu;
        float ss = d0 * d0 + d1 * d1 + d2 * d2 + d3 * d3;
        for (int m = 1; m < 32; m <<= 1) ss += __shfl_xor(ss, m);
        float var = ss * (1.0f / 128.0f);
        float rs = 1.0f / sqrtf(var + 1e-5f);
        float4 o;
        o.x = d0 * rs * g.x + bb.x;
        o.y = d1 * rs * g.y + bb.y;
        o.z = d2 * rs * g.z + bb.z;
        o.w = d3 * rs * g.w + bb.w;
        *(float4*)&AGGY1[(long long)row * 128 + tx * 4] = o;
    }
}

// ---------------- FFN (128->512->128) + LN2. Y1 and out alias (rows read to LDS first) ----------------
__global__ __launch_bounds__(256) void k_ffn_ln2(float* IO,             // in: Y1, out: final (same buffer = d_out)
                                                 const float* __restrict__ Wf1,
                                                 const float* __restrict__ bf1, const float* __restrict__ Wf2,
                                                 const float* __restrict__ bf2, const float* __restrict__ g2,
                                                 const float* __restrict__ be2) {
    __shared__ float Ys[16][136];
    __shared__ float Hc[16][136];
    __shared__ float Bs[32][136];
    int tid = threadIdx.x;
    int row0 = blockIdx.x * 16;
    int tx = tid & 31;
    int ry = tid >> 5;                 // 0..7 -> rows ry*2, ry*2+1
    {
        int r = tid >> 4, c = (tid & 15) * 4;   // r 0..15, c 0..60
        *(float4*)&Ys[r][c] = *(const float4*)&IO[(long long)(row0 + r) * 128 + c];
        *(float4*)&Ys[r][c + 64] = *(const float4*)&IO[(long long)(row0 + r) * 128 + c + 64];
    }
    __syncthreads();
    float facc[2][4] = {};
    for (int nc = 0; nc < 4; ++nc) {
        float hacc[2][4] = {};
        for (int k0 = 0; k0 < 128; k0 += 32) {
            __syncthreads();   // protect Bs reuse
            {
                int kk = tid >> 5, cc = (tid & 31) * 4;
                #pragma unroll
                for (int k2 = 0; k2 < 4; ++k2) {
                    int kr = kk + k2 * 8;
                    *(float4*)&Bs[kr][cc] = *(const float4*)&Wf1[(k0 + kr) * 512 + nc * 128 + cc];
                }
            }
            __syncthreads();
            #pragma unroll
            for (int kk = 0; kk < 32; ++kk) {
                float a0 = Ys[ry * 2 + 0][k0 + kk];
                float a1 = Ys[ry * 2 + 1][k0 + kk];
                float4 b = *(const float4*)&Bs[kk][tx * 4];
                hacc[0][0] += a0 * b.x; hacc[0][1] += a0 * b.y; hacc[0][2] += a0 * b.z; hacc[0][3] += a0 * b.w;
                hacc[1][0] += a1 * b.x; hacc[1][1] += a1 * b.y; hacc[1][2] += a1 * b.z; hacc[1][3] += a1 * b.w;
            }
        }
        __syncthreads();   // previous-chunk Hc reads done
        {
            float4 bf = *(const float4*)&bf1[nc * 128 + tx * 4];
            #pragma unroll
            for (int r = 0; r < 2; ++r) {
                float4 hv;
                hv.x = gelu_exact(hacc[r][0] + bf.x);
                hv.y = gelu_exact(hacc[r][1] + bf.y);
                hv.z = gelu_exact(hacc[r][2] + bf.z);
                hv.w = gelu_exact(hacc[r][3] + bf.w);
                *(float4*)&Hc[ry * 2 + r][tx * 4] = hv;
            }
        }
        __syncthreads();
        for (int ks = 0; ks < 128; ks += 32) {
            __syncthreads();   // protect Bs reuse
            {
                int kk = tid >> 5, cc = (tid & 31) * 4;
                #pragma unroll
                for (int k2 = 0; k2 < 4; ++k2) {
                    int kr = kk + k2 * 8;
                    *(float4*)&Bs[kr][cc] = *(const float4*)&Wf2[(nc * 128 + ks + kr) * 128 + cc];
                }
            }
            __syncthreads();
            #pragma unroll
            for (int kk = 0; kk < 32; ++kk) {
                float a0 = Hc[ry * 2 + 0][ks + kk];
                float a1 = Hc[ry * 2 + 1][ks + kk];
                float4 b = *(const float4*)&Bs[kk][tx * 4];
                facc[0][0] += a0 * b.x; facc[0][1] += a0 * b.y; facc[0][2] += a0 * b.z; facc[0][3] += a0 * b.w;
                facc[1][0] += a1 * b.x; facc[1][1] += a1 * b.y; facc[1][2] += a1 * b.z; facc[1][3] += a1 * b.w;
            }
        }
    }
    float4 b2 = *(const float4*)&bf2[tx * 4];
    float4 g = *(const float4*)&g2[tx * 4];
    float4 bb = *(const float4*)&be2[tx * 4];
    #pragma unroll
    for (int r = 0; r < 2; ++r) {
        int row = row0 + ry * 2 + r;
        float v0 = Ys[ry * 2 + r][tx * 4 + 0] + facc[r][0] + b2.x;
        float v1 = Ys[ry * 2 + r][tx * 4 + 1] + facc[r][1] + b2.y;
        float v2 = Ys[ry * 2 + r][tx * 4 + 2] + facc[r][2] + b2.z;
        float v3 = Ys[ry * 2 + r][tx * 4 + 3] + facc[r][3] + b2.w;
        float sum = v0 + v1 + v2 + v3;
        for (int m = 1; m < 32; m <<= 1) sum += __shfl_xor(sum, m);
        float mu = sum * (1.0f / 128.0f);
        float d0 = v0 - mu, d1 = v1 - mu, d2 = v2 - mu, d3 = v3 - mu;
        float ss = d0 * d0 + d1 * d1 + d2 * d2 + d3 * d3;
        for (int m = 1; m < 32; m <<= 1) ss += __shfl_xor(ss, m);
        float var = ss * (1.0f / 128.0f);
        float rs = 1.0f / sqrtf(var + 1e-5f);
        float4 o;
        o.x = d0 * rs * g.x + bb.x;
        o.y = d1 * rs * g.y + bb.y;
        o.z = d2 * rs * g.z + bb.z;
        o.w = d3 * rs * g.w + bb.w;
        *(float4*)&IO[(long long)row * 128 + tx * 4] = o;
    }
}

extern "C" void kernel_launch(void* const* d_in, const int* in_sizes, int n_in,
                              void* d_out, int out_size, void* d_ws, size_t ws_size,
                              hipStream_t stream) {
    const float* x       = (const float*)d_in[0];
    const int*   eidx    = (const int*)d_in[1];
    const float* temb    = (const float*)d_in[2];
    const int*   etype   = (const int*)d_in[3];
    const float* etime   = (const float*)d_in[4];
    const float* Wq      = (const float*)d_in[5];
    const float* Wk      = (const float*)d_in[6];
    const float* Wv      = (const float*)d_in[7];
    const float* rel_q   = (const float*)d_in[8];
    const float* rel_k   = (const float*)d_in[9];
    const float* rel_v   = (const float*)d_in[10];
    const float* Wt      = (const float*)d_in[11];
    const float* bt      = (const float*)d_in[12];
    const float* Wd1     = (const float*)d_in[13];
    const float* bd1     = (const float*)d_in[14];
    const float* Wd2     = (const float*)d_in[15];
    const float* bd2     = (const float*)d_in[16];
    const float* dscale  = (const float*)d_in[17];
    const float* c_mag   = (const float*)d_in[18];
    const float* hbeta   = (const float*)d_in[19];
    const float* lalpha  = (const float*)d_in[20];
    const float* Wo      = (const float*)d_in[21];
    const float* bo      = (const float*)d_in[22];
    const float* g1      = (const float*)d_in[23];
    const float* be1     = (const float*)d_in[24];
    const float* g2      = (const float*)d_in[25];
    const float* be2     = (const float*)d_in[26];
    const float* Wf1     = (const float*)d_in[27];
    const float* bf1     = (const float*)d_in[28];
    const float* Wf2     = (const float*)d_in[29];
    const float* bf2     = (const float*)d_in[30];

    float* ws = (float*)d_ws;
    float*    Q    = ws + OFF_Q;
    float*    K    = ws + OFF_K;
    float*    V    = ws + OFF_V;
    float*    LOG  = ws + OFF_LOG;
    unsigned* SMAX = (unsigned*)(ws + OFF_SMAX);
    float*    DEN  = ws + OFF_DEN;
    float*    T    = ws + OFF_T;
    float*    U    = ws + OFF_U;
    int*      ETM  = (int*)(ws + OFF_ETM);
    float*    AGG  = (float*)d_out;   // aggregation accumulator lives in d_out
    float*    IO   = (float*)d_out;   // Y1 / final output in-place

    k_zero<<<2048, 256, 0, stream>>>(AGG, DEN, SMAX, ETM);
    k_etmax<<<512, 256, 0, stream>>>(etype, ETM);
    k_qkv<<<dim3(1563, 6), 256, 0, stream>>>(x, Wq, Wk, Wv, Q, K, V);
    k_tu<<<25000, 256, 0, stream>>>(x, c_mag, T, U);
    k_logits<<<EE / 32, 256, 0, stream>>>(Q, K, x, T, U, temb, eidx, etype, etime,
                                          rel_q, rel_k, Wt, bt, Wd1, bd1, Wd2, bd2,
                                          dscale, ETM, hbeta, lalpha, LOG, SMAX);
    k_exps<<<(EE * HH) / 256, 256, 0, stream>>>(eidx, LOG, SMAX, DEN);
    k_agg<<<EE / 4, 256, 0, stream>>>(eidx, etype, V, rel_v, LOG, DEN, AGG);
    k_out_ln1<<<NN / 32, 256, 0, stream>>>(AGG, Wo, bo, x, g1, be1);
    k_ffn_ln2<<<NN / 16, 256, 0, stream>>>(IO, Wf1, bf1, Wf2, bf2, g2, be2);
}

// Round 4
// 2473.069 us; speedup vs baseline: 4.7325x; 4.7325x over previous
//
#include <hip/hip_runtime.h>

constexpr int NN = 100000;   // nodes
constexpr int EE = 600000;   // edges
constexpr int DD = 128;
constexpr int HH = 8;

// ---------------- ws layout (float units) — total ~44.9M floats = 180 MB ----------------
constexpr long long OFF_Q    = 0;
constexpr long long OFF_K    = OFF_Q    + (long long)NN*DD;
constexpr long long OFF_V    = OFF_K    + (long long)NN*DD;
constexpr long long OFF_LOG  = OFF_V    + (long long)NN*DD;   // E*H logits, then ex in-place
constexpr long long OFF_SMAX = OFF_LOG  + (long long)EE*HH;
constexpr long long OFF_DEN  = OFF_SMAX + (long long)NN*HH;
constexpr long long OFF_T    = OFF_DEN  + (long long)NN*HH;   // per-node scalar t
constexpr long long OFF_U    = OFF_T    + (long long)NN;      // per-node u = t^2*||x||^2
constexpr long long OFF_ETM  = OFF_U    + (long long)NN;

__device__ inline unsigned encf(float f) {
    unsigned u = __float_as_uint(f);
    return (u & 0x80000000u) ? ~u : (u | 0x80000000u);
}
__device__ inline float decf(unsigned e) {
    return (e & 0x80000000u) ? __uint_as_float(e & 0x7fffffffu) : __uint_as_float(~e);
}
__device__ inline float gelu_exact(float v) {
    return 0.5f * v * (1.0f + erff(v * 0.70710678118654752440f));
}

// ---------------- init: zero accumulators (AGG lives in d_out) ----------------
__global__ __launch_bounds__(256) void k_zero(float* __restrict__ agg, float* __restrict__ den,
                                              unsigned* __restrict__ smax, int* __restrict__ etmax) {
    int stride = gridDim.x * 256;
    for (int i = blockIdx.x * 256 + threadIdx.x; i < NN * DD; i += stride) agg[i] = 0.0f;
    for (int i = blockIdx.x * 256 + threadIdx.x; i < NN * HH; i += stride) { den[i] = 0.0f; smax[i] = 0u; }
    if (blockIdx.x == 0 && threadIdx.x == 0) etmax[0] = 0;
}

// ---------------- max(edge_type) reduction ----------------
__global__ __launch_bounds__(256) void k_etmax(const int* __restrict__ etype, int* __restrict__ etmax) {
    int lmax = 0;
    int stride = gridDim.x * 256;
    for (int i = blockIdx.x * 256 + threadIdx.x; i < EE; i += stride) lmax = max(lmax, etype[i]);
    for (int m = 1; m < 64; m <<= 1) lmax = max(lmax, __shfl_xor(lmax, m));
    if ((threadIdx.x & 63) == 0) atomicMax(etmax, lmax);
}

// ---------------- QKV GEMM: x(N,128) @ {Wq,Wk,Wv} ----------------
__global__ __launch_bounds__(256) void k_qkv(const float* __restrict__ x,
                                             const float* __restrict__ Wq, const float* __restrict__ Wk,
                                             const float* __restrict__ Wv,
                                             float* __restrict__ Q, float* __restrict__ K, float* __restrict__ V) {
    __shared__ float Ast[32][72];   // [k][row]
    __shared__ float Bs[32][72];    // [k][col]
    int tid = threadIdx.x;
    int nt = blockIdx.y;            // 0..5
    int mat = nt >> 1;
    int colbase = (nt & 1) * 64;
    const float* W = (mat == 0) ? Wq : (mat == 1) ? Wk : Wv;
    float* Out = (mat == 0) ? Q : (mat == 1) ? K : V;
    int row0 = blockIdx.x * 64;
    int tx = tid & 15, ty = tid >> 4;
    float acc[4][4] = {};
    for (int k0 = 0; k0 < 128; k0 += 32) {
        {
            int r = tid >> 3;            // 0..31
            int c = (tid & 7) * 4;       // 0..28
            #pragma unroll
            for (int rr = 0; rr < 2; ++rr) {
                int lrow = r + rr * 32;
                int grow = row0 + lrow;
                float4 v = make_float4(0.f, 0.f, 0.f, 0.f);
                if (grow < NN) v = *(const float4*)&x[(long long)grow * 128 + k0 + c];
                Ast[c + 0][lrow] = v.x; Ast[c + 1][lrow] = v.y;
                Ast[c + 2][lrow] = v.z; Ast[c + 3][lrow] = v.w;
            }
            int kk = tid >> 4;           // 0..15
            int cc = (tid & 15) * 4;     // 0..60
            #pragma unroll
            for (int k2 = 0; k2 < 2; ++k2) {
                int kr = kk + k2 * 16;
                *(float4*)&Bs[kr][cc] = *(const float4*)&W[(k0 + kr) * 128 + colbase + cc];
            }
        }
        __syncthreads();
        #pragma unroll
        for (int kk = 0; kk < 32; ++kk) {
            float4 a = *(const float4*)&Ast[kk][ty * 4];
            float4 b = *(const float4*)&Bs[kk][tx * 4];
            float av[4] = {a.x, a.y, a.z, a.w};
            float bv[4] = {b.x, b.y, b.z, b.w};
            #pragma unroll
            for (int i = 0; i < 4; ++i)
                #pragma unroll
                for (int j = 0; j < 4; ++j) acc[i][j] += av[i] * bv[j];
        }
        __syncthreads();
    }
    #pragma unroll
    for (int i = 0; i < 4; ++i) {
        int grow = row0 + ty * 4 + i;
        if (grow < NN)
            *(float4*)&Out[(long long)grow * 128 + colbase + tx * 4] =
                make_float4(acc[i][0], acc[i][1], acc[i][2], acc[i][3]);
    }
}

// ---------------- per-node hyperbolic scalars: m_i = t_i * x_i ----------------
__global__ __launch_bounds__(256) void k_tu(const float* __restrict__ x, const float* __restrict__ c_mag,
                                            float* __restrict__ T, float* __restrict__ U) {
    int wid = threadIdx.x >> 6;
    int lane = threadIdx.x & 63;
    int row = blockIdx.x * 4 + wid;
    if (row >= NN) return;
    float c = -fabsf(c_mag[0]);
    float abs_c = fmaxf(fabsf(c), 1e-15f);
    float sq = sqrtf(abs_c);
    float2 xv = *(const float2*)&x[(long long)row * 128 + lane * 2];
    float s = xv.x * xv.x + xv.y * xv.y;
    for (int m = 1; m < 64; m <<= 1) s += __shfl_xor(s, m);
    float nt = sqrtf(s);                       // true ||x||
    float n = fmaxf(nt, 1e-15f);               // clamped (reference _expmap)
    float arg = sq * n;
    float f = ((c < 0.0f) ? tanhf(arg) : tanf(arg)) / arg;
    float norm = fabsf(f) * nt;                // ||expmap(x)||, unclamped (reference _proj)
    float maxnorm = (1.0f - 1e-5f) / sq;
    float scale = (norm > maxnorm) ? (maxnorm / norm) : 1.0f;
    float t = f * scale;
    if (lane == 0) { T[row] = t; U[row] = t * t * s; }
}

// ---------------- per-edge logits (+fused decay MLP) + segment max ----------------
__global__ __launch_bounds__(256) void k_logits(const float* __restrict__ Q, const float* __restrict__ K,
                                                const float* __restrict__ x, const float* __restrict__ T,
                                                const float* __restrict__ U, const float* __restrict__ temb,
                                                const int* __restrict__ eidx, const int* __restrict__ etype,
                                                const float* __restrict__ etime,
                                                const float* __restrict__ rel_q, const float* __restrict__ rel_k,
                                                const float* __restrict__ Wt, const float* __restrict__ bt,
                                                const float* __restrict__ Wd1, const float* __restrict__ bd1,
                                                const float* __restrict__ Wd2, const float* __restrict__ bd2,
                                                const float* __restrict__ dscale, const int* __restrict__ etmax,
                                                const float* __restrict__ hyp_beta,
                                                const float* __restrict__ logit_alpha,
                                                float* __restrict__ LOG, unsigned* __restrict__ SMAX) {
    __shared__ float Ts[32][32];
    __shared__ float Dec[32][8];
    __shared__ float Wd1s[128];     // [2][64]
    __shared__ float bd1s[64];
    __shared__ float Wd2s[512];     // [64][8]
    int tid = threadIdx.x;
    int eb0 = blockIdx.x * 32;
    {
        int er = tid >> 3;          // 0..31
        int c = (tid & 7) * 4;      // 0..28
        *(float4*)&Ts[er][c] = *(const float4*)&temb[(long long)(eb0 + er) * 32 + c];
        if (tid < 128) Wd1s[tid] = Wd1[tid];
        if (tid >= 128 && tid < 192) bd1s[tid - 128] = bd1[tid - 128];
        Wd2s[tid] = Wd2[tid];
        Wd2s[tid + 256] = Wd2[tid + 256];
    }
    __syncthreads();
    // ---- fused decay MLP: one thread per (edge, head) ----
    {
        int el = tid >> 3, hh = tid & 7;
        int e = eb0 + el;
        float denom_t = fmaxf(1.0f, (float)(etmax[0]) + 1.0f);
        float in0 = etime[e];
        float in1 = (float)etype[e] / denom_t;
        float acc = bd2[hh];
        #pragma unroll
        for (int j = 0; j < 64; ++j) {
            float hid = fmaxf(in0 * Wd1s[j] + in1 * Wd1s[64 + j] + bd1s[j], 0.0f);
            acc += hid * Wd2s[j * 8 + hh];
        }
        Dec[el][hh] = expf(dscale[hh] * tanhf(acc));
    }
    __syncthreads();
    int wid = tid >> 6, lane = tid & 63;
    int ew0 = eb0 + wid * 8;
    int d0 = lane * 2;
    int h = lane >> 3;
    float2 btv = *(const float2*)&bt[d0];
    float tpx[8], tpy[8];
    #pragma unroll
    for (int i = 0; i < 8; ++i) { tpx[i] = btv.x; tpy[i] = btv.y; }
    for (int t = 0; t < 32; ++t) {
        float2 w = *(const float2*)&Wt[t * 128 + d0];
        #pragma unroll
        for (int i = 0; i < 8; ++i) {
            float f = Ts[wid * 8 + i][t];
            tpx[i] += f * w.x; tpy[i] += f * w.y;
        }
    }
    float alpha = 1.0f / (1.0f + expf(-logit_alpha[h]));
    float beta = hyp_beta[h];
    #pragma unroll
    for (int i = 0; i < 8; ++i) {
        int e = ew0 + i;
        int src = eidx[e], dst = eidx[EE + e];
        int et = etype[e];
        float2 q = *(const float2*)&Q[(long long)dst * 128 + d0];
        float2 rq = *(const float2*)&rel_q[et * 128 + d0];
        float2 k = *(const float2*)&K[(long long)src * 128 + d0];
        float2 rk = *(const float2*)&rel_k[et * 128 + d0];
        float qx = q.x + rq.x, qy = q.y + rq.y;
        float kx = k.x + rk.x + tpx[i], ky = k.y + rk.y + tpy[i];
        float ep = qx * kx + qy * ky;
        ep += __shfl_xor(ep, 1); ep += __shfl_xor(ep, 2); ep += __shfl_xor(ep, 4);
        // hyperbolic: ||m_s - m_d||^2 = u_s + u_d - 2 t_s t_d <x_s, x_d>
        float2 xs = *(const float2*)&x[(long long)src * 128 + d0];
        float2 xd = *(const float2*)&x[(long long)dst * 128 + d0];
        float dp = xs.x * xd.x + xs.y * xd.y;
        for (int mm = 1; mm < 64; mm <<= 1) dp += __shfl_xor(dp, mm);
        float man2 = fmaxf(U[src] + U[dst] - 2.0f * T[src] * T[dst] * dp, 0.0f);
        float man = sqrtf(man2);
        float dec = Dec[wid * 8 + i][h];
        float eu = ep * 0.25f * dec;                 // / sqrt(16) then * decay
        float hyp = -beta * man * dec;
        float lg = alpha * eu + (1.0f - alpha) * hyp;
        if ((lane & 7) == 0) {
            LOG[(long long)e * 8 + h] = lg;
            atomicMax(&SMAX[dst * 8 + h], encf(lg));
        }
    }
}

// ---------------- exp + denom ----------------
__global__ __launch_bounds__(256) void k_exps(const int* __restrict__ eidx, float* __restrict__ LOG,
                                              const unsigned* __restrict__ SMAX, float* __restrict__ DEN) {
    int idx = blockIdx.x * 256 + threadIdx.x;
    if (idx >= EE * HH) return;
    int e = idx >> 3, h = idx & 7;
    int dst = eidx[EE + e];
    float mx = decf(SMAX[dst * 8 + h]);
    float ex = expf(LOG[idx] - mx);
    LOG[idx] = ex;
    unsafeAtomicAdd(&DEN[dst * 8 + h], ex);
}

// ---------------- weighted V aggregation (AGG lives in d_out) ----------------
__global__ __launch_bounds__(256) void k_agg(const int* __restrict__ eidx, const int* __restrict__ etype,
                                             const float* __restrict__ V, const float* __restrict__ rel_v,
                                             const float* __restrict__ EX, const float* __restrict__ DEN,
                                             float* __restrict__ AGG) {
    int wid = threadIdx.x >> 6, lane = threadIdx.x & 63;
    int e = blockIdx.x * 4 + wid;
    int src = eidx[e], dst = eidx[EE + e];
    int et = etype[e];
    int d0 = lane, d1 = lane + 64;
    int h0 = lane >> 4, h1 = h0 + 4;
    float a0 = EX[(long long)e * 8 + h0] / DEN[dst * 8 + h0];
    float a1 = EX[(long long)e * 8 + h1] / DEN[dst * 8 + h1];
    float v0 = V[(long long)src * 128 + d0] + rel_v[et * 128 + d0];
    float v1 = V[(long long)src * 128 + d1] + rel_v[et * 128 + d1];
    unsafeAtomicAdd(&AGG[(long long)dst * 128 + d0], v0 * a0);
    unsafeAtomicAdd(&AGG[(long long)dst * 128 + d1], v1 * a1);
}

// ---------------- out = agg@Wo + bo; y1 = LN(x+out). AGG and Y1 alias (same rows, in-place) ----------------
__global__ __launch_bounds__(256) void k_out_ln1(float* AGGY1,          // in: AGG, out: Y1 (same buffer = d_out)
                                                 const float* __restrict__ Wo,
                                                 const float* __restrict__ bo, const float* __restrict__ x,
                                                 const float* __restrict__ g1, const float* __restrict__ be1) {
    __shared__ float Ast[32][40];
    __shared__ float Bs[32][136];
    int tid = threadIdx.x;
    int row0 = blockIdx.x * 32;
    int tx = tid & 31, ty = tid >> 5;
    float acc[4][4] = {};
    for (int k0 = 0; k0 < 128; k0 += 32) {
        {
            int r = tid >> 3, c = (tid & 7) * 4;     // r 0..31
            float4 v = *(const float4*)&AGGY1[(long long)(row0 + r) * 128 + k0 + c];
            Ast[c + 0][r] = v.x; Ast[c + 1][r] = v.y; Ast[c + 2][r] = v.z; Ast[c + 3][r] = v.w;
            int kk = tid >> 5, cc = (tid & 31) * 4;  // kk 0..7
            #pragma unroll
            for (int k2 = 0; k2 < 4; ++k2) {
                int kr = kk + k2 * 8;
                *(float4*)&Bs[kr][cc] = *(const float4*)&Wo[(k0 + kr) * 128 + cc];
            }
        }
        __syncthreads();
        #pragma unroll
        for (int kk = 0; kk < 32; ++kk) {
            float4 a = *(const float4*)&Ast[kk][ty * 4];
            float4 b = *(const float4*)&Bs[kk][tx * 4];
            float av[4] = {a.x, a.y, a.z, a.w};
            float bv[4] = {b.x, b.y, b.z, b.w};
            #pragma unroll
            for (int i = 0; i < 4; ++i)
                #pragma unroll
                for (int j = 0; j < 4; ++j) acc[i][j] += av[i] * bv[j];
        }
        __syncthreads();
    }
    float4 bov = *(const float4*)&bo[tx * 4];
    float4 g = *(const float4*)&g1[tx * 4];
    float4 bb = *(const float4*)&be1[tx * 4];
    #pragma unroll
    for (int i = 0; i < 4; ++i) {
        int row = row0 + ty * 4 + i;
        float4 xv = *(const float4*)&x[(long long)row * 128 + tx * 4];
        float v0 = xv.x + acc[i][0] + bov.x;
        float v1 = xv.y + acc[i][1] + bov.y;
        float v2 = xv.z + acc[i][2] + bov.z;
        float v3 = xv.w + acc[i][3] + bov.w;
        float sum = v0 + v1 + v2 + v3;
        for (int m = 1; m < 32; m <<= 1) sum += __shfl_xor(sum, m);
        float mu = sum * (1.0f / 128.0f);
        float d0 = v0 - mu, d1 = v1 - mu, d2 = v2 - mu, d3 = v3 - mu;
        float ss = d0 * d0 + d1 * d1 + d2 * d2 + d3 * d3;
        for (int m = 1; m < 32; m <<= 1) ss += __shfl_xor(ss, m);
        float var = ss * (1.0f / 128.0f);
        float rs = 1.0f / sqrtf(var + 1e-5f);
        float4 o;
        o.x = d0 * rs * g.x + bb.x;
        o.y = d1 * rs * g.y + bb.y;
        o.z = d2 * rs * g.z + bb.z;
        o.w = d3 * rs * g.w + bb.w;
        *(float4*)&AGGY1[(long long)row * 128 + tx * 4] = o;
    }
}

// ---------------- FFN (128->512->128) + LN2, register-lean rewrite ----------------
// Per block: 16 rows. Phase 1: thread owns 8 rows x 4 hidden cols (32 accums),
// Wf1 read direct from global (L2-resident). Phase 2: thread owns 2 rows x 4 out
// cols (8 accums). Y and H live in LDS; 3 barriers total.
__global__ __launch_bounds__(256) void k_ffn_ln2(float* IO,             // in: Y1, out: final (same buffer = d_out)
                                                 const float* __restrict__ Wf1,
                                                 const float* __restrict__ bf1, const float* __restrict__ Wf2,
                                                 const float* __restrict__ bf2, const float* __restrict__ g2,
                                                 const float* __restrict__ be2) {
    __shared__ float Ys[16][128];   // 8 KB
    __shared__ float Hs[16][512];   // 32 KB
    int tid = threadIdx.x;
    int row0 = blockIdx.x * 16;
    // stage Y1 tile (reads are broadcast later, so no padding needed)
    {
        int r = tid >> 4;            // 0..15
        int c = (tid & 15) * 8;      // 0..120
        float4 a = *(const float4*)&IO[(long long)(row0 + r) * 128 + c];
        float4 b = *(const float4*)&IO[(long long)(row0 + r) * 128 + c + 4];
        *(float4*)&Ys[r][c] = a;
        *(float4*)&Ys[r][c + 4] = b;
    }
    __syncthreads();
    // ---- phase 1: H = gelu(Ys @ Wf1 + bf1), thread = (row half, 4 hidden cols) ----
    {
        int cg = (tid & 127) * 4;    // hidden col 0..508
        int rb = (tid >> 7) * 8;     // row base 0 or 8 (wave-uniform)
        float4 bf = *(const float4*)&bf1[cg];
        float a0[8], a1[8], a2[8], a3[8];
        #pragma unroll
        for (int r = 0; r < 8; ++r) { a0[r] = bf.x; a1[r] = bf.y; a2[r] = bf.z; a3[r] = bf.w; }
        #pragma unroll 2
        for (int k = 0; k < 128; ++k) {
            float4 w = *(const float4*)&Wf1[k * 512 + cg];
            #pragma unroll
            for (int r = 0; r < 8; ++r) {
                float y = Ys[rb + r][k];
                a0[r] += y * w.x; a1[r] += y * w.y; a2[r] += y * w.z; a3[r] += y * w.w;
            }
        }
        #pragma unroll
        for (int r = 0; r < 8; ++r) {
            float4 hv;
            hv.x = gelu_exact(a0[r]); hv.y = gelu_exact(a1[r]);
            hv.z = gelu_exact(a2[r]); hv.w = gelu_exact(a3[r]);
            *(float4*)&Hs[rb + r][cg] = hv;
        }
    }
    __syncthreads();
    // ---- phase 2: out = LN(Ys + Hs @ Wf2 + bf2), thread = (row pair, 4 out cols) ----
    {
        int cg = (tid & 31) * 4;     // out col 0..124
        int rp = (tid >> 5) * 2;     // row pair base 0..14
        float4 b2 = *(const float4*)&bf2[cg];
        float f00 = b2.x, f01 = b2.y, f02 = b2.z, f03 = b2.w;
        float f10 = b2.x, f11 = b2.y, f12 = b2.z, f13 = b2.w;
        #pragma unroll 2
        for (int k = 0; k < 512; ++k) {
            float4 w = *(const float4*)&Wf2[k * 128 + cg];
            float h0 = Hs[rp][k], h1 = Hs[rp + 1][k];
            f00 += h0 * w.x; f01 += h0 * w.y; f02 += h0 * w.z; f03 += h0 * w.w;
            f10 += h1 * w.x; f11 += h1 * w.y; f12 += h1 * w.z; f13 += h1 * w.w;
        }
        float4 g = *(const float4*)&g2[cg];
        float4 bb = *(const float4*)&be2[cg];
        #pragma unroll
        for (int r = 0; r < 2; ++r) {
            int row = row0 + rp + r;
            float v0 = Ys[rp + r][cg + 0] + (r == 0 ? f00 : f10);
            float v1 = Ys[rp + r][cg + 1] + (r == 0 ? f01 : f11);
            float v2 = Ys[rp + r][cg + 2] + (r == 0 ? f02 : f12);
            float v3 = Ys[rp + r][cg + 3] + (r == 0 ? f03 : f13);
            float sum = v0 + v1 + v2 + v3;
            for (int m = 1; m < 32; m <<= 1) sum += __shfl_xor(sum, m);
            float mu = sum * (1.0f / 128.0f);
            float d0 = v0 - mu, d1 = v1 - mu, d2 = v2 - mu, d3 = v3 - mu;
            float ss = d0 * d0 + d1 * d1 + d2 * d2 + d3 * d3;
            for (int m = 1; m < 32; m <<= 1) ss += __shfl_xor(ss, m);
            float var = ss * (1.0f / 128.0f);
            float rs = 1.0f / sqrtf(var + 1e-5f);
            float4 o;
            o.x = d0 * rs * g.x + bb.x;
            o.y = d1 * rs * g.y + bb.y;
            o.z = d2 * rs * g.z + bb.z;
            o.w = d3 * rs * g.w + bb.w;
            *(float4*)&IO[(long long)row * 128 + cg] = o;
        }
    }
}

extern "C" void kernel_launch(void* const* d_in, const int* in_sizes, int n_in,
                              void* d_out, int out_size, void* d_ws, size_t ws_size,
                              hipStream_t stream) {
    const float* x       = (const float*)d_in[0];
    const int*   eidx    = (const int*)d_in[1];
    const float* temb    = (const float*)d_in[2];
    const int*   etype   = (const int*)d_in[3];
    const float* etime   = (const float*)d_in[4];
    const float* Wq      = (const float*)d_in[5];
    const float* Wk      = (const float*)d_in[6];
    const float* Wv      = (const float*)d_in[7];
    const float* rel_q   = (const float*)d_in[8];
    const float* rel_k   = (const float*)d_in[9];
    const float* rel_v   = (const float*)d_in[10];
    const float* Wt      = (const float*)d_in[11];
    const float* bt      = (const float*)d_in[12];
    const float* Wd1     = (const float*)d_in[13];
    const float* bd1     = (const float*)d_in[14];
    const float* Wd2     = (const float*)d_in[15];
    const float* bd2     = (const float*)d_in[16];
    const float* dscale  = (const float*)d_in[17];
    const float* c_mag   = (const float*)d_in[18];
    const float* hbeta   = (const float*)d_in[19];
    const float* lalpha  = (const float*)d_in[20];
    const float* Wo      = (const float*)d_in[21];
    const float* bo      = (const float*)d_in[22];
    const float* g1      = (const float*)d_in[23];
    const float* be1     = (const float*)d_in[24];
    const float* g2      = (const float*)d_in[25];
    const float* be2     = (const float*)d_in[26];
    const float* Wf1     = (const float*)d_in[27];
    const float* bf1     = (const float*)d_in[28];
    const float* Wf2     = (const float*)d_in[29];
    const float* bf2     = (const float*)d_in[30];

    float* ws = (float*)d_ws;
    float*    Q    = ws + OFF_Q;
    float*    K    = ws + OFF_K;
    float*    V    = ws + OFF_V;
    float*    LOG  = ws + OFF_LOG;
    unsigned* SMAX = (unsigned*)(ws + OFF_SMAX);
    float*    DEN  = ws + OFF_DEN;
    float*    T    = ws + OFF_T;
    float*    U    = ws + OFF_U;
    int*      ETM  = (int*)(ws + OFF_ETM);
    float*    AGG  = (float*)d_out;   // aggregation accumulator lives in d_out
    float*    IO   = (float*)d_out;   // Y1 / final output in-place

    k_zero<<<2048, 256, 0, stream>>>(AGG, DEN, SMAX, ETM);
    k_etmax<<<512, 256, 0, stream>>>(etype, ETM);
    k_qkv<<<dim3(1563, 6), 256, 0, stream>>>(x, Wq, Wk, Wv, Q, K, V);
    k_tu<<<25000, 256, 0, stream>>>(x, c_mag, T, U);
    k_logits<<<EE / 32, 256, 0, stream>>>(Q, K, x, T, U, temb, eidx, etype, etime,
                                          rel_q, rel_k, Wt, bt, Wd1, bd1, Wd2, bd2,
                                          dscale, ETM, hbeta, lalpha, LOG, SMAX);
    k_exps<<<(EE * HH) / 256, 256, 0, stream>>>(eidx, LOG, SMAX, DEN);
    k_agg<<<EE / 4, 256, 0, stream>>>(eidx, etype, V, rel_v, LOG, DEN, AGG);
    k_out_ln1<<<NN / 32, 256, 0, stream>>>(AGG, Wo, bo, x, g1, be1);
    k_ffn_ln2<<<NN / 16, 256, 0, stream>>>(IO, Wf1, bf1, Wf2, bf2, g2, be2);
}

// Round 6
// 1800.726 us; speedup vs baseline: 6.4995x; 1.3734x over previous
//
#include <hip/hip_runtime.h>

constexpr int NN = 100000;   // nodes
constexpr int EE = 600000;   // edges
constexpr int DD = 128;
constexpr int HH = 8;

// ---------------- ws layout (float units) ----------------
constexpr long long OFF_Q    = 0;
constexpr long long OFF_K    = OFF_Q    + (long long)NN*DD;
constexpr long long OFF_V    = OFF_K    + (long long)NN*DD;
constexpr long long OFF_LOG  = OFF_V    + (long long)NN*DD;   // E*H raw logits
constexpr long long OFF_SMAX = OFF_LOG  + (long long)EE*HH;
constexpr long long OFF_DEN  = OFF_SMAX + (long long)NN*HH;
constexpr long long OFF_T    = OFF_DEN  + (long long)NN*HH;   // per-node scalar t
constexpr long long OFF_U    = OFF_T    + (long long)NN;      // per-node u = t^2*||x||^2
constexpr long long OFF_ETM  = OFF_U    + (long long)NN;

__device__ inline unsigned encf(float f) {
    unsigned u = __float_as_uint(f);
    return (u & 0x80000000u) ? ~u : (u | 0x80000000u);
}
__device__ inline float decf(unsigned e) {
    return (e & 0x80000000u) ? __uint_as_float(e & 0x7fffffffu) : __uint_as_float(~e);
}
__device__ inline float gelu_exact(float v) {
    return 0.5f * v * (1.0f + erff(v * 0.70710678118654752440f));
}

// ---------------- init: zero accumulators (AGG lives in d_out) ----------------
__global__ __launch_bounds__(256) void k_zero(float* __restrict__ agg, float* __restrict__ den,
                                              unsigned* __restrict__ smax, int* __restrict__ etmax) {
    int stride = gridDim.x * 256;
    for (int i = blockIdx.x * 256 + threadIdx.x; i < NN * DD; i += stride) agg[i] = 0.0f;
    for (int i = blockIdx.x * 256 + threadIdx.x; i < NN * HH; i += stride) { den[i] = 0.0f; smax[i] = 0u; }
    if (blockIdx.x == 0 && threadIdx.x == 0) etmax[0] = 0;
}

// ---------------- max(edge_type) reduction ----------------
__global__ __launch_bounds__(256) void k_etmax(const int* __restrict__ etype, int* __restrict__ etmax) {
    int lmax = 0;
    int stride = gridDim.x * 256;
    for (int i = blockIdx.x * 256 + threadIdx.x; i < EE; i += stride) lmax = max(lmax, etype[i]);
    for (int m = 1; m < 64; m <<= 1) lmax = max(lmax, __shfl_xor(lmax, m));
    if ((threadIdx.x & 63) == 0) atomicMax(etmax, lmax);
}

// ---------------- QKV GEMM: x(N,128) @ {Wq,Wk,Wv} ----------------
__global__ __launch_bounds__(256) void k_qkv(const float* __restrict__ x,
                                             const float* __restrict__ Wq, const float* __restrict__ Wk,
                                             const float* __restrict__ Wv,
                                             float* __restrict__ Q, float* __restrict__ K, float* __restrict__ V) {
    __shared__ float Ast[32][72];   // [k][row]
    __shared__ float Bs[32][72];    // [k][col]
    int tid = threadIdx.x;
    int nt = blockIdx.y;            // 0..5
    int mat = nt >> 1;
    int colbase = (nt & 1) * 64;
    const float* W = (mat == 0) ? Wq : (mat == 1) ? Wk : Wv;
    float* Out = (mat == 0) ? Q : (mat == 1) ? K : V;
    int row0 = blockIdx.x * 64;
    int tx = tid & 15, ty = tid >> 4;
    float acc[4][4] = {};
    for (int k0 = 0; k0 < 128; k0 += 32) {
        {
            int r = tid >> 3;            // 0..31
            int c = (tid & 7) * 4;       // 0..28
            #pragma unroll
            for (int rr = 0; rr < 2; ++rr) {
                int lrow = r + rr * 32;
                int grow = row0 + lrow;
                float4 v = make_float4(0.f, 0.f, 0.f, 0.f);
                if (grow < NN) v = *(const float4*)&x[(long long)grow * 128 + k0 + c];
                Ast[c + 0][lrow] = v.x; Ast[c + 1][lrow] = v.y;
                Ast[c + 2][lrow] = v.z; Ast[c + 3][lrow] = v.w;
            }
            int kk = tid >> 4;           // 0..15
            int cc = (tid & 15) * 4;     // 0..60
            #pragma unroll
            for (int k2 = 0; k2 < 2; ++k2) {
                int kr = kk + k2 * 16;
                *(float4*)&Bs[kr][cc] = *(const float4*)&W[(k0 + kr) * 128 + colbase + cc];
            }
        }
        __syncthreads();
        #pragma unroll
        for (int kk = 0; kk < 32; ++kk) {
            float4 a = *(const float4*)&Ast[kk][ty * 4];
            float4 b = *(const float4*)&Bs[kk][tx * 4];
            float av[4] = {a.x, a.y, a.z, a.w};
            float bv[4] = {b.x, b.y, b.z, b.w};
            #pragma unroll
            for (int i = 0; i < 4; ++i)
                #pragma unroll
                for (int j = 0; j < 4; ++j) acc[i][j] += av[i] * bv[j];
        }
        __syncthreads();
    }
    #pragma unroll
    for (int i = 0; i < 4; ++i) {
        int grow = row0 + ty * 4 + i;
        if (grow < NN)
            *(float4*)&Out[(long long)grow * 128 + colbase + tx * 4] =
                make_float4(acc[i][0], acc[i][1], acc[i][2], acc[i][3]);
    }
}

// ---------------- per-node hyperbolic scalars: m_i = t_i * x_i ----------------
__global__ __launch_bounds__(256) void k_tu(const float* __restrict__ x, const float* __restrict__ c_mag,
                                            float* __restrict__ T, float* __restrict__ U) {
    int wid = threadIdx.x >> 6;
    int lane = threadIdx.x & 63;
    int row = blockIdx.x * 4 + wid;
    if (row >= NN) return;
    float c = -fabsf(c_mag[0]);
    float abs_c = fmaxf(fabsf(c), 1e-15f);
    float sq = sqrtf(abs_c);
    float2 xv = *(const float2*)&x[(long long)row * 128 + lane * 2];
    float s = xv.x * xv.x + xv.y * xv.y;
    for (int m = 1; m < 64; m <<= 1) s += __shfl_xor(s, m);
    float nt = sqrtf(s);                       // true ||x||
    float n = fmaxf(nt, 1e-15f);               // clamped (reference _expmap)
    float arg = sq * n;
    float f = ((c < 0.0f) ? tanhf(arg) : tanf(arg)) / arg;
    float norm = fabsf(f) * nt;                // ||expmap(x)||, unclamped (reference _proj)
    float maxnorm = (1.0f - 1e-5f) / sq;
    float scale = (norm > maxnorm) ? (maxnorm / norm) : 1.0f;
    float t = f * scale;
    if (lane == 0) { T[row] = t; U[row] = t * t * s; }
}

// ---------------- per-edge logits (+fused decay MLP + LDS time-proj) + segment max ----------------
// Block = 32 edges. Main loop: half-wave (32 lanes x float4) owns one edge ->
// 2 edges in flight per wave, 4 unrolled iterations.
__global__ __launch_bounds__(256) void k_logits(const float* __restrict__ Q, const float* __restrict__ K,
                                                const float* __restrict__ x, const float* __restrict__ T,
                                                const float* __restrict__ U, const float* __restrict__ temb,
                                                const int* __restrict__ eidx, const int* __restrict__ etype,
                                                const float* __restrict__ etime,
                                                const float* __restrict__ rel_q, const float* __restrict__ rel_k,
                                                const float* __restrict__ Wt, const float* __restrict__ bt,
                                                const float* __restrict__ Wd1, const float* __restrict__ bd1,
                                                const float* __restrict__ Wd2, const float* __restrict__ bd2,
                                                const float* __restrict__ dscale, const int* __restrict__ etmax,
                                                const float* __restrict__ hyp_beta,
                                                const float* __restrict__ logit_alpha,
                                                float* __restrict__ LOG, unsigned* __restrict__ SMAX) {
    __shared__ float Ts[32][32];    // temb tile
    __shared__ float TP[32][128];   // time projection per edge
    __shared__ float Dec[32][8];
    __shared__ float Wd1s[128];
    __shared__ float bd1s[64];
    __shared__ float Wd2s[512];
    int tid = threadIdx.x;
    int eb0 = blockIdx.x * 32;
    {
        int er = tid >> 3;          // 0..31
        int c = (tid & 7) * 4;      // 0..28
        *(float4*)&Ts[er][c] = *(const float4*)&temb[(long long)(eb0 + er) * 32 + c];
        if (tid < 128) Wd1s[tid] = Wd1[tid];
        if (tid >= 128 && tid < 192) bd1s[tid - 128] = bd1[tid - 128];
        Wd2s[tid] = Wd2[tid];
        Wd2s[tid + 256] = Wd2[tid + 256];
    }
    __syncthreads();
    // ---- decay MLP: one thread per (edge, head) ----
    {
        int el = tid >> 3, hh = tid & 7;
        int e = eb0 + el;
        float denom_t = fmaxf(1.0f, (float)(etmax[0]) + 1.0f);
        float in0 = etime[e];
        float in1 = (float)etype[e] / denom_t;
        float acc = bd2[hh];
        #pragma unroll
        for (int j = 0; j < 64; ++j) {
            float hid = fmaxf(in0 * Wd1s[j] + in1 * Wd1s[64 + j] + bd1s[j], 0.0f);
            acc += hid * Wd2s[j * 8 + hh];
        }
        Dec[el][hh] = expf(dscale[hh] * tanhf(acc));
    }
    // ---- TP = Ts @ Wt + bt : thread covers (col group c4, edges g,g+8,g+16,g+24) ----
    {
        int c4 = (tid & 31) * 4;
        int g = tid >> 5;           // 0..7
        float4 bt4 = *(const float4*)&bt[c4];
        float4 a0 = bt4, a1 = bt4, a2 = bt4, a3 = bt4;
        for (int t = 0; t < 32; ++t) {
            float4 w = *(const float4*)&Wt[t * 128 + c4];
            float f0 = Ts[g][t], f1 = Ts[g + 8][t], f2 = Ts[g + 16][t], f3 = Ts[g + 24][t];
            a0.x += f0 * w.x; a0.y += f0 * w.y; a0.z += f0 * w.z; a0.w += f0 * w.w;
            a1.x += f1 * w.x; a1.y += f1 * w.y; a1.z += f1 * w.z; a1.w += f1 * w.w;
            a2.x += f2 * w.x; a2.y += f2 * w.y; a2.z += f2 * w.z; a2.w += f2 * w.w;
            a3.x += f3 * w.x; a3.y += f3 * w.y; a3.z += f3 * w.z; a3.w += f3 * w.w;
        }
        *(float4*)&TP[g][c4] = a0;
        *(float4*)&TP[g + 8][c4] = a1;
        *(float4*)&TP[g + 16][c4] = a2;
        *(float4*)&TP[g + 24][c4] = a3;
    }
    __syncthreads();
    // ---- main: half-wave per edge ----
    int wid = tid >> 6;
    int lane = tid & 63;
    int half = lane >> 5;
    int l = lane & 31;
    int d4 = l * 4;
    int h = l >> 2;
    float alpha = 1.0f / (1.0f + expf(-logit_alpha[h]));
    float beta = hyp_beta[h];
    #pragma unroll
    for (int i = 0; i < 4; ++i) {
        int elocal = wid * 8 + i * 2 + half;
        int e = eb0 + elocal;
        int src = eidx[e], dst = eidx[EE + e];
        int et = etype[e];
        float4 q  = *(const float4*)&Q[(long long)dst * 128 + d4];
        float4 rq = *(const float4*)&rel_q[et * 128 + d4];
        float4 k  = *(const float4*)&K[(long long)src * 128 + d4];
        float4 rk = *(const float4*)&rel_k[et * 128 + d4];
        float4 tp = *(const float4*)&TP[elocal][d4];
        float4 xs = *(const float4*)&x[(long long)src * 128 + d4];
        float4 xd = *(const float4*)&x[(long long)dst * 128 + d4];
        float ep = (q.x + rq.x) * (k.x + rk.x + tp.x)
                 + (q.y + rq.y) * (k.y + rk.y + tp.y)
                 + (q.z + rq.z) * (k.z + rk.z + tp.z)
                 + (q.w + rq.w) * (k.w + rk.w + tp.w);
        float dp = xs.x * xd.x + xs.y * xd.y + xs.z * xd.z + xs.w * xd.w;
        ep += __shfl_xor(ep, 1); ep += __shfl_xor(ep, 2);
        dp += __shfl_xor(dp, 1); dp += __shfl_xor(dp, 2); dp += __shfl_xor(dp, 4);
        dp += __shfl_xor(dp, 8); dp += __shfl_xor(dp, 16);
        float man2 = fmaxf(U[src] + U[dst] - 2.0f * T[src] * T[dst] * dp, 0.0f);
        float man = sqrtf(man2);
        float dec = Dec[elocal][h];
        float eu = ep * 0.25f * dec;                 // / sqrt(16) then * decay
        float hyp = -beta * man * dec;
        float lg = alpha * eu + (1.0f - alpha) * hyp;
        if ((l & 3) == 0) {
            LOG[(long long)e * 8 + h] = lg;
            atomicMax(&SMAX[dst * 8 + h], encf(lg));
        }
    }
}

// ---------------- weighted V aggregation with fused exp/denom (AGG in d_out, unnormalized) ----------------
__global__ __launch_bounds__(256) void k_agg(const int* __restrict__ eidx, const int* __restrict__ etype,
                                             const float* __restrict__ V, const float* __restrict__ rel_v,
                                             const float* __restrict__ LOG, const unsigned* __restrict__ SMAX,
                                             float* __restrict__ DEN, float* __restrict__ AGG) {
    int wid = threadIdx.x >> 6, lane = threadIdx.x & 63;
    int e = blockIdx.x * 4 + wid;
    int src = eidx[e], dst = eidx[EE + e];
    int et = etype[e];
    int d = lane * 2;
    int h = lane >> 3;
    float lg = LOG[(long long)e * 8 + h];
    float mx = decf(SMAX[dst * 8 + h]);
    float ex = expf(lg - mx);
    if ((lane & 7) == 0) unsafeAtomicAdd(&DEN[dst * 8 + h], ex);
    float2 v  = *(const float2*)&V[(long long)src * 128 + d];
    float2 rv = *(const float2*)&rel_v[et * 128 + d];
    unsafeAtomicAdd(&AGG[(long long)dst * 128 + d + 0], (v.x + rv.x) * ex);
    unsafeAtomicAdd(&AGG[(long long)dst * 128 + d + 1], (v.y + rv.y) * ex);
}

// ---------------- out = (agg/den)@Wo + bo; y1 = LN(x+out). AGG and Y1 alias in d_out ----------------
__global__ __launch_bounds__(256) void k_out_ln1(float* AGGY1,          // in: AGG (unnormalized), out: Y1
                                                 const float* __restrict__ DEN,
                                                 const float* __restrict__ Wo,
                                                 const float* __restrict__ bo, const float* __restrict__ x,
                                                 const float* __restrict__ g1, const float* __restrict__ be1) {
    __shared__ float Ast[32][40];
    __shared__ float Bs[32][136];
    int tid = threadIdx.x;
    int row0 = blockIdx.x * 32;
    int tx = tid & 31, ty = tid >> 5;
    float acc[4][4] = {};
    for (int k0 = 0; k0 < 128; k0 += 32) {
        {
            int r = tid >> 3, c = (tid & 7) * 4;     // r 0..31
            float4 v = *(const float4*)&AGGY1[(long long)(row0 + r) * 128 + k0 + c];
            float den = DEN[(row0 + r) * 8 + ((k0 + c) >> 4)];
            float sc = (den > 0.0f) ? (1.0f / den) : 0.0f;   // zero in-degree -> agg row 0
            Ast[c + 0][r] = v.x * sc; Ast[c + 1][r] = v.y * sc;
            Ast[c + 2][r] = v.z * sc; Ast[c + 3][r] = v.w * sc;
            int kk = tid >> 5, cc = (tid & 31) * 4;  // kk 0..7
            #pragma unroll
            for (int k2 = 0; k2 < 4; ++k2) {
                int kr = kk + k2 * 8;
                *(float4*)&Bs[kr][cc] = *(const float4*)&Wo[(k0 + kr) * 128 + cc];
            }
        }
        __syncthreads();
        #pragma unroll
        for (int kk = 0; kk < 32; ++kk) {
            float4 a = *(const float4*)&Ast[kk][ty * 4];
            float4 b = *(const float4*)&Bs[kk][tx * 4];
            float av[4] = {a.x, a.y, a.z, a.w};
            float bv[4] = {b.x, b.y, b.z, b.w};
            #pragma unroll
            for (int i = 0; i < 4; ++i)
                #pragma unroll
                for (int j = 0; j < 4; ++j) acc[i][j] += av[i] * bv[j];
        }
        __syncthreads();
    }
    float4 bov = *(const float4*)&bo[tx * 4];
    float4 g = *(const float4*)&g1[tx * 4];
    float4 bb = *(const float4*)&be1[tx * 4];
    #pragma unroll
    for (int i = 0; i < 4; ++i) {
        int row = row0 + ty * 4 + i;
        float4 xv = *(const float4*)&x[(long long)row * 128 + tx * 4];
        float v0 = xv.x + acc[i][0] + bov.x;
        float v1 = xv.y + acc[i][1] + bov.y;
        float v2 = xv.z + acc[i][2] + bov.z;
        float v3 = xv.w + acc[i][3] + bov.w;
        float sum = v0 + v1 + v2 + v3;
        for (int m = 1; m < 32; m <<= 1) sum += __shfl_xor(sum, m);
        float mu = sum * (1.0f / 128.0f);
        float d0 = v0 - mu, d1 = v1 - mu, d2 = v2 - mu, d3 = v3 - mu;
        float ss = d0 * d0 + d1 * d1 + d2 * d2 + d3 * d3;
        for (int m = 1; m < 32; m <<= 1) ss += __shfl_xor(ss, m);
        float var = ss * (1.0f / 128.0f);
        float rs = 1.0f / sqrtf(var + 1e-5f);
        float4 o;
        o.x = d0 * rs * g.x + bb.x;
        o.y = d1 * rs * g.y + bb.y;
        o.z = d2 * rs * g.z + bb.z;
        o.w = d3 * rs * g.w + bb.w;
        *(float4*)&AGGY1[(long long)row * 128 + tx * 4] = o;
    }
}

// ---------------- FFN (128->512->128) + LN2, register-lean ----------------
__global__ __launch_bounds__(256) void k_ffn_ln2(float* IO,             // in: Y1, out: final (same buffer = d_out)
                                                 const float* __restrict__ Wf1,
                                                 const float* __restrict__ bf1, const float* __restrict__ Wf2,
                                                 const float* __restrict__ bf2, const float* __restrict__ g2,
                                                 const float* __restrict__ be2) {
    __shared__ float Ys[16][128];   // 8 KB
    __shared__ float Hs[16][512];   // 32 KB
    int tid = threadIdx.x;
    int row0 = blockIdx.x * 16;
    {
        int r = tid >> 4;            // 0..15
        int c = (tid & 15) * 8;      // 0..120
        float4 a = *(const float4*)&IO[(long long)(row0 + r) * 128 + c];
        float4 b = *(const float4*)&IO[(long long)(row0 + r) * 128 + c + 4];
        *(float4*)&Ys[r][c] = a;
        *(float4*)&Ys[r][c + 4] = b;
    }
    __syncthreads();
    // ---- phase 1: H = gelu(Ys @ Wf1 + bf1) ----
    {
        int cg = (tid & 127) * 4;    // hidden col 0..508
        int rb = (tid >> 7) * 8;     // row base 0 or 8
        float4 bf = *(const float4*)&bf1[cg];
        float a0[8], a1[8], a2[8], a3[8];
        #pragma unroll
        for (int r = 0; r < 8; ++r) { a0[r] = bf.x; a1[r] = bf.y; a2[r] = bf.z; a3[r] = bf.w; }
        #pragma unroll 2
        for (int k = 0; k < 128; ++k) {
            float4 w = *(const float4*)&Wf1[k * 512 + cg];
            #pragma unroll
            for (int r = 0; r < 8; ++r) {
                float y = Ys[rb + r][k];
                a0[r] += y * w.x; a1[r] += y * w.y; a2[r] += y * w.z; a3[r] += y * w.w;
            }
        }
        #pragma unroll
        for (int r = 0; r < 8; ++r) {
            float4 hv;
            hv.x = gelu_exact(a0[r]); hv.y = gelu_exact(a1[r]);
            hv.z = gelu_exact(a2[r]); hv.w = gelu_exact(a3[r]);
            *(float4*)&Hs[rb + r][cg] = hv;
        }
    }
    __syncthreads();
    // ---- phase 2: out = LN(Ys + Hs @ Wf2 + bf2) ----
    {
        int cg = (tid & 31) * 4;     // out col 0..124
        int rp = (tid >> 5) * 2;     // row pair base 0..14
        float4 b2 = *(const float4*)&bf2[cg];
        float f00 = b2.x, f01 = b2.y, f02 = b2.z, f03 = b2.w;
        float f10 = b2.x, f11 = b2.y, f12 = b2.z, f13 = b2.w;
        #pragma unroll 2
        for (int k = 0; k < 512; ++k) {
            float4 w = *(const float4*)&Wf2[k * 128 + cg];
            float h0 = Hs[rp][k], h1 = Hs[rp + 1][k];
            f00 += h0 * w.x; f01 += h0 * w.y; f02 += h0 * w.z; f03 += h0 * w.w;
            f10 += h1 * w.x; f11 += h1 * w.y; f12 += h1 * w.z; f13 += h1 * w.w;
        }
        float4 g = *(const float4*)&g2[cg];
        float4 bb = *(const float4*)&be2[cg];
        #pragma unroll
        for (int r = 0; r < 2; ++r) {
            int row = row0 + rp + r;
            float v0 = Ys[rp + r][cg + 0] + (r == 0 ? f00 : f10);
            float v1 = Ys[rp + r][cg + 1] + (r == 0 ? f01 : f11);
            float v2 = Ys[rp + r][cg + 2] + (r == 0 ? f02 : f12);
            float v3 = Ys[rp + r][cg + 3] + (r == 0 ? f03 : f13);
            float sum = v0 + v1 + v2 + v3;
            for (int m = 1; m < 32; m <<= 1) sum += __shfl_xor(sum, m);
            float mu = sum * (1.0f / 128.0f);
            float d0 = v0 - mu, d1 = v1 - mu, d2 = v2 - mu, d3 = v3 - mu;
            float ss = d0 * d0 + d1 * d1 + d2 * d2 + d3 * d3;
            for (int m = 1; m < 32; m <<= 1) ss += __shfl_xor(ss, m);
            float var = ss * (1.0f / 128.0f);
            float rs = 1.0f / sqrtf(var + 1e-5f);
            float4 o;
            o.x = d0 * rs * g.x + bb.x;
            o.y = d1 * rs * g.y + bb.y;
            o.z = d2 * rs * g.z + bb.z;
            o.w = d3 * rs * g.w + bb.w;
            *(float4*)&IO[(long long)row * 128 + cg] = o;
        }
    }
}

extern "C" void kernel_launch(void* const* d_in, const int* in_sizes, int n_in,
                              void* d_out, int out_size, void* d_ws, size_t ws_size,
                              hipStream_t stream) {
    const float* x       = (const float*)d_in[0];
    const int*   eidx    = (const int*)d_in[1];
    const float* temb    = (const float*)d_in[2];
    const int*   etype   = (const int*)d_in[3];
    const float* etime   = (const float*)d_in[4];
    const float* Wq      = (const float*)d_in[5];
    const float* Wk      = (const float*)d_in[6];
    const float* Wv      = (const float*)d_in[7];
    const float* rel_q   = (const float*)d_in[8];
    const float* rel_k   = (const float*)d_in[9];
    const float* rel_v   = (const float*)d_in[10];
    const float* Wt      = (const float*)d_in[11];
    const float* bt      = (const float*)d_in[12];
    const float* Wd1     = (const float*)d_in[13];
    const float* bd1     = (const float*)d_in[14];
    const float* Wd2     = (const float*)d_in[15];
    const float* bd2     = (const float*)d_in[16];
    const float* dscale  = (const float*)d_in[17];
    const float* c_mag   = (const float*)d_in[18];
    const float* hbeta   = (const float*)d_in[19];
    const float* lalpha  = (const float*)d_in[20];
    const float* Wo      = (const float*)d_in[21];
    const float* bo      = (const float*)d_in[22];
    const float* g1      = (const float*)d_in[23];
    const float* be1     = (const float*)d_in[24];
    const float* g2      = (const float*)d_in[25];
    const float* be2     = (const float*)d_in[26];
    const float* Wf1     = (const float*)d_in[27];
    const float* bf1     = (const float*)d_in[28];
    const float* Wf2     = (const float*)d_in[29];
    const float* bf2     = (const float*)d_in[30];

    float* ws = (float*)d_ws;
    float*    Q    = ws + OFF_Q;
    float*    K    = ws + OFF_K;
    float*    V    = ws + OFF_V;
    float*    LOG  = ws + OFF_LOG;
    unsigned* SMAX = (unsigned*)(ws + OFF_SMAX);
    float*    DEN  = ws + OFF_DEN;
    float*    T    = ws + OFF_T;
    float*    U    = ws + OFF_U;
    int*      ETM  = (int*)(ws + OFF_ETM);
    float*    AGG  = (float*)d_out;   // aggregation accumulator lives in d_out
    float*    IO   = (float*)d_out;   // Y1 / final output in-place

    k_zero<<<2048, 256, 0, stream>>>(AGG, DEN, SMAX, ETM);
    k_etmax<<<512, 256, 0, stream>>>(etype, ETM);
    k_qkv<<<dim3(1563, 6), 256, 0, stream>>>(x, Wq, Wk, Wv, Q, K, V);
    k_tu<<<25000, 256, 0, stream>>>(x, c_mag, T, U);
    k_logits<<<EE / 32, 256, 0, stream>>>(Q, K, x, T, U, temb, eidx, etype, etime,
                                          rel_q, rel_k, Wt, bt, Wd1, bd1, Wd2, bd2,
                                          dscale, ETM, hbeta, lalpha, LOG, SMAX);
    k_agg<<<EE / 4, 256, 0, stream>>>(eidx, etype, V, rel_v, LOG, SMAX, DEN, AGG);
    k_out_ln1<<<NN / 32, 256, 0, stream>>>(AGG, DEN, Wo, bo, x, g1, be1);
    k_ffn_ln2<<<NN / 16, 256, 0, stream>>>(IO, Wf1, bf1, Wf2, bf2, g2, be2);
}

// Round 7
// 1448.952 us; speedup vs baseline: 8.0774x; 1.2428x over previous
//
#include <hip/hip_runtime.h>

constexpr int NN = 100000;   // nodes
constexpr int EE = 600000;   // edges
constexpr int DD = 128;
constexpr int HH = 8;

// ---------------- ws layout (float units) ----------------
constexpr long long OFF_Q    = 0;
constexpr long long OFF_K    = OFF_Q    + (long long)NN*DD;
constexpr long long OFF_V    = OFF_K    + (long long)NN*DD;
constexpr long long OFF_LOG  = OFF_V    + (long long)NN*DD;   // E*H raw logits
constexpr long long OFF_SMAX = OFF_LOG  + (long long)EE*HH;
constexpr long long OFF_DEN  = OFF_SMAX + (long long)NN*HH;
constexpr long long OFF_T    = OFF_DEN  + (long long)NN*HH;   // per-node scalar t
constexpr long long OFF_U    = OFF_T    + (long long)NN;      // per-node u = t^2*||x||^2
constexpr long long OFF_ETM  = OFF_U    + (long long)NN;
// split-bf16 weight arrays live in the V region (V is dead after k_agg; k_cvt runs after k_agg)

typedef float f32x4 __attribute__((ext_vector_type(4)));
typedef short s16x8 __attribute__((ext_vector_type(8)));

__device__ inline unsigned encf(float f) {
    unsigned u = __float_as_uint(f);
    return (u & 0x80000000u) ? ~u : (u | 0x80000000u);
}
__device__ inline float decf(unsigned e) {
    return (e & 0x80000000u) ? __uint_as_float(e & 0x7fffffffu) : __uint_as_float(~e);
}
__device__ inline float gelu_exact(float v) {
    return 0.5f * v * (1.0f + erff(v * 0.70710678118654752440f));
}
__device__ inline void bsplit1(float x, unsigned short& hb, unsigned short& lb) {
    unsigned u = __float_as_uint(x);
    hb = (unsigned short)(u >> 16);
    float rem = x - __uint_as_float(((unsigned)hb) << 16);
    lb = (unsigned short)(__float_as_uint(rem) >> 16);
}

// ---------------- init: zero accumulators (AGG lives in d_out) ----------------
__global__ __launch_bounds__(256) void k_zero(float* __restrict__ agg, float* __restrict__ den,
                                              unsigned* __restrict__ smax, int* __restrict__ etmax) {
    int stride = gridDim.x * 256;
    for (int i = blockIdx.x * 256 + threadIdx.x; i < NN * DD; i += stride) agg[i] = 0.0f;
    for (int i = blockIdx.x * 256 + threadIdx.x; i < NN * HH; i += stride) { den[i] = 0.0f; smax[i] = 0u; }
    if (blockIdx.x == 0 && threadIdx.x == 0) etmax[0] = 0;
}

// ---------------- max(edge_type) reduction ----------------
__global__ __launch_bounds__(256) void k_etmax(const int* __restrict__ etype, int* __restrict__ etmax) {
    int lmax = 0;
    int stride = gridDim.x * 256;
    for (int i = blockIdx.x * 256 + threadIdx.x; i < EE; i += stride) lmax = max(lmax, etype[i]);
    for (int m = 1; m < 64; m <<= 1) lmax = max(lmax, __shfl_xor(lmax, m));
    if ((threadIdx.x & 63) == 0) atomicMax(etmax, lmax);
}

// ---------------- QKV GEMM: x(N,128) @ {Wq,Wk,Wv} ----------------
__global__ __launch_bounds__(256) void k_qkv(const float* __restrict__ x,
                                             const float* __restrict__ Wq, const float* __restrict__ Wk,
                                             const float* __restrict__ Wv,
                                             float* __restrict__ Q, float* __restrict__ K, float* __restrict__ V) {
    __shared__ float Ast[32][72];   // [k][row]
    __shared__ float Bs[32][72];    // [k][col]
    int tid = threadIdx.x;
    int nt = blockIdx.y;            // 0..5
    int mat = nt >> 1;
    int colbase = (nt & 1) * 64;
    const float* W = (mat == 0) ? Wq : (mat == 1) ? Wk : Wv;
    float* Out = (mat == 0) ? Q : (mat == 1) ? K : V;
    int row0 = blockIdx.x * 64;
    int tx = tid & 15, ty = tid >> 4;
    float acc[4][4] = {};
    for (int k0 = 0; k0 < 128; k0 += 32) {
        {
            int r = tid >> 3;            // 0..31
            int c = (tid & 7) * 4;       // 0..28
            #pragma unroll
            for (int rr = 0; rr < 2; ++rr) {
                int lrow = r + rr * 32;
                int grow = row0 + lrow;
                float4 v = make_float4(0.f, 0.f, 0.f, 0.f);
                if (grow < NN) v = *(const float4*)&x[(long long)grow * 128 + k0 + c];
                Ast[c + 0][lrow] = v.x; Ast[c + 1][lrow] = v.y;
                Ast[c + 2][lrow] = v.z; Ast[c + 3][lrow] = v.w;
            }
            int kk = tid >> 4;           // 0..15
            int cc = (tid & 15) * 4;     // 0..60
            #pragma unroll
            for (int k2 = 0; k2 < 2; ++k2) {
                int kr = kk + k2 * 16;
                *(float4*)&Bs[kr][cc] = *(const float4*)&W[(k0 + kr) * 128 + colbase + cc];
            }
        }
        __syncthreads();
        #pragma unroll
        for (int kk = 0; kk < 32; ++kk) {
            float4 a = *(const float4*)&Ast[kk][ty * 4];
            float4 b = *(const float4*)&Bs[kk][tx * 4];
            float av[4] = {a.x, a.y, a.z, a.w};
            float bv[4] = {b.x, b.y, b.z, b.w};
            #pragma unroll
            for (int i = 0; i < 4; ++i)
                #pragma unroll
                for (int j = 0; j < 4; ++j) acc[i][j] += av[i] * bv[j];
        }
        __syncthreads();
    }
    #pragma unroll
    for (int i = 0; i < 4; ++i) {
        int grow = row0 + ty * 4 + i;
        if (grow < NN)
            *(float4*)&Out[(long long)grow * 128 + colbase + tx * 4] =
                make_float4(acc[i][0], acc[i][1], acc[i][2], acc[i][3]);
    }
}

// ---------------- per-node hyperbolic scalars: m_i = t_i * x_i ----------------
__global__ __launch_bounds__(256) void k_tu(const float* __restrict__ x, const float* __restrict__ c_mag,
                                            float* __restrict__ T, float* __restrict__ U) {
    int wid = threadIdx.x >> 6;
    int lane = threadIdx.x & 63;
    int row = blockIdx.x * 4 + wid;
    if (row >= NN) return;
    float c = -fabsf(c_mag[0]);
    float abs_c = fmaxf(fabsf(c), 1e-15f);
    float sq = sqrtf(abs_c);
    float2 xv = *(const float2*)&x[(long long)row * 128 + lane * 2];
    float s = xv.x * xv.x + xv.y * xv.y;
    for (int m = 1; m < 64; m <<= 1) s += __shfl_xor(s, m);
    float nt = sqrtf(s);                       // true ||x||
    float n = fmaxf(nt, 1e-15f);               // clamped (reference _expmap)
    float arg = sq * n;
    float f = ((c < 0.0f) ? tanhf(arg) : tanf(arg)) / arg;
    float norm = fabsf(f) * nt;                // ||expmap(x)||, unclamped (reference _proj)
    float maxnorm = (1.0f - 1e-5f) / sq;
    float scale = (norm > maxnorm) ? (maxnorm / norm) : 1.0f;
    float t = f * scale;
    if (lane == 0) { T[row] = t; U[row] = t * t * s; }
}

// ---------------- per-edge logits (+fused decay MLP + LDS time-proj) + segment max ----------------
__global__ __launch_bounds__(256) void k_logits(const float* __restrict__ Q, const float* __restrict__ K,
                                                const float* __restrict__ x, const float* __restrict__ T,
                                                const float* __restrict__ U, const float* __restrict__ temb,
                                                const int* __restrict__ eidx, const int* __restrict__ etype,
                                                const float* __restrict__ etime,
                                                const float* __restrict__ rel_q, const float* __restrict__ rel_k,
                                                const float* __restrict__ Wt, const float* __restrict__ bt,
                                                const float* __restrict__ Wd1, const float* __restrict__ bd1,
                                                const float* __restrict__ Wd2, const float* __restrict__ bd2,
                                                const float* __restrict__ dscale, const int* __restrict__ etmax,
                                                const float* __restrict__ hyp_beta,
                                                const float* __restrict__ logit_alpha,
                                                float* __restrict__ LOG, unsigned* __restrict__ SMAX) {
    __shared__ float Ts[32][32];    // temb tile
    __shared__ float TP[32][128];   // time projection per edge
    __shared__ float Dec[32][8];
    __shared__ float Wd1s[128];
    __shared__ float bd1s[64];
    __shared__ float Wd2s[512];
    int tid = threadIdx.x;
    int eb0 = blockIdx.x * 32;
    {
        int er = tid >> 3;          // 0..31
        int c = (tid & 7) * 4;      // 0..28
        *(float4*)&Ts[er][c] = *(const float4*)&temb[(long long)(eb0 + er) * 32 + c];
        if (tid < 128) Wd1s[tid] = Wd1[tid];
        if (tid >= 128 && tid < 192) bd1s[tid - 128] = bd1[tid - 128];
        Wd2s[tid] = Wd2[tid];
        Wd2s[tid + 256] = Wd2[tid + 256];
    }
    __syncthreads();
    // ---- decay MLP: one thread per (edge, head) ----
    {
        int el = tid >> 3, hh = tid & 7;
        int e = eb0 + el;
        float denom_t = fmaxf(1.0f, (float)(etmax[0]) + 1.0f);
        float in0 = etime[e];
        float in1 = (float)etype[e] / denom_t;
        float acc = bd2[hh];
        #pragma unroll
        for (int j = 0; j < 64; ++j) {
            float hid = fmaxf(in0 * Wd1s[j] + in1 * Wd1s[64 + j] + bd1s[j], 0.0f);
            acc += hid * Wd2s[j * 8 + hh];
        }
        Dec[el][hh] = expf(dscale[hh] * tanhf(acc));
    }
    // ---- TP = Ts @ Wt + bt ----
    {
        int c4 = (tid & 31) * 4;
        int g = tid >> 5;           // 0..7
        float4 bt4 = *(const float4*)&bt[c4];
        float4 a0 = bt4, a1 = bt4, a2 = bt4, a3 = bt4;
        for (int t = 0; t < 32; ++t) {
            float4 w = *(const float4*)&Wt[t * 128 + c4];
            float f0 = Ts[g][t], f1 = Ts[g + 8][t], f2 = Ts[g + 16][t], f3 = Ts[g + 24][t];
            a0.x += f0 * w.x; a0.y += f0 * w.y; a0.z += f0 * w.z; a0.w += f0 * w.w;
            a1.x += f1 * w.x; a1.y += f1 * w.y; a1.z += f1 * w.z; a1.w += f1 * w.w;
            a2.x += f2 * w.x; a2.y += f2 * w.y; a2.z += f2 * w.z; a2.w += f2 * w.w;
            a3.x += f3 * w.x; a3.y += f3 * w.y; a3.z += f3 * w.z; a3.w += f3 * w.w;
        }
        *(float4*)&TP[g][c4] = a0;
        *(float4*)&TP[g + 8][c4] = a1;
        *(float4*)&TP[g + 16][c4] = a2;
        *(float4*)&TP[g + 24][c4] = a3;
    }
    __syncthreads();
    // ---- main: half-wave per edge ----
    int wid = tid >> 6;
    int lane = tid & 63;
    int half = lane >> 5;
    int l = lane & 31;
    int d4 = l * 4;
    int h = l >> 2;
    float alpha = 1.0f / (1.0f + expf(-logit_alpha[h]));
    float beta = hyp_beta[h];
    #pragma unroll
    for (int i = 0; i < 4; ++i) {
        int elocal = wid * 8 + i * 2 + half;
        int e = eb0 + elocal;
        int src = eidx[e], dst = eidx[EE + e];
        int et = etype[e];
        float4 q  = *(const float4*)&Q[(long long)dst * 128 + d4];
        float4 rq = *(const float4*)&rel_q[et * 128 + d4];
        float4 k  = *(const float4*)&K[(long long)src * 128 + d4];
        float4 rk = *(const float4*)&rel_k[et * 128 + d4];
        float4 tp = *(const float4*)&TP[elocal][d4];
        float4 xs = *(const float4*)&x[(long long)src * 128 + d4];
        float4 xd = *(const float4*)&x[(long long)dst * 128 + d4];
        float ep = (q.x + rq.x) * (k.x + rk.x + tp.x)
                 + (q.y + rq.y) * (k.y + rk.y + tp.y)
                 + (q.z + rq.z) * (k.z + rk.z + tp.z)
                 + (q.w + rq.w) * (k.w + rk.w + tp.w);
        float dp = xs.x * xd.x + xs.y * xd.y + xs.z * xd.z + xs.w * xd.w;
        ep += __shfl_xor(ep, 1); ep += __shfl_xor(ep, 2);
        dp += __shfl_xor(dp, 1); dp += __shfl_xor(dp, 2); dp += __shfl_xor(dp, 4);
        dp += __shfl_xor(dp, 8); dp += __shfl_xor(dp, 16);
        float man2 = fmaxf(U[src] + U[dst] - 2.0f * T[src] * T[dst] * dp, 0.0f);
        float man = sqrtf(man2);
        float dec = Dec[elocal][h];
        float eu = ep * 0.25f * dec;                 // / sqrt(16) then * decay
        float hyp = -beta * man * dec;
        float lg = alpha * eu + (1.0f - alpha) * hyp;
        if ((l & 3) == 0) {
            LOG[(long long)e * 8 + h] = lg;
            atomicMax(&SMAX[dst * 8 + h], encf(lg));
        }
    }
}

// ---------------- weighted V aggregation with fused exp/denom (AGG in d_out, unnormalized) ----------------
__global__ __launch_bounds__(256) void k_agg(const int* __restrict__ eidx, const int* __restrict__ etype,
                                             const float* __restrict__ V, const float* __restrict__ rel_v,
                                             const float* __restrict__ LOG, const unsigned* __restrict__ SMAX,
                                             float* __restrict__ DEN, float* __restrict__ AGG) {
    int wid = threadIdx.x >> 6, lane = threadIdx.x & 63;
    int e = blockIdx.x * 4 + wid;
    int src = eidx[e], dst = eidx[EE + e];
    int et = etype[e];
    int d = lane * 2;
    int h = lane >> 3;
    float lg = LOG[(long long)e * 8 + h];
    float mx = decf(SMAX[dst * 8 + h]);
    float ex = expf(lg - mx);
    if ((lane & 7) == 0) unsafeAtomicAdd(&DEN[dst * 8 + h], ex);
    float2 v  = *(const float2*)&V[(long long)src * 128 + d];
    float2 rv = *(const float2*)&rel_v[et * 128 + d];
    unsafeAtomicAdd(&AGG[(long long)dst * 128 + d + 0], (v.x + rv.x) * ex);
    unsafeAtomicAdd(&AGG[(long long)dst * 128 + d + 1], (v.y + rv.y) * ex);
}

// ---------------- split Wf1/Wf2 into bf16 hi/lo in MFMA fragment order ----------------
// frag elem (tile, kstep, lane, j) = W[k = kstep*32 + (lane>>4)*8 + j][n = tile*16 + (lane&15)]
__global__ __launch_bounds__(256) void k_cvt(const float* __restrict__ Wf1, const float* __restrict__ Wf2,
                                             unsigned short* __restrict__ W1h, unsigned short* __restrict__ W1l,
                                             unsigned short* __restrict__ W2h, unsigned short* __restrict__ W2l) {
    int idx = blockIdx.x * 256 + threadIdx.x;   // 0..65535
    {   // Wf1: 128x512, tiles=32 (N), ksteps=4
        int tile = idx >> 11, rem = idx & 2047;
        int ks = rem >> 9, rem2 = rem & 511;
        int l = rem2 >> 3, j = rem2 & 7;
        int k = ks * 32 + ((l >> 4) << 3) + j;
        int n = (tile << 4) + (l & 15);
        unsigned short hb, lb;
        bsplit1(Wf1[k * 512 + n], hb, lb);
        W1h[idx] = hb; W1l[idx] = lb;
    }
    {   // Wf2: 512x128, tiles=8 (N), ksteps=16
        int tile = idx >> 13;
        int ks = (idx >> 9) & 15;
        int l = (idx >> 3) & 63, j = idx & 7;
        int k = ks * 32 + ((l >> 4) << 3) + j;
        int n = (tile << 4) + (l & 15);
        unsigned short hb, lb;
        bsplit1(Wf2[k * 128 + n], hb, lb);
        W2h[idx] = hb; W2l[idx] = lb;
    }
}

// ---------------- out = (agg/den)@Wo + bo; y1 = LN(x+out). AGG and Y1 alias in d_out ----------------
__global__ __launch_bounds__(256) void k_out_ln1(float* AGGY1,          // in: AGG (unnormalized), out: Y1
                                                 const float* __restrict__ DEN,
                                                 const float* __restrict__ Wo,
                                                 const float* __restrict__ bo, const float* __restrict__ x,
                                                 const float* __restrict__ g1, const float* __restrict__ be1) {
    __shared__ float Ast[32][40];
    __shared__ float Bs[32][136];
    int tid = threadIdx.x;
    int row0 = blockIdx.x * 32;
    int tx = tid & 31, ty = tid >> 5;
    float acc[4][4] = {};
    for (int k0 = 0; k0 < 128; k0 += 32) {
        {
            int r = tid >> 3, c = (tid & 7) * 4;     // r 0..31
            float4 v = *(const float4*)&AGGY1[(long long)(row0 + r) * 128 + k0 + c];
            float den = DEN[(row0 + r) * 8 + ((k0 + c) >> 4)];
            float sc = (den > 0.0f) ? (1.0f / den) : 0.0f;   // zero in-degree -> agg row 0
            Ast[c + 0][r] = v.x * sc; Ast[c + 1][r] = v.y * sc;
            Ast[c + 2][r] = v.z * sc; Ast[c + 3][r] = v.w * sc;
            int kk = tid >> 5, cc = (tid & 31) * 4;  // kk 0..7
            #pragma unroll
            for (int k2 = 0; k2 < 4; ++k2) {
                int kr = kk + k2 * 8;
                *(float4*)&Bs[kr][cc] = *(const float4*)&Wo[(k0 + kr) * 128 + cc];
            }
        }
        __syncthreads();
        #pragma unroll
        for (int kk = 0; kk < 32; ++kk) {
            float4 a = *(const float4*)&Ast[kk][ty * 4];
            float4 b = *(const float4*)&Bs[kk][tx * 4];
            float av[4] = {a.x, a.y, a.z, a.w};
            float bv[4] = {b.x, b.y, b.z, b.w};
            #pragma unroll
            for (int i = 0; i < 4; ++i)
                #pragma unroll
                for (int j = 0; j < 4; ++j) acc[i][j] += av[i] * bv[j];
        }
        __syncthreads();
    }
    float4 bov = *(const float4*)&bo[tx * 4];
    float4 g = *(const float4*)&g1[tx * 4];
    float4 bb = *(const float4*)&be1[tx * 4];
    #pragma unroll
    for (int i = 0; i < 4; ++i) {
        int row = row0 + ty * 4 + i;
        float4 xv = *(const float4*)&x[(long long)row * 128 + tx * 4];
        float v0 = xv.x + acc[i][0] + bov.x;
        float v1 = xv.y + acc[i][1] + bov.y;
        float v2 = xv.z + acc[i][2] + bov.z;
        float v3 = xv.w + acc[i][3] + bov.w;
        float sum = v0 + v1 + v2 + v3;
        for (int m = 1; m < 32; m <<= 1) sum += __shfl_xor(sum, m);
        float mu = sum * (1.0f / 128.0f);
        float d0 = v0 - mu, d1 = v1 - mu, d2 = v2 - mu, d3 = v3 - mu;
        float ss = d0 * d0 + d1 * d1 + d2 * d2 + d3 * d3;
        for (int m = 1; m < 32; m <<= 1) ss += __shfl_xor(ss, m);
        float var = ss * (1.0f / 128.0f);
        float rs = 1.0f / sqrtf(var + 1e-5f);
        float4 o;
        o.x = d0 * rs * g.x + bb.x;
        o.y = d1 * rs * g.y + bb.y;
        o.z = d2 * rs * g.z + bb.z;
        o.w = d3 * rs * g.w + bb.w;
        *(float4*)&AGGY1[(long long)row * 128 + tx * 4] = o;
    }
}

// ---------------- FFN (128->512->128) + LN2 via split-bf16 MFMA ----------------
// 16 rows/block, 4 waves. GEMM1: wave w owns N-tiles w*8..w*8+7 (cols w*128..+127).
// GEMM2: wave w owns N-tiles w*2, w*2+1; K processed in two halves (LDS budget).
// x*w = hi*hi + hi*lo + lo*hi (3 MFMAs), fp32 accumulate.
__global__ __launch_bounds__(256) void k_ffn_ln2(float* IO,
        const unsigned short* __restrict__ W1h, const unsigned short* __restrict__ W1l,
        const unsigned short* __restrict__ W2h, const unsigned short* __restrict__ W2l,
        const float* __restrict__ bf1, const float* __restrict__ bf2,
        const float* __restrict__ g2, const float* __restrict__ be2) {
    __shared__ __align__(16) float Ys[16][132];      // 8448 B (pad: bank spread)
    __shared__ __align__(16) short Yfrag[2][2048];   // 8192 B (hi,lo)  — Os overlays later
    __shared__ __align__(16) float Hs[16][516];      // 33024 B (pad 516: conflict-free epi writes)
    __shared__ __align__(16) short Hfrag[2][4096];   // 16384 B (one K-half at a time)
    int tid = threadIdx.x;
    int row0 = blockIdx.x * 16;
    int wave = tid >> 6, l = tid & 63;
    // ---- stage Y tile ----
    {
        int r = tid >> 4, c = (tid & 15) * 8;
        float4 a = *(const float4*)&IO[(long long)(row0 + r) * 128 + c];
        float4 b = *(const float4*)&IO[(long long)(row0 + r) * 128 + c + 4];
        *(float4*)&Ys[r][c] = a;
        *(float4*)&Ys[r][c + 4] = b;
    }
    __syncthreads();
    // ---- Y frag pass: split to bf16 hi/lo in fragment order (once per block) ----
    {
        int ks = tid >> 6, ll = tid & 63;
        int rr = ll & 15, kb = ks * 32 + ((ll >> 4) << 3);
        float4 p0 = *(const float4*)&Ys[rr][kb];
        float4 p1 = *(const float4*)&Ys[rr][kb + 4];
        float av[8] = {p0.x, p0.y, p0.z, p0.w, p1.x, p1.y, p1.z, p1.w};
        s16x8 vh, vl;
        #pragma unroll
        for (int j = 0; j < 8; ++j) {
            unsigned short hb, lb;
            bsplit1(av[j], hb, lb);
            vh[j] = (short)hb; vl[j] = (short)lb;
        }
        *(s16x8*)&Yfrag[0][(ks * 64 + ll) * 8] = vh;
        *(s16x8*)&Yfrag[1][(ks * 64 + ll) * 8] = vl;
    }
    __syncthreads();
    // ---- GEMM1: Hs = gelu(Y @ Wf1 + bf1) ----
    {
        f32x4 zero = {0.0f, 0.0f, 0.0f, 0.0f};
        f32x4 acc[8];
        #pragma unroll
        for (int t = 0; t < 8; ++t) acc[t] = zero;
        #pragma unroll
        for (int ks = 0; ks < 4; ++ks) {
            s16x8 ah = *(const s16x8*)&Yfrag[0][(ks * 64 + l) * 8];
            s16x8 al = *(const s16x8*)&Yfrag[1][(ks * 64 + l) * 8];
            #pragma unroll
            for (int t = 0; t < 8; ++t) {
                int idx = (((wave * 8 + t) * 4 + ks) * 64 + l) * 8;
                s16x8 bh = *(const s16x8*)&W1h[idx];
                s16x8 bl = *(const s16x8*)&W1l[idx];
                acc[t] = __builtin_amdgcn_mfma_f32_16x16x32_bf16(ah, bh, acc[t], 0, 0, 0);
                acc[t] = __builtin_amdgcn_mfma_f32_16x16x32_bf16(ah, bl, acc[t], 0, 0, 0);
                acc[t] = __builtin_amdgcn_mfma_f32_16x16x32_bf16(al, bh, acc[t], 0, 0, 0);
            }
        }
        int rb = (l >> 4) * 4, cl = l & 15;
        #pragma unroll
        for (int t = 0; t < 8; ++t) {
            int col = (wave * 8 + t) * 16 + cl;
            float bb = bf1[col];
            #pragma unroll
            for (int r = 0; r < 4; ++r)
                Hs[rb + r][col] = gelu_exact(acc[t][r] + bb);
        }
    }
    __syncthreads();
    // ---- GEMM2: Os = Hs @ Wf2, two K-halves ----
    f32x4 acc2[2];
    acc2[0] = (f32x4){0.0f, 0.0f, 0.0f, 0.0f};
    acc2[1] = (f32x4){0.0f, 0.0f, 0.0f, 0.0f};
    #pragma unroll
    for (int halfk = 0; halfk < 2; ++halfk) {
        {   // H frag pass for ksteps [halfk*8, halfk*8+8)
            int ksh = tid >> 5, lg = tid & 31;
            #pragma unroll
            for (int q = 0; q < 2; ++q) {
                int l2 = lg * 2 + q;
                int rr = l2 & 15, kb = (halfk * 8 + ksh) * 32 + ((l2 >> 4) << 3);
                float4 p0 = *(const float4*)&Hs[rr][kb];
                float4 p1 = *(const float4*)&Hs[rr][kb + 4];
                float av[8] = {p0.x, p0.y, p0.z, p0.w, p1.x, p1.y, p1.z, p1.w};
                s16x8 vh, vl;
                #pragma unroll
                for (int j = 0; j < 8; ++j) {
                    unsigned short hb, lb;
                    bsplit1(av[j], hb, lb);
                    vh[j] = (short)hb; vl[j] = (short)lb;
                }
                *(s16x8*)&Hfrag[0][(ksh * 64 + l2) * 8] = vh;
                *(s16x8*)&Hfrag[1][(ksh * 64 + l2) * 8] = vl;
            }
        }
        __syncthreads();
        #pragma unroll
        for (int ksl = 0; ksl < 8; ++ksl) {
            int ks = halfk * 8 + ksl;
            s16x8 ah = *(const s16x8*)&Hfrag[0][(ksl * 64 + l) * 8];
            s16x8 al = *(const s16x8*)&Hfrag[1][(ksl * 64 + l) * 8];
            #pragma unroll
            for (int t = 0; t < 2; ++t) {
                int idx = (((wave * 2 + t) * 16 + ks) * 64 + l) * 8;
                s16x8 bh = *(const s16x8*)&W2h[idx];
                s16x8 bl = *(const s16x8*)&W2l[idx];
                acc2[t] = __builtin_amdgcn_mfma_f32_16x16x32_bf16(ah, bh, acc2[t], 0, 0, 0);
                acc2[t] = __builtin_amdgcn_mfma_f32_16x16x32_bf16(ah, bl, acc2[t], 0, 0, 0);
                acc2[t] = __builtin_amdgcn_mfma_f32_16x16x32_bf16(al, bh, acc2[t], 0, 0, 0);
            }
        }
        __syncthreads();
    }
    // ---- write GEMM2 result (Os overlays Yfrag: GEMM1 reads ended 3 barriers ago) ----
    float* Os = (float*)&Yfrag[0][0];   // [16][128]
    {
        int rb = (l >> 4) * 4, cl = l & 15;
        #pragma unroll
        for (int t = 0; t < 2; ++t) {
            int col = (wave * 2 + t) * 16 + cl;
            #pragma unroll
            for (int r = 0; r < 4; ++r)
                Os[(rb + r) * 128 + col] = acc2[t][r];
        }
    }
    __syncthreads();
    // ---- LN epilogue: out = LN(Ys + Os + bf2) ----
    {
        int cg = (tid & 31) * 4;
        int rp = (tid >> 5) * 2;
        float4 b2 = *(const float4*)&bf2[cg];
        float4 g = *(const float4*)&g2[cg];
        float4 bb = *(const float4*)&be2[cg];
        #pragma unroll
        for (int r = 0; r < 2; ++r) {
            int rr = rp + r;
            int row = row0 + rr;
            float v0 = Ys[rr][cg + 0] + Os[rr * 128 + cg + 0] + b2.x;
            float v1 = Ys[rr][cg + 1] + Os[rr * 128 + cg + 1] + b2.y;
            float v2 = Ys[rr][cg + 2] + Os[rr * 128 + cg + 2] + b2.z;
            float v3 = Ys[rr][cg + 3] + Os[rr * 128 + cg + 3] + b2.w;
            float sum = v0 + v1 + v2 + v3;
            for (int m = 1; m < 32; m <<= 1) sum += __shfl_xor(sum, m);
            float mu = sum * (1.0f / 128.0f);
            float d0 = v0 - mu, d1 = v1 - mu, d2 = v2 - mu, d3 = v3 - mu;
            float ss = d0 * d0 + d1 * d1 + d2 * d2 + d3 * d3;
            for (int m = 1; m < 32; m <<= 1) ss += __shfl_xor(ss, m);
            float var = ss * (1.0f / 128.0f);
            float rs = 1.0f / sqrtf(var + 1e-5f);
            float4 o;
            o.x = d0 * rs * g.x + bb.x;
            o.y = d1 * rs * g.y + bb.y;
            o.z = d2 * rs * g.z + bb.z;
            o.w = d3 * rs * g.w + bb.w;
            *(float4*)&IO[(long long)row * 128 + cg] = o;
        }
    }
}

extern "C" void kernel_launch(void* const* d_in, const int* in_sizes, int n_in,
                              void* d_out, int out_size, void* d_ws, size_t ws_size,
                              hipStream_t stream) {
    const float* x       = (const float*)d_in[0];
    const int*   eidx    = (const int*)d_in[1];
    const float* temb    = (const float*)d_in[2];
    const int*   etype   = (const int*)d_in[3];
    const float* etime   = (const float*)d_in[4];
    const float* Wq      = (const float*)d_in[5];
    const float* Wk      = (const float*)d_in[6];
    const float* Wv      = (const float*)d_in[7];
    const float* rel_q   = (const float*)d_in[8];
    const float* rel_k   = (const float*)d_in[9];
    const float* rel_v   = (const float*)d_in[10];
    const float* Wt      = (const float*)d_in[11];
    const float* bt      = (const float*)d_in[12];
    const float* Wd1     = (const float*)d_in[13];
    const float* bd1     = (const float*)d_in[14];
    const float* Wd2     = (const float*)d_in[15];
    const float* bd2     = (const float*)d_in[16];
    const float* dscale  = (const float*)d_in[17];
    const float* c_mag   = (const float*)d_in[18];
    const float* hbeta   = (const float*)d_in[19];
    const float* lalpha  = (const float*)d_in[20];
    const float* Wo      = (const float*)d_in[21];
    const float* bo      = (const float*)d_in[22];
    const float* g1      = (const float*)d_in[23];
    const float* be1     = (const float*)d_in[24];
    const float* g2      = (const float*)d_in[25];
    const float* be2     = (const float*)d_in[26];
    const float* Wf1     = (const float*)d_in[27];
    const float* bf1     = (const float*)d_in[28];
    const float* Wf2     = (const float*)d_in[29];
    const float* bf2     = (const float*)d_in[30];

    float* ws = (float*)d_ws;
    float*    Q    = ws + OFF_Q;
    float*    K    = ws + OFF_K;
    float*    V    = ws + OFF_V;
    float*    LOG  = ws + OFF_LOG;
    unsigned* SMAX = (unsigned*)(ws + OFF_SMAX);
    float*    DEN  = ws + OFF_DEN;
    float*    T    = ws + OFF_T;
    float*    U    = ws + OFF_U;
    int*      ETM  = (int*)(ws + OFF_ETM);
    float*    AGG  = (float*)d_out;   // aggregation accumulator lives in d_out
    float*    IO   = (float*)d_out;   // Y1 / final output in-place
    // split-bf16 weight arrays overlay the V region (V dead after k_agg)
    unsigned short* W1h = (unsigned short*)(ws + OFF_V);
    unsigned short* W1l = W1h + 65536;
    unsigned short* W2h = W1l + 65536;
    unsigned short* W2l = W2h + 65536;

    k_zero<<<2048, 256, 0, stream>>>(AGG, DEN, SMAX, ETM);
    k_etmax<<<512, 256, 0, stream>>>(etype, ETM);
    k_qkv<<<dim3(1563, 6), 256, 0, stream>>>(x, Wq, Wk, Wv, Q, K, V);
    k_tu<<<25000, 256, 0, stream>>>(x, c_mag, T, U);
    k_logits<<<EE / 32, 256, 0, stream>>>(Q, K, x, T, U, temb, eidx, etype, etime,
                                          rel_q, rel_k, Wt, bt, Wd1, bd1, Wd2, bd2,
                                          dscale, ETM, hbeta, lalpha, LOG, SMAX);
    k_agg<<<EE / 4, 256, 0, stream>>>(eidx, etype, V, rel_v, LOG, SMAX, DEN, AGG);
    k_cvt<<<256, 256, 0, stream>>>(Wf1, Wf2, W1h, W1l, W2h, W2l);   // after k_agg (V dead)
    k_out_ln1<<<NN / 32, 256, 0, stream>>>(AGG, DEN, Wo, bo, x, g1, be1);
    k_ffn_ln2<<<NN / 16, 256, 0, stream>>>(IO, W1h, W1l, W2h, W2l, bf1, bf2, g2, be2);
}

// Round 8
// 1118.396 us; speedup vs baseline: 10.4648x; 1.2956x over previous
//
#include <hip/hip_runtime.h>

constexpr int NN = 100000;   // nodes
constexpr int EE = 600000;   // edges
constexpr int DD = 128;
constexpr int HH = 8;
constexpr int NB = (NN + 255) / 256;   // scan blocks = 391

// ---------------- ws layout (float units) — ~44.3M floats = 177 MB ----------------
constexpr long long OFF_Q    = 0;
constexpr long long OFF_K    = OFF_Q    + (long long)NN*DD;
constexpr long long OFF_V    = OFF_K    + (long long)NN*DD;
constexpr long long OFF_LOG  = OFF_V    + (long long)NN*DD;   // E*H raw logits
constexpr long long OFF_T    = OFF_LOG  + (long long)EE*HH;
constexpr long long OFF_U    = OFF_T    + (long long)NN;
constexpr long long OFF_ETM  = OFF_U    + (long long)NN;
constexpr long long OFF_CNT  = OFF_ETM  + 4;                  // int[NN]
constexpr long long OFF_CUR  = OFF_CNT  + (long long)NN;      // int[NN]
constexpr long long OFF_RP   = OFF_CUR  + (long long)NN;      // int[NN+1]
constexpr long long OFF_ES   = OFF_RP   + (long long)NN + 4;  // int[EE]
constexpr long long OFF_BS   = OFF_ES   + (long long)EE;      // int[512]
// split-bf16 weight arrays overlay the V region (V dead after k_agg2; k_cvt runs after)

typedef float f32x4 __attribute__((ext_vector_type(4)));
typedef short s16x8 __attribute__((ext_vector_type(8)));

__device__ inline float gelu_exact(float v) {
    return 0.5f * v * (1.0f + erff(v * 0.70710678118654752440f));
}
__device__ inline void bsplit1(float x, unsigned short& hb, unsigned short& lb) {
    unsigned u = __float_as_uint(x);
    hb = (unsigned short)(u >> 16);
    float rem = x - __uint_as_float(((unsigned)hb) << 16);
    lb = (unsigned short)(__float_as_uint(rem) >> 16);
}

// ---------------- init: zero sort counters ----------------
__global__ __launch_bounds__(256) void k_zero(int* __restrict__ cnt, int* __restrict__ cur,
                                              int* __restrict__ etmax) {
    int stride = gridDim.x * 256;
    for (int i = blockIdx.x * 256 + threadIdx.x; i < NN; i += stride) { cnt[i] = 0; cur[i] = 0; }
    if (blockIdx.x == 0 && threadIdx.x == 0) etmax[0] = 0;
}

// ---------------- max(edge_type) reduction ----------------
__global__ __launch_bounds__(256) void k_etmax(const int* __restrict__ etype, int* __restrict__ etmax) {
    int lmax = 0;
    int stride = gridDim.x * 256;
    for (int i = blockIdx.x * 256 + threadIdx.x; i < EE; i += stride) lmax = max(lmax, etype[i]);
    for (int m = 1; m < 64; m <<= 1) lmax = max(lmax, __shfl_xor(lmax, m));
    if ((threadIdx.x & 63) == 0) atomicMax(etmax, lmax);
}

// ---------------- counting sort by dst: hist -> scan -> scatter ----------------
__global__ __launch_bounds__(256) void k_hist(const int* __restrict__ eidx, int* __restrict__ cnt) {
    int i = blockIdx.x * 256 + threadIdx.x;
    if (i < EE) atomicAdd(&cnt[eidx[EE + i]], 1);
}
__global__ __launch_bounds__(256) void k_scan1(const int* __restrict__ cnt, int* __restrict__ bs) {
    __shared__ int wsum[4];
    int i = blockIdx.x * 256 + threadIdx.x;
    int v = (i < NN) ? cnt[i] : 0;
    for (int m = 1; m < 64; m <<= 1) v += __shfl_xor(v, m);
    if ((threadIdx.x & 63) == 0) wsum[threadIdx.x >> 6] = v;
    __syncthreads();
    if (threadIdx.x == 0) bs[blockIdx.x] = wsum[0] + wsum[1] + wsum[2] + wsum[3];
}
__global__ __launch_bounds__(512) void k_scan2(int* __restrict__ bs) {
    __shared__ int s[512];
    int t = threadIdx.x;
    int v = (t < NB) ? bs[t] : 0;
    s[t] = v;
    __syncthreads();
    for (int off = 1; off < 512; off <<= 1) {
        int val = 0;
        if (t >= off) val = s[t - off];
        __syncthreads();
        if (t >= off) s[t] += val;
        __syncthreads();
    }
    if (t < NB) bs[t] = s[t] - v;   // exclusive
}
__global__ __launch_bounds__(256) void k_scan3(const int* __restrict__ cnt, const int* __restrict__ bs,
                                               int* __restrict__ rp) {
    __shared__ int s[256];
    int t = threadIdx.x;
    int i = blockIdx.x * 256 + t;
    int v = (i < NN) ? cnt[i] : 0;
    s[t] = v;
    __syncthreads();
    for (int off = 1; off < 256; off <<= 1) {
        int val = 0;
        if (t >= off) val = s[t - off];
        __syncthreads();
        if (t >= off) s[t] += val;
        __syncthreads();
    }
    int incl = s[t];
    int off0 = bs[blockIdx.x];
    if (i < NN) rp[i] = off0 + incl - v;
    if (i == NN - 1) rp[NN] = off0 + incl;
}
__global__ __launch_bounds__(256) void k_scatter(const int* __restrict__ eidx, const int* __restrict__ rp,
                                                 int* __restrict__ cur, int* __restrict__ es) {
    int i = blockIdx.x * 256 + threadIdx.x;
    if (i < EE) {
        int d = eidx[EE + i];
        int pos = rp[d] + atomicAdd(&cur[d], 1);
        es[pos] = i;
    }
}

// ---------------- QKV GEMM: x(N,128) @ {Wq,Wk,Wv} ----------------
__global__ __launch_bounds__(256) void k_qkv(const float* __restrict__ x,
                                             const float* __restrict__ Wq, const float* __restrict__ Wk,
                                             const float* __restrict__ Wv,
                                             float* __restrict__ Q, float* __restrict__ K, float* __restrict__ V) {
    __shared__ float Ast[32][72];   // [k][row]
    __shared__ float Bs[32][72];    // [k][col]
    int tid = threadIdx.x;
    int nt = blockIdx.y;            // 0..5
    int mat = nt >> 1;
    int colbase = (nt & 1) * 64;
    const float* W = (mat == 0) ? Wq : (mat == 1) ? Wk : Wv;
    float* Out = (mat == 0) ? Q : (mat == 1) ? K : V;
    int row0 = blockIdx.x * 64;
    int tx = tid & 15, ty = tid >> 4;
    float acc[4][4] = {};
    for (int k0 = 0; k0 < 128; k0 += 32) {
        {
            int r = tid >> 3;            // 0..31
            int c = (tid & 7) * 4;       // 0..28
            #pragma unroll
            for (int rr = 0; rr < 2; ++rr) {
                int lrow = r + rr * 32;
                int grow = row0 + lrow;
                float4 v = make_float4(0.f, 0.f, 0.f, 0.f);
                if (grow < NN) v = *(const float4*)&x[(long long)grow * 128 + k0 + c];
                Ast[c + 0][lrow] = v.x; Ast[c + 1][lrow] = v.y;
                Ast[c + 2][lrow] = v.z; Ast[c + 3][lrow] = v.w;
            }
            int kk = tid >> 4;           // 0..15
            int cc = (tid & 15) * 4;     // 0..60
            #pragma unroll
            for (int k2 = 0; k2 < 2; ++k2) {
                int kr = kk + k2 * 16;
                *(float4*)&Bs[kr][cc] = *(const float4*)&W[(k0 + kr) * 128 + colbase + cc];
            }
        }
        __syncthreads();
        #pragma unroll
        for (int kk = 0; kk < 32; ++kk) {
            float4 a = *(const float4*)&Ast[kk][ty * 4];
            float4 b = *(const float4*)&Bs[kk][tx * 4];
            float av[4] = {a.x, a.y, a.z, a.w};
            float bv[4] = {b.x, b.y, b.z, b.w};
            #pragma unroll
            for (int i = 0; i < 4; ++i)
                #pragma unroll
                for (int j = 0; j < 4; ++j) acc[i][j] += av[i] * bv[j];
        }
        __syncthreads();
    }
    #pragma unroll
    for (int i = 0; i < 4; ++i) {
        int grow = row0 + ty * 4 + i;
        if (grow < NN)
            *(float4*)&Out[(long long)grow * 128 + colbase + tx * 4] =
                make_float4(acc[i][0], acc[i][1], acc[i][2], acc[i][3]);
    }
}

// ---------------- per-node hyperbolic scalars: m_i = t_i * x_i ----------------
__global__ __launch_bounds__(256) void k_tu(const float* __restrict__ x, const float* __restrict__ c_mag,
                                            float* __restrict__ T, float* __restrict__ U) {
    int wid = threadIdx.x >> 6;
    int lane = threadIdx.x & 63;
    int row = blockIdx.x * 4 + wid;
    if (row >= NN) return;
    float c = -fabsf(c_mag[0]);
    float abs_c = fmaxf(fabsf(c), 1e-15f);
    float sq = sqrtf(abs_c);
    float2 xv = *(const float2*)&x[(long long)row * 128 + lane * 2];
    float s = xv.x * xv.x + xv.y * xv.y;
    for (int m = 1; m < 64; m <<= 1) s += __shfl_xor(s, m);
    float nt = sqrtf(s);                       // true ||x||
    float n = fmaxf(nt, 1e-15f);               // clamped (reference _expmap)
    float arg = sq * n;
    float f = ((c < 0.0f) ? tanhf(arg) : tanf(arg)) / arg;
    float norm = fabsf(f) * nt;                // ||expmap(x)||, unclamped (reference _proj)
    float maxnorm = (1.0f - 1e-5f) / sq;
    float scale = (norm > maxnorm) ? (maxnorm / norm) : 1.0f;
    float t = f * scale;
    if (lane == 0) { T[row] = t; U[row] = t * t * s; }
}

// ---------------- per-edge logits (+fused decay MLP + LDS time-proj) ----------------
__global__ __launch_bounds__(256) void k_logits(const float* __restrict__ Q, const float* __restrict__ K,
                                                const float* __restrict__ x, const float* __restrict__ T,
                                                const float* __restrict__ U, const float* __restrict__ temb,
                                                const int* __restrict__ eidx, const int* __restrict__ etype,
                                                const float* __restrict__ etime,
                                                const float* __restrict__ rel_q, const float* __restrict__ rel_k,
                                                const float* __restrict__ Wt, const float* __restrict__ bt,
                                                const float* __restrict__ Wd1, const float* __restrict__ bd1,
                                                const float* __restrict__ Wd2, const float* __restrict__ bd2,
                                                const float* __restrict__ dscale, const int* __restrict__ etmax,
                                                const float* __restrict__ hyp_beta,
                                                const float* __restrict__ logit_alpha,
                                                float* __restrict__ LOG) {
    __shared__ float Ts[32][32];    // temb tile
    __shared__ float TP[32][128];   // time projection per edge
    __shared__ float Dec[32][8];
    __shared__ float Wd1s[128];
    __shared__ float bd1s[64];
    __shared__ float Wd2s[512];
    int tid = threadIdx.x;
    int eb0 = blockIdx.x * 32;
    {
        int er = tid >> 3;          // 0..31
        int c = (tid & 7) * 4;      // 0..28
        *(float4*)&Ts[er][c] = *(const float4*)&temb[(long long)(eb0 + er) * 32 + c];
        if (tid < 128) Wd1s[tid] = Wd1[tid];
        if (tid >= 128 && tid < 192) bd1s[tid - 128] = bd1[tid - 128];
        Wd2s[tid] = Wd2[tid];
        Wd2s[tid + 256] = Wd2[tid + 256];
    }
    __syncthreads();
    // ---- decay MLP: one thread per (edge, head) ----
    {
        int el = tid >> 3, hh = tid & 7;
        int e = eb0 + el;
        float denom_t = fmaxf(1.0f, (float)(etmax[0]) + 1.0f);
        float in0 = etime[e];
        float in1 = (float)etype[e] / denom_t;
        float acc = bd2[hh];
        #pragma unroll
        for (int j = 0; j < 64; ++j) {
            float hid = fmaxf(in0 * Wd1s[j] + in1 * Wd1s[64 + j] + bd1s[j], 0.0f);
            acc += hid * Wd2s[j * 8 + hh];
        }
        Dec[el][hh] = expf(dscale[hh] * tanhf(acc));
    }
    // ---- TP = Ts @ Wt + bt ----
    {
        int c4 = (tid & 31) * 4;
        int g = tid >> 5;           // 0..7
        float4 bt4 = *(const float4*)&bt[c4];
        float4 a0 = bt4, a1 = bt4, a2 = bt4, a3 = bt4;
        for (int t = 0; t < 32; ++t) {
            float4 w = *(const float4*)&Wt[t * 128 + c4];
            float f0 = Ts[g][t], f1 = Ts[g + 8][t], f2 = Ts[g + 16][t], f3 = Ts[g + 24][t];
            a0.x += f0 * w.x; a0.y += f0 * w.y; a0.z += f0 * w.z; a0.w += f0 * w.w;
            a1.x += f1 * w.x; a1.y += f1 * w.y; a1.z += f1 * w.z; a1.w += f1 * w.w;
            a2.x += f2 * w.x; a2.y += f2 * w.y; a2.z += f2 * w.z; a2.w += f2 * w.w;
            a3.x += f3 * w.x; a3.y += f3 * w.y; a3.z += f3 * w.z; a3.w += f3 * w.w;
        }
        *(float4*)&TP[g][c4] = a0;
        *(float4*)&TP[g + 8][c4] = a1;
        *(float4*)&TP[g + 16][c4] = a2;
        *(float4*)&TP[g + 24][c4] = a3;
    }
    __syncthreads();
    // ---- main: half-wave per edge ----
    int wid = tid >> 6;
    int lane = tid & 63;
    int half = lane >> 5;
    int l = lane & 31;
    int d4 = l * 4;
    int h = l >> 2;
    float alpha = 1.0f / (1.0f + expf(-logit_alpha[h]));
    float beta = hyp_beta[h];
    #pragma unroll
    for (int i = 0; i < 4; ++i) {
        int elocal = wid * 8 + i * 2 + half;
        int e = eb0 + elocal;
        int src = eidx[e], dst = eidx[EE + e];
        int et = etype[e];
        float4 q  = *(const float4*)&Q[(long long)dst * 128 + d4];
        float4 rq = *(const float4*)&rel_q[et * 128 + d4];
        float4 k  = *(const float4*)&K[(long long)src * 128 + d4];
        float4 rk = *(const float4*)&rel_k[et * 128 + d4];
        float4 tp = *(const float4*)&TP[elocal][d4];
        float4 xs = *(const float4*)&x[(long long)src * 128 + d4];
        float4 xd = *(const float4*)&x[(long long)dst * 128 + d4];
        float ep = (q.x + rq.x) * (k.x + rk.x + tp.x)
                 + (q.y + rq.y) * (k.y + rk.y + tp.y)
                 + (q.z + rq.z) * (k.z + rk.z + tp.z)
                 + (q.w + rq.w) * (k.w + rk.w + tp.w);
        float dp = xs.x * xd.x + xs.y * xd.y + xs.z * xd.z + xs.w * xd.w;
        ep += __shfl_xor(ep, 1); ep += __shfl_xor(ep, 2);
        dp += __shfl_xor(dp, 1); dp += __shfl_xor(dp, 2); dp += __shfl_xor(dp, 4);
        dp += __shfl_xor(dp, 8); dp += __shfl_xor(dp, 16);
        float man2 = fmaxf(U[src] + U[dst] - 2.0f * T[src] * T[dst] * dp, 0.0f);
        float man = sqrtf(man2);
        float dec = Dec[elocal][h];
        float eu = ep * 0.25f * dec;                 // / sqrt(16) then * decay
        float hyp = -beta * man * dec;
        float lg = alpha * eu + (1.0f - alpha) * hyp;
        if ((l & 3) == 0) LOG[(long long)e * 8 + h] = lg;
    }
}

// ---------------- segmented softmax + V aggregation: one wave per dst node ----------------
// Writes NORMALIZED agg rows to d_out with plain stores (no atomics).
__global__ __launch_bounds__(256) void k_agg2(const int* __restrict__ rp, const int* __restrict__ es,
                                              const int* __restrict__ eidx, const int* __restrict__ etype,
                                              const float* __restrict__ V, const float* __restrict__ rel_v,
                                              const float* __restrict__ LOG, float* __restrict__ AGG) {
    int wid = threadIdx.x >> 6, lane = threadIdx.x & 63;
    int node = blockIdx.x * 4 + wid;
    if (node >= NN) return;
    int beg = rp[node], end = rp[node + 1];
    int d = lane * 2;
    int h = lane >> 3;
    float mx = -3.0e38f;
    for (int i = beg; i < end; ++i) {
        int e = es[i];
        mx = fmaxf(mx, LOG[(long long)e * 8 + h]);
    }
    float den = 0.0f;
    float ax = 0.0f, ay = 0.0f;
    for (int i = beg; i < end; ++i) {
        int e = es[i];
        int src = eidx[e];
        int et = etype[e];
        float ex = expf(LOG[(long long)e * 8 + h] - mx);
        den += ex;
        float2 v  = *(const float2*)&V[(long long)src * 128 + d];
        float2 rv = *(const float2*)&rel_v[et * 128 + d];
        ax += (v.x + rv.x) * ex;
        ay += (v.y + rv.y) * ex;
    }
    float sc = (end > beg) ? (1.0f / den) : 0.0f;
    *(float2*)&AGG[(long long)node * 128 + d] = make_float2(ax * sc, ay * sc);
}

// ---------------- split Wf1/Wf2 into bf16 hi/lo in MFMA fragment order ----------------
__global__ __launch_bounds__(256) void k_cvt(const float* __restrict__ Wf1, const float* __restrict__ Wf2,
                                             unsigned short* __restrict__ W1h, unsigned short* __restrict__ W1l,
                                             unsigned short* __restrict__ W2h, unsigned short* __restrict__ W2l) {
    int idx = blockIdx.x * 256 + threadIdx.x;   // 0..65535
    {   // Wf1: 128x512, tiles=32 (N), ksteps=4
        int tile = idx >> 11, rem = idx & 2047;
        int ks = rem >> 9, rem2 = rem & 511;
        int l = rem2 >> 3, j = rem2 & 7;
        int k = ks * 32 + ((l >> 4) << 3) + j;
        int n = (tile << 4) + (l & 15);
        unsigned short hb, lb;
        bsplit1(Wf1[k * 512 + n], hb, lb);
        W1h[idx] = hb; W1l[idx] = lb;
    }
    {   // Wf2: 512x128, tiles=8 (N), ksteps=16
        int tile = idx >> 13;
        int ks = (idx >> 9) & 15;
        int l = (idx >> 3) & 63, j = idx & 7;
        int k = ks * 32 + ((l >> 4) << 3) + j;
        int n = (tile << 4) + (l & 15);
        unsigned short hb, lb;
        bsplit1(Wf2[k * 128 + n], hb, lb);
        W2h[idx] = hb; W2l[idx] = lb;
    }
}

// ---------------- out = agg@Wo + bo; y1 = LN(x+out). AGG and Y1 alias in d_out ----------------
__global__ __launch_bounds__(256) void k_out_ln1(float* AGGY1,          // in: AGG (normalized), out: Y1
                                                 const float* __restrict__ Wo,
                                                 const float* __restrict__ bo, const float* __restrict__ x,
                                                 const float* __restrict__ g1, const float* __restrict__ be1) {
    __shared__ float Ast[32][40];
    __shared__ float Bs[32][136];
    int tid = threadIdx.x;
    int row0 = blockIdx.x * 32;
    int tx = tid & 31, ty = tid >> 5;
    float acc[4][4] = {};
    for (int k0 = 0; k0 < 128; k0 += 32) {
        {
            int r = tid >> 3, c = (tid & 7) * 4;     // r 0..31
            float4 v = *(const float4*)&AGGY1[(long long)(row0 + r) * 128 + k0 + c];
            Ast[c + 0][r] = v.x; Ast[c + 1][r] = v.y; Ast[c + 2][r] = v.z; Ast[c + 3][r] = v.w;
            int kk = tid >> 5, cc = (tid & 31) * 4;  // kk 0..7
            #pragma unroll
            for (int k2 = 0; k2 < 4; ++k2) {
                int kr = kk + k2 * 8;
                *(float4*)&Bs[kr][cc] = *(const float4*)&Wo[(k0 + kr) * 128 + cc];
            }
        }
        __syncthreads();
        #pragma unroll
        for (int kk = 0; kk < 32; ++kk) {
            float4 a = *(const float4*)&Ast[kk][ty * 4];
            float4 b = *(const float4*)&Bs[kk][tx * 4];
            float av[4] = {a.x, a.y, a.z, a.w};
            float bv[4] = {b.x, b.y, b.z, b.w};
            #pragma unroll
            for (int i = 0; i < 4; ++i)
                #pragma unroll
                for (int j = 0; j < 4; ++j) acc[i][j] += av[i] * bv[j];
        }
        __syncthreads();
    }
    float4 bov = *(const float4*)&bo[tx * 4];
    float4 g = *(const float4*)&g1[tx * 4];
    float4 bb = *(const float4*)&be1[tx * 4];
    #pragma unroll
    for (int i = 0; i < 4; ++i) {
        int row = row0 + ty * 4 + i;
        float4 xv = *(const float4*)&x[(long long)row * 128 + tx * 4];
        float v0 = xv.x + acc[i][0] + bov.x;
        float v1 = xv.y + acc[i][1] + bov.y;
        float v2 = xv.z + acc[i][2] + bov.z;
        float v3 = xv.w + acc[i][3] + bov.w;
        float sum = v0 + v1 + v2 + v3;
        for (int m = 1; m < 32; m <<= 1) sum += __shfl_xor(sum, m);
        float mu = sum * (1.0f / 128.0f);
        float d0 = v0 - mu, d1 = v1 - mu, d2 = v2 - mu, d3 = v3 - mu;
        float ss = d0 * d0 + d1 * d1 + d2 * d2 + d3 * d3;
        for (int m = 1; m < 32; m <<= 1) ss += __shfl_xor(ss, m);
        float var = ss * (1.0f / 128.0f);
        float rs = 1.0f / sqrtf(var + 1e-5f);
        float4 o;
        o.x = d0 * rs * g.x + bb.x;
        o.y = d1 * rs * g.y + bb.y;
        o.z = d2 * rs * g.z + bb.z;
        o.w = d3 * rs * g.w + bb.w;
        *(float4*)&AGGY1[(long long)row * 128 + tx * 4] = o;
    }
}

// ---------------- FFN (128->512->128) + LN2 via split-bf16 MFMA ----------------
__global__ __launch_bounds__(256) void k_ffn_ln2(float* IO,
        const unsigned short* __restrict__ W1h, const unsigned short* __restrict__ W1l,
        const unsigned short* __restrict__ W2h, const unsigned short* __restrict__ W2l,
        const float* __restrict__ bf1, const float* __restrict__ bf2,
        const float* __restrict__ g2, const float* __restrict__ be2) {
    __shared__ __align__(16) float Ys[16][132];      // 8448 B
    __shared__ __align__(16) short Yfrag[2][2048];   // 8192 B (hi,lo) — Os overlays later
    __shared__ __align__(16) float Hs[16][516];      // 33024 B
    __shared__ __align__(16) short Hfrag[2][4096];   // 16384 B (one K-half at a time)
    int tid = threadIdx.x;
    int row0 = blockIdx.x * 16;
    int wave = tid >> 6, l = tid & 63;
    // ---- stage Y tile ----
    {
        int r = tid >> 4, c = (tid & 15) * 8;
        float4 a = *(const float4*)&IO[(long long)(row0 + r) * 128 + c];
        float4 b = *(const float4*)&IO[(long long)(row0 + r) * 128 + c + 4];
        *(float4*)&Ys[r][c] = a;
        *(float4*)&Ys[r][c + 4] = b;
    }
    __syncthreads();
    // ---- Y frag pass ----
    {
        int ks = tid >> 6, ll = tid & 63;
        int rr = ll & 15, kb = ks * 32 + ((ll >> 4) << 3);
        float4 p0 = *(const float4*)&Ys[rr][kb];
        float4 p1 = *(const float4*)&Ys[rr][kb + 4];
        float av[8] = {p0.x, p0.y, p0.z, p0.w, p1.x, p1.y, p1.z, p1.w};
        s16x8 vh, vl;
        #pragma unroll
        for (int j = 0; j < 8; ++j) {
            unsigned short hb, lb;
            bsplit1(av[j], hb, lb);
            vh[j] = (short)hb; vl[j] = (short)lb;
        }
        *(s16x8*)&Yfrag[0][(ks * 64 + ll) * 8] = vh;
        *(s16x8*)&Yfrag[1][(ks * 64 + ll) * 8] = vl;
    }
    __syncthreads();
    // ---- GEMM1: Hs = gelu(Y @ Wf1 + bf1) ----
    {
        f32x4 zero = {0.0f, 0.0f, 0.0f, 0.0f};
        f32x4 acc[8];
        #pragma unroll
        for (int t = 0; t < 8; ++t) acc[t] = zero;
        #pragma unroll
        for (int ks = 0; ks < 4; ++ks) {
            s16x8 ah = *(const s16x8*)&Yfrag[0][(ks * 64 + l) * 8];
            s16x8 al = *(const s16x8*)&Yfrag[1][(ks * 64 + l) * 8];
            #pragma unroll
            for (int t = 0; t < 8; ++t) {
                int idx = (((wave * 8 + t) * 4 + ks) * 64 + l) * 8;
                s16x8 bh = *(const s16x8*)&W1h[idx];
                s16x8 bl = *(const s16x8*)&W1l[idx];
                acc[t] = __builtin_amdgcn_mfma_f32_16x16x32_bf16(ah, bh, acc[t], 0, 0, 0);
                acc[t] = __builtin_amdgcn_mfma_f32_16x16x32_bf16(ah, bl, acc[t], 0, 0, 0);
                acc[t] = __builtin_amdgcn_mfma_f32_16x16x32_bf16(al, bh, acc[t], 0, 0, 0);
            }
        }
        int rb = (l >> 4) * 4, cl = l & 15;
        #pragma unroll
        for (int t = 0; t < 8; ++t) {
            int col = (wave * 8 + t) * 16 + cl;
            float bb = bf1[col];
            #pragma unroll
            for (int r = 0; r < 4; ++r)
                Hs[rb + r][col] = gelu_exact(acc[t][r] + bb);
        }
    }
    __syncthreads();
    // ---- GEMM2: Os = Hs @ Wf2, two K-halves ----
    f32x4 acc2[2];
    acc2[0] = (f32x4){0.0f, 0.0f, 0.0f, 0.0f};
    acc2[1] = (f32x4){0.0f, 0.0f, 0.0f, 0.0f};
    #pragma unroll
    for (int halfk = 0; halfk < 2; ++halfk) {
        {
            int ksh = tid >> 5, lg = tid & 31;
            #pragma unroll
            for (int q = 0; q < 2; ++q) {
                int l2 = lg * 2 + q;
                int rr = l2 & 15, kb = (halfk * 8 + ksh) * 32 + ((l2 >> 4) << 3);
                float4 p0 = *(const float4*)&Hs[rr][kb];
                float4 p1 = *(const float4*)&Hs[rr][kb + 4];
                float av[8] = {p0.x, p0.y, p0.z, p0.w, p1.x, p1.y, p1.z, p1.w};
                s16x8 vh, vl;
                #pragma unroll
                for (int j = 0; j < 8; ++j) {
                    unsigned short hb, lb;
                    bsplit1(av[j], hb, lb);
                    vh[j] = (short)hb; vl[j] = (short)lb;
                }
                *(s16x8*)&Hfrag[0][(ksh * 64 + l2) * 8] = vh;
                *(s16x8*)&Hfrag[1][(ksh * 64 + l2) * 8] = vl;
            }
        }
        __syncthreads();
        #pragma unroll
        for (int ksl = 0; ksl < 8; ++ksl) {
            int ks = halfk * 8 + ksl;
            s16x8 ah = *(const s16x8*)&Hfrag[0][(ksl * 64 + l) * 8];
            s16x8 al = *(const s16x8*)&Hfrag[1][(ksl * 64 + l) * 8];
            #pragma unroll
            for (int t = 0; t < 2; ++t) {
                int idx = (((wave * 2 + t) * 16 + ks) * 64 + l) * 8;
                s16x8 bh = *(const s16x8*)&W2h[idx];
                s16x8 bl = *(const s16x8*)&W2l[idx];
                acc2[t] = __builtin_amdgcn_mfma_f32_16x16x32_bf16(ah, bh, acc2[t], 0, 0, 0);
                acc2[t] = __builtin_amdgcn_mfma_f32_16x16x32_bf16(ah, bl, acc2[t], 0, 0, 0);
                acc2[t] = __builtin_amdgcn_mfma_f32_16x16x32_bf16(al, bh, acc2[t], 0, 0, 0);
            }
        }
        __syncthreads();
    }
    // ---- write GEMM2 result (Os overlays Yfrag) ----
    float* Os = (float*)&Yfrag[0][0];   // [16][128]
    {
        int rb = (l >> 4) * 4, cl = l & 15;
        #pragma unroll
        for (int t = 0; t < 2; ++t) {
            int col = (wave * 2 + t) * 16 + cl;
            #pragma unroll
            for (int r = 0; r < 4; ++r)
                Os[(rb + r) * 128 + col] = acc2[t][r];
        }
    }
    __syncthreads();
    // ---- LN epilogue: out = LN(Ys + Os + bf2) ----
    {
        int cg = (tid & 31) * 4;
        int rp_ = (tid >> 5) * 2;
        float4 b2 = *(const float4*)&bf2[cg];
        float4 g = *(const float4*)&g2[cg];
        float4 bb = *(const float4*)&be2[cg];
        #pragma unroll
        for (int r = 0; r < 2; ++r) {
            int rr = rp_ + r;
            int row = row0 + rr;
            float v0 = Ys[rr][cg + 0] + Os[rr * 128 + cg + 0] + b2.x;
            float v1 = Ys[rr][cg + 1] + Os[rr * 128 + cg + 1] + b2.y;
            float v2 = Ys[rr][cg + 2] + Os[rr * 128 + cg + 2] + b2.z;
            float v3 = Ys[rr][cg + 3] + Os[rr * 128 + cg + 3] + b2.w;
            float sum = v0 + v1 + v2 + v3;
            for (int m = 1; m < 32; m <<= 1) sum += __shfl_xor(sum, m);
            float mu = sum * (1.0f / 128.0f);
            float d0 = v0 - mu, d1 = v1 - mu, d2 = v2 - mu, d3 = v3 - mu;
            float ss = d0 * d0 + d1 * d1 + d2 * d2 + d3 * d3;
            for (int m = 1; m < 32; m <<= 1) ss += __shfl_xor(ss, m);
            float var = ss * (1.0f / 128.0f);
            float rs = 1.0f / sqrtf(var + 1e-5f);
            float4 o;
            o.x = d0 * rs * g.x + bb.x;
            o.y = d1 * rs * g.y + bb.y;
            o.z = d2 * rs * g.z + bb.z;
            o.w = d3 * rs * g.w + bb.w;
            *(float4*)&IO[(long long)row * 128 + cg] = o;
        }
    }
}

extern "C" void kernel_launch(void* const* d_in, const int* in_sizes, int n_in,
                              void* d_out, int out_size, void* d_ws, size_t ws_size,
                              hipStream_t stream) {
    const float* x       = (const float*)d_in[0];
    const int*   eidx    = (const int*)d_in[1];
    const float* temb    = (const float*)d_in[2];
    const int*   etype   = (const int*)d_in[3];
    const float* etime   = (const float*)d_in[4];
    const float* Wq      = (const float*)d_in[5];
    const float* Wk      = (const float*)d_in[6];
    const float* Wv      = (const float*)d_in[7];
    const float* rel_q   = (const float*)d_in[8];
    const float* rel_k   = (const float*)d_in[9];
    const float* rel_v   = (const float*)d_in[10];
    const float* Wt      = (const float*)d_in[11];
    const float* bt      = (const float*)d_in[12];
    const float* Wd1     = (const float*)d_in[13];
    const float* bd1     = (const float*)d_in[14];
    const float* Wd2     = (const float*)d_in[15];
    const float* bd2     = (const float*)d_in[16];
    const float* dscale  = (const float*)d_in[17];
    const float* c_mag   = (const float*)d_in[18];
    const float* hbeta   = (const float*)d_in[19];
    const float* lalpha  = (const float*)d_in[20];
    const float* Wo      = (const float*)d_in[21];
    const float* bo      = (const float*)d_in[22];
    const float* g1      = (const float*)d_in[23];
    const float* be1     = (const float*)d_in[24];
    const float* g2      = (const float*)d_in[25];
    const float* be2     = (const float*)d_in[26];
    const float* Wf1     = (const float*)d_in[27];
    const float* bf1     = (const float*)d_in[28];
    const float* Wf2     = (const float*)d_in[29];
    const float* bf2     = (const float*)d_in[30];

    float* ws = (float*)d_ws;
    float*    Q    = ws + OFF_Q;
    float*    K    = ws + OFF_K;
    float*    V    = ws + OFF_V;
    float*    LOG  = ws + OFF_LOG;
    float*    T    = ws + OFF_T;
    float*    U    = ws + OFF_U;
    int*      ETM  = (int*)(ws + OFF_ETM);
    int*      CNT  = (int*)(ws + OFF_CNT);
    int*      CUR  = (int*)(ws + OFF_CUR);
    int*      RP   = (int*)(ws + OFF_RP);
    int*      ES   = (int*)(ws + OFF_ES);
    int*      BS   = (int*)(ws + OFF_BS);
    float*    AGG  = (float*)d_out;   // normalized aggregation, then Y1/out in-place
    float*    IO   = (float*)d_out;
    // split-bf16 weight arrays overlay the V region (V dead after k_agg2)
    unsigned short* W1h = (unsigned short*)(ws + OFF_V);
    unsigned short* W1l = W1h + 65536;
    unsigned short* W2h = W1l + 65536;
    unsigned short* W2l = W2h + 65536;

    k_zero<<<512, 256, 0, stream>>>(CNT, CUR, ETM);
    k_etmax<<<512, 256, 0, stream>>>(etype, ETM);
    k_hist<<<(EE + 255) / 256, 256, 0, stream>>>(eidx, CNT);
    k_scan1<<<NB, 256, 0, stream>>>(CNT, BS);
    k_scan2<<<1, 512, 0, stream>>>(BS);
    k_scan3<<<NB, 256, 0, stream>>>(CNT, BS, RP);
    k_scatter<<<(EE + 255) / 256, 256, 0, stream>>>(eidx, RP, CUR, ES);
    k_qkv<<<dim3(1563, 6), 256, 0, stream>>>(x, Wq, Wk, Wv, Q, K, V);
    k_tu<<<25000, 256, 0, stream>>>(x, c_mag, T, U);
    k_logits<<<EE / 32, 256, 0, stream>>>(Q, K, x, T, U, temb, eidx, etype, etime,
                                          rel_q, rel_k, Wt, bt, Wd1, bd1, Wd2, bd2,
                                          dscale, ETM, hbeta, lalpha, LOG);
    k_agg2<<<25000, 256, 0, stream>>>(RP, ES, eidx, etype, V, rel_v, LOG, AGG);
    k_cvt<<<256, 256, 0, stream>>>(Wf1, Wf2, W1h, W1l, W2h, W2l);   // after k_agg2 (V dead)
    k_out_ln1<<<NN / 32, 256, 0, stream>>>(AGG, Wo, bo, x, g1, be1);
    k_ffn_ln2<<<NN / 16, 256, 0, stream>>>(IO, W1h, W1l, W2h, W2l, bf1, bf2, g2, be2);
}

// Round 9
// 1072.821 us; speedup vs baseline: 10.9093x; 1.0425x over previous
//
#include <hip/hip_runtime.h>

constexpr int NN = 100000;   // nodes
constexpr int EE = 600000;   // edges
constexpr int DD = 128;
constexpr int HH = 8;
constexpr int NB = (NN + 255) / 256;   // scan blocks = 391

// ---------------- ws layout (float units) — ~46M floats = 184 MB ----------------
constexpr long long OFF_Q    = 0;
constexpr long long OFF_K    = OFF_Q    + (long long)NN*DD;
constexpr long long OFF_V    = OFF_K    + (long long)NN*DD;
constexpr long long OFF_LOG  = OFF_V    + (long long)NN*DD;   // E*H logits, SORTED position order
constexpr long long OFF_T    = OFF_LOG  + (long long)EE*HH;
constexpr long long OFF_U    = OFF_T    + (long long)NN;
constexpr long long OFF_ETM  = OFF_U    + (long long)NN;
constexpr long long OFF_CNT  = OFF_ETM  + 4;                  // int[NN]
constexpr long long OFF_CUR  = OFF_CNT  + (long long)NN;      // int[NN]
constexpr long long OFF_RP   = OFF_CUR  + (long long)NN;      // int[NN+1]
constexpr long long OFF_ES   = OFF_RP   + (long long)NN + 4;  // int[EE]  orig edge id per sorted pos
constexpr long long OFF_SRCS = OFF_ES   + (long long)EE;      // int[EE]  src per sorted pos
constexpr long long OFF_DSTS = OFF_SRCS + (long long)EE;      // int[EE]  dst per sorted pos
constexpr long long OFF_ETS  = OFF_DSTS + (long long)EE;      // int[EE]  etype per sorted pos
constexpr long long OFF_BS   = OFF_ETS  + (long long)EE;      // int[512]
// split-bf16 weight arrays overlay the V region (V dead after k_agg2; k_cvt runs after)

typedef float f32x4 __attribute__((ext_vector_type(4)));
typedef short s16x8 __attribute__((ext_vector_type(8)));

__device__ inline float gelu_exact(float v) {
    return 0.5f * v * (1.0f + erff(v * 0.70710678118654752440f));
}
__device__ inline void bsplit1(float x, unsigned short& hb, unsigned short& lb) {
    unsigned u = __float_as_uint(x);
    hb = (unsigned short)(u >> 16);
    float rem = x - __uint_as_float(((unsigned)hb) << 16);
    lb = (unsigned short)(__float_as_uint(rem) >> 16);
}

// ---------------- init: zero sort counters ----------------
__global__ __launch_bounds__(256) void k_zero(int* __restrict__ cnt, int* __restrict__ cur,
                                              int* __restrict__ etmax) {
    int stride = gridDim.x * 256;
    for (int i = blockIdx.x * 256 + threadIdx.x; i < NN; i += stride) { cnt[i] = 0; cur[i] = 0; }
    if (blockIdx.x == 0 && threadIdx.x == 0) etmax[0] = 0;
}

// ---------------- max(edge_type) reduction ----------------
__global__ __launch_bounds__(256) void k_etmax(const int* __restrict__ etype, int* __restrict__ etmax) {
    int lmax = 0;
    int stride = gridDim.x * 256;
    for (int i = blockIdx.x * 256 + threadIdx.x; i < EE; i += stride) lmax = max(lmax, etype[i]);
    for (int m = 1; m < 64; m <<= 1) lmax = max(lmax, __shfl_xor(lmax, m));
    if ((threadIdx.x & 63) == 0) atomicMax(etmax, lmax);
}

// ---------------- counting sort by dst: hist -> scan -> scatter ----------------
__global__ __launch_bounds__(256) void k_hist(const int* __restrict__ eidx, int* __restrict__ cnt) {
    int i = blockIdx.x * 256 + threadIdx.x;
    if (i < EE) atomicAdd(&cnt[eidx[EE + i]], 1);
}
__global__ __launch_bounds__(256) void k_scan1(const int* __restrict__ cnt, int* __restrict__ bs) {
    __shared__ int wsum[4];
    int i = blockIdx.x * 256 + threadIdx.x;
    int v = (i < NN) ? cnt[i] : 0;
    for (int m = 1; m < 64; m <<= 1) v += __shfl_xor(v, m);
    if ((threadIdx.x & 63) == 0) wsum[threadIdx.x >> 6] = v;
    __syncthreads();
    if (threadIdx.x == 0) bs[blockIdx.x] = wsum[0] + wsum[1] + wsum[2] + wsum[3];
}
__global__ __launch_bounds__(512) void k_scan2(int* __restrict__ bs) {
    __shared__ int s[512];
    int t = threadIdx.x;
    int v = (t < NB) ? bs[t] : 0;
    s[t] = v;
    __syncthreads();
    for (int off = 1; off < 512; off <<= 1) {
        int val = 0;
        if (t >= off) val = s[t - off];
        __syncthreads();
        if (t >= off) s[t] += val;
        __syncthreads();
    }
    if (t < NB) bs[t] = s[t] - v;   // exclusive
}
__global__ __launch_bounds__(256) void k_scan3(const int* __restrict__ cnt, const int* __restrict__ bs,
                                               int* __restrict__ rp) {
    __shared__ int s[256];
    int t = threadIdx.x;
    int i = blockIdx.x * 256 + t;
    int v = (i < NN) ? cnt[i] : 0;
    s[t] = v;
    __syncthreads();
    for (int off = 1; off < 256; off <<= 1) {
        int val = 0;
        if (t >= off) val = s[t - off];
        __syncthreads();
        if (t >= off) s[t] += val;
        __syncthreads();
    }
    int incl = s[t];
    int off0 = bs[blockIdx.x];
    if (i < NN) rp[i] = off0 + incl - v;
    if (i == NN - 1) rp[NN] = off0 + incl;
}
__global__ __launch_bounds__(256) void k_scatter(const int* __restrict__ eidx, const int* __restrict__ etype,
                                                 const int* __restrict__ rp, int* __restrict__ cur,
                                                 int* __restrict__ es, int* __restrict__ src_s,
                                                 int* __restrict__ dst_s, int* __restrict__ et_s) {
    int i = blockIdx.x * 256 + threadIdx.x;
    if (i < EE) {
        int d = eidx[EE + i];
        int pos = rp[d] + atomicAdd(&cur[d], 1);
        es[pos] = i;
        src_s[pos] = eidx[i];
        dst_s[pos] = d;
        et_s[pos] = etype[i];
    }
}

// ---------------- QKV GEMM: x(N,128) @ {Wq,Wk,Wv} ----------------
__global__ __launch_bounds__(256) void k_qkv(const float* __restrict__ x,
                                             const float* __restrict__ Wq, const float* __restrict__ Wk,
                                             const float* __restrict__ Wv,
                                             float* __restrict__ Q, float* __restrict__ K, float* __restrict__ V) {
    __shared__ float Ast[32][72];   // [k][row]
    __shared__ float Bs[32][72];    // [k][col]
    int tid = threadIdx.x;
    int nt = blockIdx.y;            // 0..5
    int mat = nt >> 1;
    int colbase = (nt & 1) * 64;
    const float* W = (mat == 0) ? Wq : (mat == 1) ? Wk : Wv;
    float* Out = (mat == 0) ? Q : (mat == 1) ? K : V;
    int row0 = blockIdx.x * 64;
    int tx = tid & 15, ty = tid >> 4;
    float acc[4][4] = {};
    for (int k0 = 0; k0 < 128; k0 += 32) {
        {
            int r = tid >> 3;            // 0..31
            int c = (tid & 7) * 4;       // 0..28
            #pragma unroll
            for (int rr = 0; rr < 2; ++rr) {
                int lrow = r + rr * 32;
                int grow = row0 + lrow;
                float4 v = make_float4(0.f, 0.f, 0.f, 0.f);
                if (grow < NN) v = *(const float4*)&x[(long long)grow * 128 + k0 + c];
                Ast[c + 0][lrow] = v.x; Ast[c + 1][lrow] = v.y;
                Ast[c + 2][lrow] = v.z; Ast[c + 3][lrow] = v.w;
            }
            int kk = tid >> 4;           // 0..15
            int cc = (tid & 15) * 4;     // 0..60
            #pragma unroll
            for (int k2 = 0; k2 < 2; ++k2) {
                int kr = kk + k2 * 16;
                *(float4*)&Bs[kr][cc] = *(const float4*)&W[(k0 + kr) * 128 + colbase + cc];
            }
        }
        __syncthreads();
        #pragma unroll
        for (int kk = 0; kk < 32; ++kk) {
            float4 a = *(const float4*)&Ast[kk][ty * 4];
            float4 b = *(const float4*)&Bs[kk][tx * 4];
            float av[4] = {a.x, a.y, a.z, a.w};
            float bv[4] = {b.x, b.y, b.z, b.w};
            #pragma unroll
            for (int i = 0; i < 4; ++i)
                #pragma unroll
                for (int j = 0; j < 4; ++j) acc[i][j] += av[i] * bv[j];
        }
        __syncthreads();
    }
    #pragma unroll
    for (int i = 0; i < 4; ++i) {
        int grow = row0 + ty * 4 + i;
        if (grow < NN)
            *(float4*)&Out[(long long)grow * 128 + colbase + tx * 4] =
                make_float4(acc[i][0], acc[i][1], acc[i][2], acc[i][3]);
    }
}

// ---------------- per-node hyperbolic scalars: m_i = t_i * x_i ----------------
__global__ __launch_bounds__(256) void k_tu(const float* __restrict__ x, const float* __restrict__ c_mag,
                                            float* __restrict__ T, float* __restrict__ U) {
    int wid = threadIdx.x >> 6;
    int lane = threadIdx.x & 63;
    int row = blockIdx.x * 4 + wid;
    if (row >= NN) return;
    float c = -fabsf(c_mag[0]);
    float abs_c = fmaxf(fabsf(c), 1e-15f);
    float sq = sqrtf(abs_c);
    float2 xv = *(const float2*)&x[(long long)row * 128 + lane * 2];
    float s = xv.x * xv.x + xv.y * xv.y;
    for (int m = 1; m < 64; m <<= 1) s += __shfl_xor(s, m);
    float nt = sqrtf(s);                       // true ||x||
    float n = fmaxf(nt, 1e-15f);               // clamped (reference _expmap)
    float arg = sq * n;
    float f = ((c < 0.0f) ? tanhf(arg) : tanf(arg)) / arg;
    float norm = fabsf(f) * nt;                // ||expmap(x)||, unclamped (reference _proj)
    float maxnorm = (1.0f - 1e-5f) / sq;
    float scale = (norm > maxnorm) ? (maxnorm / norm) : 1.0f;
    float t = f * scale;
    if (lane == 0) { T[row] = t; U[row] = t * t * s; }
}

// ---------------- per-edge logits in dst-sorted order (+fused decay MLP + LDS time-proj) ----------------
// Block = 32 consecutive sorted positions -> dst gathers are near-sequential.
__global__ __launch_bounds__(256) void k_logits(const float* __restrict__ Q, const float* __restrict__ K,
                                                const float* __restrict__ x, const float* __restrict__ T,
                                                const float* __restrict__ U, const float* __restrict__ temb,
                                                const int* __restrict__ es, const int* __restrict__ src_s,
                                                const int* __restrict__ dst_s, const int* __restrict__ et_s,
                                                const float* __restrict__ etime,
                                                const float* __restrict__ rel_q, const float* __restrict__ rel_k,
                                                const float* __restrict__ Wt, const float* __restrict__ bt,
                                                const float* __restrict__ Wd1, const float* __restrict__ bd1,
                                                const float* __restrict__ Wd2, const float* __restrict__ bd2,
                                                const float* __restrict__ dscale, const int* __restrict__ etmax,
                                                const float* __restrict__ hyp_beta,
                                                const float* __restrict__ logit_alpha,
                                                float* __restrict__ LOG) {
    __shared__ float Ts[32][32];    // temb rows of this block's 32 (sorted) edges
    __shared__ float TP[32][128];   // time projection per edge
    __shared__ float Dec[32][8];
    __shared__ float Wd1s[128];
    __shared__ float bd1s[64];
    __shared__ float Wd2s[512];
    int tid = threadIdx.x;
    int pb0 = blockIdx.x * 32;      // sorted position base
    {
        int er = tid >> 3;          // 0..31
        int c = (tid & 7) * 4;      // 0..28
        int e = es[pb0 + er];
        *(float4*)&Ts[er][c] = *(const float4*)&temb[(long long)e * 32 + c];
        if (tid < 128) Wd1s[tid] = Wd1[tid];
        if (tid >= 128 && tid < 192) bd1s[tid - 128] = bd1[tid - 128];
        Wd2s[tid] = Wd2[tid];
        Wd2s[tid + 256] = Wd2[tid + 256];
    }
    __syncthreads();
    // ---- decay MLP: one thread per (edge, head) ----
    {
        int el = tid >> 3, hh = tid & 7;
        int pos = pb0 + el;
        float denom_t = fmaxf(1.0f, (float)(etmax[0]) + 1.0f);
        float in0 = etime[es[pos]];
        float in1 = (float)et_s[pos] / denom_t;
        float acc = bd2[hh];
        #pragma unroll
        for (int j = 0; j < 64; ++j) {
            float hid = fmaxf(in0 * Wd1s[j] + in1 * Wd1s[64 + j] + bd1s[j], 0.0f);
            acc += hid * Wd2s[j * 8 + hh];
        }
        Dec[el][hh] = expf(dscale[hh] * tanhf(acc));
    }
    // ---- TP = Ts @ Wt + bt ----
    {
        int c4 = (tid & 31) * 4;
        int g = tid >> 5;           // 0..7
        float4 bt4 = *(const float4*)&bt[c4];
        float4 a0 = bt4, a1 = bt4, a2 = bt4, a3 = bt4;
        for (int t = 0; t < 32; ++t) {
            float4 w = *(const float4*)&Wt[t * 128 + c4];
            float f0 = Ts[g][t], f1 = Ts[g + 8][t], f2 = Ts[g + 16][t], f3 = Ts[g + 24][t];
            a0.x += f0 * w.x; a0.y += f0 * w.y; a0.z += f0 * w.z; a0.w += f0 * w.w;
            a1.x += f1 * w.x; a1.y += f1 * w.y; a1.z += f1 * w.z; a1.w += f1 * w.w;
            a2.x += f2 * w.x; a2.y += f2 * w.y; a2.z += f2 * w.z; a2.w += f2 * w.w;
            a3.x += f3 * w.x; a3.y += f3 * w.y; a3.z += f3 * w.z; a3.w += f3 * w.w;
        }
        *(float4*)&TP[g][c4] = a0;
        *(float4*)&TP[g + 8][c4] = a1;
        *(float4*)&TP[g + 16][c4] = a2;
        *(float4*)&TP[g + 24][c4] = a3;
    }
    __syncthreads();
    // ---- main: half-wave per sorted position ----
    int wid = tid >> 6;
    int lane = tid & 63;
    int half = lane >> 5;
    int l = lane & 31;
    int d4 = l * 4;
    int h = l >> 2;
    float alpha = 1.0f / (1.0f + expf(-logit_alpha[h]));
    float beta = hyp_beta[h];
    #pragma unroll
    for (int i = 0; i < 4; ++i) {
        int elocal = wid * 8 + i * 2 + half;
        int pos = pb0 + elocal;
        int src = src_s[pos], dst = dst_s[pos];
        int et = et_s[pos];
        float4 q  = *(const float4*)&Q[(long long)dst * 128 + d4];
        float4 rq = *(const float4*)&rel_q[et * 128 + d4];
        float4 k  = *(const float4*)&K[(long long)src * 128 + d4];
        float4 rk = *(const float4*)&rel_k[et * 128 + d4];
        float4 tp = *(const float4*)&TP[elocal][d4];
        float4 xs = *(const float4*)&x[(long long)src * 128 + d4];
        float4 xd = *(const float4*)&x[(long long)dst * 128 + d4];
        float ep = (q.x + rq.x) * (k.x + rk.x + tp.x)
                 + (q.y + rq.y) * (k.y + rk.y + tp.y)
                 + (q.z + rq.z) * (k.z + rk.z + tp.z)
                 + (q.w + rq.w) * (k.w + rk.w + tp.w);
        float dp = xs.x * xd.x + xs.y * xd.y + xs.z * xd.z + xs.w * xd.w;
        ep += __shfl_xor(ep, 1); ep += __shfl_xor(ep, 2);
        dp += __shfl_xor(dp, 1); dp += __shfl_xor(dp, 2); dp += __shfl_xor(dp, 4);
        dp += __shfl_xor(dp, 8); dp += __shfl_xor(dp, 16);
        float man2 = fmaxf(U[src] + U[dst] - 2.0f * T[src] * T[dst] * dp, 0.0f);
        float man = sqrtf(man2);
        float dec = Dec[elocal][h];
        float eu = ep * 0.25f * dec;                 // / sqrt(16) then * decay
        float hyp = -beta * man * dec;
        float lg = alpha * eu + (1.0f - alpha) * hyp;
        if ((l & 3) == 0) LOG[(long long)pos * 8 + h] = lg;   // sorted-position layout
    }
}

// ---------------- segmented softmax + V aggregation: one wave per dst node ----------------
// LOG is in sorted-position order -> sequential reads. No atomics; normalized plain stores.
__global__ __launch_bounds__(256) void k_agg2(const int* __restrict__ rp, const int* __restrict__ src_s,
                                              const int* __restrict__ et_s,
                                              const float* __restrict__ V, const float* __restrict__ rel_v,
                                              const float* __restrict__ LOG, float* __restrict__ AGG) {
    int wid = threadIdx.x >> 6, lane = threadIdx.x & 63;
    int node = blockIdx.x * 4 + wid;
    if (node >= NN) return;
    int beg = rp[node], end = rp[node + 1];
    int d = lane * 2;
    int h = lane >> 3;
    float mx = -3.0e38f;
    for (int i = beg; i < end; ++i) {
        mx = fmaxf(mx, LOG[(long long)i * 8 + h]);
    }
    float den = 0.0f;
    float ax = 0.0f, ay = 0.0f;
    for (int i = beg; i < end; ++i) {
        int src = src_s[i];
        int et = et_s[i];
        float ex = expf(LOG[(long long)i * 8 + h] - mx);
        den += ex;
        float2 v  = *(const float2*)&V[(long long)src * 128 + d];
        float2 rv = *(const float2*)&rel_v[et * 128 + d];
        ax += (v.x + rv.x) * ex;
        ay += (v.y + rv.y) * ex;
    }
    float sc = (end > beg) ? (1.0f / den) : 0.0f;
    *(float2*)&AGG[(long long)node * 128 + d] = make_float2(ax * sc, ay * sc);
}

// ---------------- split Wf1/Wf2 into bf16 hi/lo in MFMA fragment order ----------------
__global__ __launch_bounds__(256) void k_cvt(const float* __restrict__ Wf1, const float* __restrict__ Wf2,
                                             unsigned short* __restrict__ W1h, unsigned short* __restrict__ W1l,
                                             unsigned short* __restrict__ W2h, unsigned short* __restrict__ W2l) {
    int idx = blockIdx.x * 256 + threadIdx.x;   // 0..65535
    {   // Wf1: 128x512, tiles=32 (N), ksteps=4
        int tile = idx >> 11, rem = idx & 2047;
        int ks = rem >> 9, rem2 = rem & 511;
        int l = rem2 >> 3, j = rem2 & 7;
        int k = ks * 32 + ((l >> 4) << 3) + j;
        int n = (tile << 4) + (l & 15);
        unsigned short hb, lb;
        bsplit1(Wf1[k * 512 + n], hb, lb);
        W1h[idx] = hb; W1l[idx] = lb;
    }
    {   // Wf2: 512x128, tiles=8 (N), ksteps=16
        int tile = idx >> 13;
        int ks = (idx >> 9) & 15;
        int l = (idx >> 3) & 63, j = idx & 7;
        int k = ks * 32 + ((l >> 4) << 3) + j;
        int n = (tile << 4) + (l & 15);
        unsigned short hb, lb;
        bsplit1(Wf2[k * 128 + n], hb, lb);
        W2h[idx] = hb; W2l[idx] = lb;
    }
}

// ---------------- out = agg@Wo + bo; y1 = LN(x+out). AGG and Y1 alias in d_out ----------------
__global__ __launch_bounds__(256) void k_out_ln1(float* AGGY1,          // in: AGG (normalized), out: Y1
                                                 const float* __restrict__ Wo,
                                                 const float* __restrict__ bo, const float* __restrict__ x,
                                                 const float* __restrict__ g1, const float* __restrict__ be1) {
    __shared__ float Ast[32][40];
    __shared__ float Bs[32][136];
    int tid = threadIdx.x;
    int row0 = blockIdx.x * 32;
    int tx = tid & 31, ty = tid >> 5;
    float acc[4][4] = {};
    for (int k0 = 0; k0 < 128; k0 += 32) {
        {
            int r = tid >> 3, c = (tid & 7) * 4;     // r 0..31
            float4 v = *(const float4*)&AGGY1[(long long)(row0 + r) * 128 + k0 + c];
            Ast[c + 0][r] = v.x; Ast[c + 1][r] = v.y; Ast[c + 2][r] = v.z; Ast[c + 3][r] = v.w;
            int kk = tid >> 5, cc = (tid & 31) * 4;  // kk 0..7
            #pragma unroll
            for (int k2 = 0; k2 < 4; ++k2) {
                int kr = kk + k2 * 8;
                *(float4*)&Bs[kr][cc] = *(const float4*)&Wo[(k0 + kr) * 128 + cc];
            }
        }
        __syncthreads();
        #pragma unroll
        for (int kk = 0; kk < 32; ++kk) {
            float4 a = *(const float4*)&Ast[kk][ty * 4];
            float4 b = *(const float4*)&Bs[kk][tx * 4];
            float av[4] = {a.x, a.y, a.z, a.w};
            float bv[4] = {b.x, b.y, b.z, b.w};
            #pragma unroll
            for (int i = 0; i < 4; ++i)
                #pragma unroll
                for (int j = 0; j < 4; ++j) acc[i][j] += av[i] * bv[j];
        }
        __syncthreads();
    }
    float4 bov = *(const float4*)&bo[tx * 4];
    float4 g = *(const float4*)&g1[tx * 4];
    float4 bb = *(const float4*)&be1[tx * 4];
    #pragma unroll
    for (int i = 0; i < 4; ++i) {
        int row = row0 + ty * 4 + i;
        float4 xv = *(const float4*)&x[(long long)row * 128 + tx * 4];
        float v0 = xv.x + acc[i][0] + bov.x;
        float v1 = xv.y + acc[i][1] + bov.y;
        float v2 = xv.z + acc[i][2] + bov.z;
        float v3 = xv.w + acc[i][3] + bov.w;
        float sum = v0 + v1 + v2 + v3;
        for (int m = 1; m < 32; m <<= 1) sum += __shfl_xor(sum, m);
        float mu = sum * (1.0f / 128.0f);
        float d0 = v0 - mu, d1 = v1 - mu, d2 = v2 - mu, d3 = v3 - mu;
        float ss = d0 * d0 + d1 * d1 + d2 * d2 + d3 * d3;
        for (int m = 1; m < 32; m <<= 1) ss += __shfl_xor(ss, m);
        float var = ss * (1.0f / 128.0f);
        float rs = 1.0f / sqrtf(var + 1e-5f);
        float4 o;
        o.x = d0 * rs * g.x + bb.x;
        o.y = d1 * rs * g.y + bb.y;
        o.z = d2 * rs * g.z + bb.z;
        o.w = d3 * rs * g.w + bb.w;
        *(float4*)&AGGY1[(long long)row * 128 + tx * 4] = o;
    }
}

// ---------------- FFN (128->512->128) + LN2 via split-bf16 MFMA ----------------
__global__ __launch_bounds__(256) void k_ffn_ln2(float* IO,
        const unsigned short* __restrict__ W1h, const unsigned short* __restrict__ W1l,
        const unsigned short* __restrict__ W2h, const unsigned short* __restrict__ W2l,
        const float* __restrict__ bf1, const float* __restrict__ bf2,
        const float* __restrict__ g2, const float* __restrict__ be2) {
    __shared__ __align__(16) float Ys[16][132];      // 8448 B
    __shared__ __align__(16) short Yfrag[2][2048];   // 8192 B (hi,lo) — Os overlays later
    __shared__ __align__(16) float Hs[16][516];      // 33024 B
    __shared__ __align__(16) short Hfrag[2][4096];   // 16384 B (one K-half at a time)
    int tid = threadIdx.x;
    int row0 = blockIdx.x * 16;
    int wave = tid >> 6, l = tid & 63;
    // ---- stage Y tile ----
    {
        int r = tid >> 4, c = (tid & 15) * 8;
        float4 a = *(const float4*)&IO[(long long)(row0 + r) * 128 + c];
        float4 b = *(const float4*)&IO[(long long)(row0 + r) * 128 + c + 4];
        *(float4*)&Ys[r][c] = a;
        *(float4*)&Ys[r][c + 4] = b;
    }
    __syncthreads();
    // ---- Y frag pass ----
    {
        int ks = tid >> 6, ll = tid & 63;
        int rr = ll & 15, kb = ks * 32 + ((ll >> 4) << 3);
        float4 p0 = *(const float4*)&Ys[rr][kb];
        float4 p1 = *(const float4*)&Ys[rr][kb + 4];
        float av[8] = {p0.x, p0.y, p0.z, p0.w, p1.x, p1.y, p1.z, p1.w};
        s16x8 vh, vl;
        #pragma unroll
        for (int j = 0; j < 8; ++j) {
            unsigned short hb, lb;
            bsplit1(av[j], hb, lb);
            vh[j] = (short)hb; vl[j] = (short)lb;
        }
        *(s16x8*)&Yfrag[0][(ks * 64 + ll) * 8] = vh;
        *(s16x8*)&Yfrag[1][(ks * 64 + ll) * 8] = vl;
    }
    __syncthreads();
    // ---- GEMM1: Hs = gelu(Y @ Wf1 + bf1) ----
    {
        f32x4 zero = {0.0f, 0.0f, 0.0f, 0.0f};
        f32x4 acc[8];
        #pragma unroll
        for (int t = 0; t < 8; ++t) acc[t] = zero;
        #pragma unroll
        for (int ks = 0; ks < 4; ++ks) {
            s16x8 ah = *(const s16x8*)&Yfrag[0][(ks * 64 + l) * 8];
            s16x8 al = *(const s16x8*)&Yfrag[1][(ks * 64 + l) * 8];
            #pragma unroll
            for (int t = 0; t < 8; ++t) {
                int idx = (((wave * 8 + t) * 4 + ks) * 64 + l) * 8;
                s16x8 bh = *(const s16x8*)&W1h[idx];
                s16x8 bl = *(const s16x8*)&W1l[idx];
                acc[t] = __builtin_amdgcn_mfma_f32_16x16x32_bf16(ah, bh, acc[t], 0, 0, 0);
                acc[t] = __builtin_amdgcn_mfma_f32_16x16x32_bf16(ah, bl, acc[t], 0, 0, 0);
                acc[t] = __builtin_amdgcn_mfma_f32_16x16x32_bf16(al, bh, acc[t], 0, 0, 0);
            }
        }
        int rb = (l >> 4) * 4, cl = l & 15;
        #pragma unroll
        for (int t = 0; t < 8; ++t) {
            int col = (wave * 8 + t) * 16 + cl;
            float bb = bf1[col];
            #pragma unroll
            for (int r = 0; r < 4; ++r)
                Hs[rb + r][col] = gelu_exact(acc[t][r] + bb);
        }
    }
    __syncthreads();
    // ---- GEMM2: Os = Hs @ Wf2, two K-halves ----
    f32x4 acc2[2];
    acc2[0] = (f32x4){0.0f, 0.0f, 0.0f, 0.0f};
    acc2[1] = (f32x4){0.0f, 0.0f, 0.0f, 0.0f};
    #pragma unroll
    for (int halfk = 0; halfk < 2; ++halfk) {
        {
            int ksh = tid >> 5, lg = tid & 31;
            #pragma unroll
            for (int q = 0; q < 2; ++q) {
                int l2 = lg * 2 + q;
                int rr = l2 & 15, kb = (halfk * 8 + ksh) * 32 + ((l2 >> 4) << 3);
                float4 p0 = *(const float4*)&Hs[rr][kb];
                float4 p1 = *(const float4*)&Hs[rr][kb + 4];
                float av[8] = {p0.x, p0.y, p0.z, p0.w, p1.x, p1.y, p1.z, p1.w};
                s16x8 vh, vl;
                #pragma unroll
                for (int j = 0; j < 8; ++j) {
                    unsigned short hb, lb;
                    bsplit1(av[j], hb, lb);
                    vh[j] = (short)hb; vl[j] = (short)lb;
                }
                *(s16x8*)&Hfrag[0][(ksh * 64 + l2) * 8] = vh;
                *(s16x8*)&Hfrag[1][(ksh * 64 + l2) * 8] = vl;
            }
        }
        __syncthreads();
        #pragma unroll
        for (int ksl = 0; ksl < 8; ++ksl) {
            int ks = halfk * 8 + ksl;
            s16x8 ah = *(const s16x8*)&Hfrag[0][(ksl * 64 + l) * 8];
            s16x8 al = *(const s16x8*)&Hfrag[1][(ksl * 64 + l) * 8];
            #pragma unroll
            for (int t = 0; t < 2; ++t) {
                int idx = (((wave * 2 + t) * 16 + ks) * 64 + l) * 8;
                s16x8 bh = *(const s16x8*)&W2h[idx];
                s16x8 bl = *(const s16x8*)&W2l[idx];
                acc2[t] = __builtin_amdgcn_mfma_f32_16x16x32_bf16(ah, bh, acc2[t], 0, 0, 0);
                acc2[t] = __builtin_amdgcn_mfma_f32_16x16x32_bf16(ah, bl, acc2[t], 0, 0, 0);
                acc2[t] = __builtin_amdgcn_mfma_f32_16x16x32_bf16(al, bh, acc2[t], 0, 0, 0);
            }
        }
        __syncthreads();
    }
    // ---- write GEMM2 result (Os overlays Yfrag) ----
    float* Os = (float*)&Yfrag[0][0];   // [16][128]
    {
        int rb = (l >> 4) * 4, cl = l & 15;
        #pragma unroll
        for (int t = 0; t < 2; ++t) {
            int col = (wave * 2 + t) * 16 + cl;
            #pragma unroll
            for (int r = 0; r < 4; ++r)
                Os[(rb + r) * 128 + col] = acc2[t][r];
        }
    }
    __syncthreads();
    // ---- LN epilogue: out = LN(Ys + Os + bf2) ----
    {
        int cg = (tid & 31) * 4;
        int rp_ = (tid >> 5) * 2;
        float4 b2 = *(const float4*)&bf2[cg];
        float4 g = *(const float4*)&g2[cg];
        float4 bb = *(const float4*)&be2[cg];
        #pragma unroll
        for (int r = 0; r < 2; ++r) {
            int rr = rp_ + r;
            int row = row0 + rr;
            float v0 = Ys[rr][cg + 0] + Os[rr * 128 + cg + 0] + b2.x;
            float v1 = Ys[rr][cg + 1] + Os[rr * 128 + cg + 1] + b2.y;
            float v2 = Ys[rr][cg + 2] + Os[rr * 128 + cg + 2] + b2.z;
            float v3 = Ys[rr][cg + 3] + Os[rr * 128 + cg + 3] + b2.w;
            float sum = v0 + v1 + v2 + v3;
            for (int m = 1; m < 32; m <<= 1) sum += __shfl_xor(sum, m);
            float mu = sum * (1.0f / 128.0f);
            float d0 = v0 - mu, d1 = v1 - mu, d2 = v2 - mu, d3 = v3 - mu;
            float ss = d0 * d0 + d1 * d1 + d2 * d2 + d3 * d3;
            for (int m = 1; m < 32; m <<= 1) ss += __shfl_xor(ss, m);
            float var = ss * (1.0f / 128.0f);
            float rs = 1.0f / sqrtf(var + 1e-5f);
            float4 o;
            o.x = d0 * rs * g.x + bb.x;
            o.y = d1 * rs * g.y + bb.y;
            o.z = d2 * rs * g.z + bb.z;
            o.w = d3 * rs * g.w + bb.w;
            *(float4*)&IO[(long long)row * 128 + cg] = o;
        }
    }
}

extern "C" void kernel_launch(void* const* d_in, const int* in_sizes, int n_in,
                              void* d_out, int out_size, void* d_ws, size_t ws_size,
                              hipStream_t stream) {
    const float* x       = (const float*)d_in[0];
    const int*   eidx    = (const int*)d_in[1];
    const float* temb    = (const float*)d_in[2];
    const int*   etype   = (const int*)d_in[3];
    const float* etime   = (const float*)d_in[4];
    const float* Wq      = (const float*)d_in[5];
    const float* Wk      = (const float*)d_in[6];
    const float* Wv      = (const float*)d_in[7];
    const float* rel_q   = (const float*)d_in[8];
    const float* rel_k   = (const float*)d_in[9];
    const float* rel_v   = (const float*)d_in[10];
    const float* Wt      = (const float*)d_in[11];
    const float* bt      = (const float*)d_in[12];
    const float* Wd1     = (const float*)d_in[13];
    const float* bd1     = (const float*)d_in[14];
    const float* Wd2     = (const float*)d_in[15];
    const float* bd2     = (const float*)d_in[16];
    const float* dscale  = (const float*)d_in[17];
    const float* c_mag   = (const float*)d_in[18];
    const float* hbeta   = (const float*)d_in[19];
    const float* lalpha  = (const float*)d_in[20];
    const float* Wo      = (const float*)d_in[21];
    const float* bo      = (const float*)d_in[22];
    const float* g1      = (const float*)d_in[23];
    const float* be1     = (const float*)d_in[24];
    const float* g2      = (const float*)d_in[25];
    const float* be2     = (const float*)d_in[26];
    const float* Wf1     = (const float*)d_in[27];
    const float* bf1     = (const float*)d_in[28];
    const float* Wf2     = (const float*)d_in[29];
    const float* bf2     = (const float*)d_in[30];

    float* ws = (float*)d_ws;
    float*    Q    = ws + OFF_Q;
    float*    K    = ws + OFF_K;
    float*    V    = ws + OFF_V;
    float*    LOG  = ws + OFF_LOG;
    float*    T    = ws + OFF_T;
    float*    U    = ws + OFF_U;
    int*      ETM  = (int*)(ws + OFF_ETM);
    int*      CNT  = (int*)(ws + OFF_CNT);
    int*      CUR  = (int*)(ws + OFF_CUR);
    int*      RP   = (int*)(ws + OFF_RP);
    int*      ES   = (int*)(ws + OFF_ES);
    int*      SRCS = (int*)(ws + OFF_SRCS);
    int*      DSTS = (int*)(ws + OFF_DSTS);
    int*      ETS  = (int*)(ws + OFF_ETS);
    int*      BS   = (int*)(ws + OFF_BS);
    float*    AGG  = (float*)d_out;   // normalized aggregation, then Y1/out in-place
    float*    IO   = (float*)d_out;
    // split-bf16 weight arrays overlay the V region (V dead after k_agg2)
    unsigned short* W1h = (unsigned short*)(ws + OFF_V);
    unsigned short* W1l = W1h + 65536;
    unsigned short* W2h = W1l + 65536;
    unsigned short* W2l = W2h + 65536;

    k_zero<<<512, 256, 0, stream>>>(CNT, CUR, ETM);
    k_etmax<<<512, 256, 0, stream>>>(etype, ETM);
    k_hist<<<(EE + 255) / 256, 256, 0, stream>>>(eidx, CNT);
    k_scan1<<<NB, 256, 0, stream>>>(CNT, BS);
    k_scan2<<<1, 512, 0, stream>>>(BS);
    k_scan3<<<NB, 256, 0, stream>>>(CNT, BS, RP);
    k_scatter<<<(EE + 255) / 256, 256, 0, stream>>>(eidx, etype, RP, CUR, ES, SRCS, DSTS, ETS);
    k_qkv<<<dim3(1563, 6), 256, 0, stream>>>(x, Wq, Wk, Wv, Q, K, V);
    k_tu<<<25000, 256, 0, stream>>>(x, c_mag, T, U);
    k_logits<<<EE / 32, 256, 0, stream>>>(Q, K, x, T, U, temb, ES, SRCS, DSTS, ETS, etime,
                                          rel_q, rel_k, Wt, bt, Wd1, bd1, Wd2, bd2,
                                          dscale, ETM, hbeta, lalpha, LOG);
    k_agg2<<<25000, 256, 0, stream>>>(RP, SRCS, ETS, V, rel_v, LOG, AGG);
    k_cvt<<<256, 256, 0, stream>>>(Wf1, Wf2, W1h, W1l, W2h, W2l);   // after k_agg2 (V dead)
    k_out_ln1<<<NN / 32, 256, 0, stream>>>(AGG, Wo, bo, x, g1, be1);
    k_ffn_ln2<<<NN / 16, 256, 0, stream>>>(IO, W1h, W1l, W2h, W2l, bf1, bf2, g2, be2);
}

// Round 11
// 987.631 us; speedup vs baseline: 11.8503x; 1.0863x over previous
//
#include <hip/hip_runtime.h>

constexpr int NN = 100000;   // nodes
constexpr int EE = 600000;   // edges
constexpr int DD = 128;
constexpr int HH = 8;
constexpr int NB = (NN + 255) / 256;   // scan blocks = 391

// ---------------- ws layout (float units) — ~46M floats = 186 MB ----------------
constexpr long long OFF_Q    = 0;
constexpr long long OFF_K    = OFF_Q    + (long long)NN*DD;
constexpr long long OFF_V    = OFF_K    + (long long)NN*DD;
constexpr long long OFF_LOG  = OFF_V    + (long long)NN*DD;   // E*H logits, SORTED position order
constexpr long long OFF_T    = OFF_LOG  + (long long)EE*HH;
constexpr long long OFF_U    = OFF_T    + (long long)NN;
constexpr long long OFF_ETM  = OFF_U    + (long long)NN;
constexpr long long OFF_CNT  = OFF_ETM  + 4;                  // int[NN]
constexpr long long OFF_CUR  = OFF_CNT  + (long long)NN;      // int[NN]
constexpr long long OFF_RP   = OFF_CUR  + (long long)NN;      // int[NN+1]
constexpr long long OFF_ES   = OFF_RP   + (long long)NN + 4;  // int[EE]  orig edge id per sorted pos
constexpr long long OFF_SRCS = OFF_ES   + (long long)EE;      // int[EE]  src per sorted pos
constexpr long long OFF_DSTS = OFF_SRCS + (long long)EE;      // int[EE]  dst per sorted pos
constexpr long long OFF_ETS  = OFF_DSTS + (long long)EE;      // int[EE]  etype per sorted pos
constexpr long long OFF_BS   = OFF_ETS  + (long long)EE;      // int[512]
constexpr long long OFF_WQKVF= OFF_BS   + 512;                // 98304 shorts = 49152 floats (Wq/Wk/Wv hi+lo frags)
constexpr long long OFF_WTF  = OFF_WQKVF+ 49152;              // 8192 shorts = 4096 floats (Wt hi+lo frags)
// split-bf16 FFN weight arrays overlay the V region (V dead after k_agg2; k_cvt runs after)

typedef float f32x4 __attribute__((ext_vector_type(4)));
typedef short s16x8 __attribute__((ext_vector_type(8)));

__device__ inline float gelu_exact(float v) {
    return 0.5f * v * (1.0f + erff(v * 0.70710678118654752440f));
}
__device__ inline void bsplit1(float x, unsigned short& hb, unsigned short& lb) {
    unsigned u = __float_as_uint(x);
    hb = (unsigned short)(u >> 16);
    float rem = x - __uint_as_float(((unsigned)hb) << 16);
    lb = (unsigned short)(__float_as_uint(rem) >> 16);
}

// ---------------- init: zero sort counters ----------------
__global__ __launch_bounds__(256) void k_zero(int* __restrict__ cnt, int* __restrict__ cur,
                                              int* __restrict__ etmax) {
    int stride = gridDim.x * 256;
    for (int i = blockIdx.x * 256 + threadIdx.x; i < NN; i += stride) { cnt[i] = 0; cur[i] = 0; }
    if (blockIdx.x == 0 && threadIdx.x == 0) etmax[0] = 0;
}

// ---------------- max(edge_type) reduction ----------------
__global__ __launch_bounds__(256) void k_etmax(const int* __restrict__ etype, int* __restrict__ etmax) {
    int lmax = 0;
    int stride = gridDim.x * 256;
    for (int i = blockIdx.x * 256 + threadIdx.x; i < EE; i += stride) lmax = max(lmax, etype[i]);
    for (int m = 1; m < 64; m <<= 1) lmax = max(lmax, __shfl_xor(lmax, m));
    if ((threadIdx.x & 63) == 0) atomicMax(etmax, lmax);
}

// ---------------- counting sort by dst: hist -> scan -> scatter ----------------
__global__ __launch_bounds__(256) void k_hist(const int* __restrict__ eidx, int* __restrict__ cnt) {
    int i = blockIdx.x * 256 + threadIdx.x;
    if (i < EE) atomicAdd(&cnt[eidx[EE + i]], 1);
}
__global__ __launch_bounds__(256) void k_scan1(const int* __restrict__ cnt, int* __restrict__ bs) {
    __shared__ int wsum[4];
    int i = blockIdx.x * 256 + threadIdx.x;
    int v = (i < NN) ? cnt[i] : 0;
    for (int m = 1; m < 64; m <<= 1) v += __shfl_xor(v, m);
    if ((threadIdx.x & 63) == 0) wsum[threadIdx.x >> 6] = v;
    __syncthreads();
    if (threadIdx.x == 0) bs[blockIdx.x] = wsum[0] + wsum[1] + wsum[2] + wsum[3];
}
__global__ __launch_bounds__(512) void k_scan2(int* __restrict__ bs) {
    __shared__ int s[512];
    int t = threadIdx.x;
    int v = (t < NB) ? bs[t] : 0;
    s[t] = v;
    __syncthreads();
    for (int off = 1; off < 512; off <<= 1) {
        int val = 0;
        if (t >= off) val = s[t - off];
        __syncthreads();
        if (t >= off) s[t] += val;
        __syncthreads();
    }
    if (t < NB) bs[t] = s[t] - v;   // exclusive
}
__global__ __launch_bounds__(256) void k_scan3(const int* __restrict__ cnt, const int* __restrict__ bs,
                                               int* __restrict__ rp) {
    __shared__ int s[256];
    int t = threadIdx.x;
    int i = blockIdx.x * 256 + t;
    int v = (i < NN) ? cnt[i] : 0;
    s[t] = v;
    __syncthreads();
    for (int off = 1; off < 256; off <<= 1) {
        int val = 0;
        if (t >= off) val = s[t - off];
        __syncthreads();
        if (t >= off) s[t] += val;
        __syncthreads();
    }
    int incl = s[t];
    int off0 = bs[blockIdx.x];
    if (i < NN) rp[i] = off0 + incl - v;
    if (i == NN - 1) rp[NN] = off0 + incl;
}
__global__ __launch_bounds__(256) void k_scatter(const int* __restrict__ eidx, const int* __restrict__ etype,
                                                 const int* __restrict__ rp, int* __restrict__ cur,
                                                 int* __restrict__ es, int* __restrict__ src_s,
                                                 int* __restrict__ dst_s, int* __restrict__ et_s) {
    int i = blockIdx.x * 256 + threadIdx.x;
    if (i < EE) {
        int d = eidx[EE + i];
        int pos = rp[d] + atomicAdd(&cur[d], 1);
        es[pos] = i;
        src_s[pos] = eidx[i];
        dst_s[pos] = d;
        et_s[pos] = etype[i];
    }
}

// ---------------- pre-split Wq/Wk/Wv (128x128) + Wt (32x128) into bf16 hi/lo MFMA frags ----------------
__global__ __launch_bounds__(256) void k_cvt_pre(const float* __restrict__ Wq, const float* __restrict__ Wk,
                                                 const float* __restrict__ Wv, const float* __restrict__ Wt,
                                                 unsigned short* __restrict__ WQKVh, unsigned short* __restrict__ WQKVl,
                                                 unsigned short* __restrict__ WTh, unsigned short* __restrict__ WTl) {
    int idx = blockIdx.x * 256 + threadIdx.x;   // 0..53247
    if (idx < 49152) {
        int mat = idx >> 14, r = idx & 16383;
        int tile = r >> 11, ks = (r >> 9) & 3, l = (r >> 3) & 63, j = r & 7;
        int k = ks * 32 + ((l >> 4) << 3) + j;
        int n = (tile << 4) + (l & 15);
        const float* W = (mat == 0) ? Wq : (mat == 1) ? Wk : Wv;
        unsigned short hb, lb;
        bsplit1(W[k * 128 + n], hb, lb);
        WQKVh[idx] = hb; WQKVl[idx] = lb;
    } else {
        int r = idx - 49152;   // 0..4095, Wt: tiles=8, kstep=1
        int tile = r >> 9, l = (r >> 3) & 63, j = r & 7;
        int k = ((l >> 4) << 3) + j;
        int n = (tile << 4) + (l & 15);
        unsigned short hb, lb;
        bsplit1(Wt[k * 128 + n], hb, lb);
        WTh[r] = hb; WTl[r] = lb;
    }
}

// ---------------- QKV GEMM via split-bf16 MFMA: 64 rows x 128 cols x one matrix per block ----------------
__global__ __launch_bounds__(256) void k_qkv(const float* __restrict__ x,
                                             const unsigned short* __restrict__ WQKVh,
                                             const unsigned short* __restrict__ WQKVl,
                                             float* __restrict__ Q, float* __restrict__ K, float* __restrict__ V) {
    __shared__ __align__(16) short Xfrag[2][8192];   // 32 KB (hi, lo)
    int tid = threadIdx.x;
    int wave = tid >> 6, l = tid & 63;
    int mat = blockIdx.y;
    float* Out = (mat == 0) ? Q : (mat == 1) ? K : V;
    int row0 = blockIdx.x * 64;
    // ---- stage + split x tile into frag order: 16 (rowgroup, kstep) pairs ----
    #pragma unroll
    for (int it = 0; it < 4; ++it) {
        int pair = it * 4 + wave;
        int rg = pair >> 2, ks = pair & 3;
        int grow = row0 + rg * 16 + (l & 15);
        int kb = ks * 32 + ((l >> 4) << 3);
        float4 p0 = make_float4(0.f, 0.f, 0.f, 0.f), p1 = make_float4(0.f, 0.f, 0.f, 0.f);
        if (grow < NN) {
            p0 = *(const float4*)&x[(long long)grow * 128 + kb];
            p1 = *(const float4*)&x[(long long)grow * 128 + kb + 4];
        }
        float av[8] = {p0.x, p0.y, p0.z, p0.w, p1.x, p1.y, p1.z, p1.w};
        s16x8 vh, vl;
        #pragma unroll
        for (int j = 0; j < 8; ++j) {
            unsigned short hb, lb;
            bsplit1(av[j], hb, lb);
            vh[j] = (short)hb; vl[j] = (short)lb;
        }
        *(s16x8*)&Xfrag[0][(pair * 64 + l) * 8] = vh;
        *(s16x8*)&Xfrag[1][(pair * 64 + l) * 8] = vl;
    }
    __syncthreads();
    // ---- GEMM: wave owns row-group `wave`, all 8 col-tiles ----
    f32x4 acc[8];
    #pragma unroll
    for (int t = 0; t < 8; ++t) acc[t] = (f32x4){0.f, 0.f, 0.f, 0.f};
    #pragma unroll
    for (int ks = 0; ks < 4; ++ks) {
        s16x8 ah = *(const s16x8*)&Xfrag[0][((wave * 4 + ks) * 64 + l) * 8];
        s16x8 al = *(const s16x8*)&Xfrag[1][((wave * 4 + ks) * 64 + l) * 8];
        #pragma unroll
        for (int t = 0; t < 8; ++t) {
            int bidx = mat * 16384 + (t * 4 + ks) * 512 + l * 8;
            s16x8 bh = *(const s16x8*)&WQKVh[bidx];
            s16x8 bl = *(const s16x8*)&WQKVl[bidx];
            acc[t] = __builtin_amdgcn_mfma_f32_16x16x32_bf16(ah, bh, acc[t], 0, 0, 0);
            acc[t] = __builtin_amdgcn_mfma_f32_16x16x32_bf16(ah, bl, acc[t], 0, 0, 0);
            acc[t] = __builtin_amdgcn_mfma_f32_16x16x32_bf16(al, bh, acc[t], 0, 0, 0);
        }
    }
    int rb = row0 + wave * 16 + ((l >> 4) << 2);
    int cl = l & 15;
    #pragma unroll
    for (int t = 0; t < 8; ++t) {
        int col = t * 16 + cl;
        #pragma unroll
        for (int r = 0; r < 4; ++r) {
            int row = rb + r;
            if (row < NN) Out[(long long)row * 128 + col] = acc[t][r];
        }
    }
}

// ---------------- per-node hyperbolic scalars: m_i = t_i * x_i ----------------
__global__ __launch_bounds__(256) void k_tu(const float* __restrict__ x, const float* __restrict__ c_mag,
                                            float* __restrict__ T, float* __restrict__ U) {
    int wid = threadIdx.x >> 6;
    int lane = threadIdx.x & 63;
    int row = blockIdx.x * 4 + wid;
    if (row >= NN) return;
    float c = -fabsf(c_mag[0]);
    float abs_c = fmaxf(fabsf(c), 1e-15f);
    float sq = sqrtf(abs_c);
    float2 xv = *(const float2*)&x[(long long)row * 128 + lane * 2];
    float s = xv.x * xv.x + xv.y * xv.y;
    for (int m = 1; m < 64; m <<= 1) s += __shfl_xor(s, m);
    float nt = sqrtf(s);                       // true ||x||
    float n = fmaxf(nt, 1e-15f);               // clamped (reference _expmap)
    float arg = sq * n;
    float f = ((c < 0.0f) ? tanhf(arg) : tanf(arg)) / arg;
    float norm = fabsf(f) * nt;                // ||expmap(x)||, unclamped (reference _proj)
    float maxnorm = (1.0f - 1e-5f) / sq;
    float scale = (norm > maxnorm) ? (maxnorm / norm) : 1.0f;
    float t = f * scale;
    if (lane == 0) { T[row] = t; U[row] = t * t * s; }
}

// ---------------- per-edge logits in dst-sorted order (decay MLP + MFMA time-proj) ----------------
__global__ __launch_bounds__(256) void k_logits(const float* __restrict__ Q, const float* __restrict__ K,
                                                const float* __restrict__ x, const float* __restrict__ T,
                                                const float* __restrict__ U, const float* __restrict__ temb,
                                                const int* __restrict__ es, const int* __restrict__ src_s,
                                                const int* __restrict__ dst_s, const int* __restrict__ et_s,
                                                const float* __restrict__ etime,
                                                const float* __restrict__ rel_q, const float* __restrict__ rel_k,
                                                const unsigned short* __restrict__ WTh,
                                                const unsigned short* __restrict__ WTl,
                                                const float* __restrict__ bt,
                                                const float* __restrict__ Wd1, const float* __restrict__ bd1,
                                                const float* __restrict__ Wd2, const float* __restrict__ bd2,
                                                const float* __restrict__ dscale, const int* __restrict__ etmax,
                                                const float* __restrict__ hyp_beta,
                                                const float* __restrict__ logit_alpha,
                                                float* __restrict__ LOG) {
    __shared__ float Ts[32][32];    // temb rows of this block's 32 (sorted) edges
    __shared__ float TP[32][128];   // time projection per edge
    __shared__ float Dec[32][8];
    __shared__ float Wd1s[128];
    __shared__ float bd1s[64];
    __shared__ float Wd2s[512];
    int tid = threadIdx.x;
    int wave = tid >> 6, l = tid & 63;
    int pb0 = blockIdx.x * 32;      // sorted position base
    {
        int er = tid >> 3;          // 0..31
        int c = (tid & 7) * 4;      // 0..28
        int e = es[pb0 + er];
        *(float4*)&Ts[er][c] = *(const float4*)&temb[(long long)e * 32 + c];
        if (tid < 128) Wd1s[tid] = Wd1[tid];
        if (tid >= 128 && tid < 192) bd1s[tid - 128] = bd1[tid - 128];
        Wd2s[tid] = Wd2[tid];
        Wd2s[tid + 256] = Wd2[tid + 256];
    }
    __syncthreads();
    // ---- decay MLP: one thread per (edge, head) ----
    {
        int el = tid >> 3, hh = tid & 7;
        int pos = pb0 + el;
        float denom_t = fmaxf(1.0f, (float)(etmax[0]) + 1.0f);
        float in0 = etime[es[pos]];
        float in1 = (float)et_s[pos] / denom_t;
        float acc = bd2[hh];
        #pragma unroll
        for (int j = 0; j < 64; ++j) {
            float hid = fmaxf(in0 * Wd1s[j] + in1 * Wd1s[64 + j] + bd1s[j], 0.0f);
            acc += hid * Wd2s[j * 8 + hh];
        }
        Dec[el][hh] = expf(dscale[hh] * tanhf(acc));
    }
    // ---- TP = Ts @ Wt + bt via split-bf16 MFMA: wave -> (edge-group, 4 col-tiles) ----
    {
        int eg = wave >> 1;              // edge group 0/1 (16 edges)
        int tb = (wave & 1) * 4;         // tile base
        int kb = (l >> 4) << 3;
        float4 p0 = *(const float4*)&Ts[eg * 16 + (l & 15)][kb];
        float4 p1 = *(const float4*)&Ts[eg * 16 + (l & 15)][kb + 4];
        float av[8] = {p0.x, p0.y, p0.z, p0.w, p1.x, p1.y, p1.z, p1.w};
        s16x8 ah, al;
        #pragma unroll
        for (int j = 0; j < 8; ++j) {
            unsigned short hb, lb;
            bsplit1(av[j], hb, lb);
            ah[j] = (short)hb; al[j] = (short)lb;
        }
        int rbl = eg * 16 + ((l >> 4) << 2);
        #pragma unroll
        for (int t = 0; t < 4; ++t) {
            int tile = tb + t;
            int bidx = tile * 512 + l * 8;
            s16x8 bh = *(const s16x8*)&WTh[bidx];
            s16x8 bl = *(const s16x8*)&WTl[bidx];
            f32x4 acc = (f32x4){0.f, 0.f, 0.f, 0.f};
            acc = __builtin_amdgcn_mfma_f32_16x16x32_bf16(ah, bh, acc, 0, 0, 0);
            acc = __builtin_amdgcn_mfma_f32_16x16x32_bf16(ah, bl, acc, 0, 0, 0);
            acc = __builtin_amdgcn_mfma_f32_16x16x32_bf16(al, bh, acc, 0, 0, 0);
            int col = tile * 16 + (l & 15);
            float btv = bt[col];
            #pragma unroll
            for (int r = 0; r < 4; ++r)
                TP[rbl + r][col] = acc[r] + btv;
        }
    }
    __syncthreads();
    // ---- main: half-wave per sorted position ----
    int wid = wave;
    int lane = l;
    int half = lane >> 5;
    int ll = lane & 31;
    int d4 = ll * 4;
    int h = ll >> 2;
    float alpha = 1.0f / (1.0f + expf(-logit_alpha[h]));
    float beta = hyp_beta[h];
    #pragma unroll
    for (int i = 0; i < 4; ++i) {
        int elocal = wid * 8 + i * 2 + half;
        int pos = pb0 + elocal;
        int src = src_s[pos], dst = dst_s[pos];
        int et = et_s[pos];
        float4 q  = *(const float4*)&Q[(long long)dst * 128 + d4];
        float4 rq = *(const float4*)&rel_q[et * 128 + d4];
        float4 k  = *(const float4*)&K[(long long)src * 128 + d4];
        float4 rk = *(const float4*)&rel_k[et * 128 + d4];
        float4 tp = *(const float4*)&TP[elocal][d4];
        float4 xs = *(const float4*)&x[(long long)src * 128 + d4];
        float4 xd = *(const float4*)&x[(long long)dst * 128 + d4];
        float ep = (q.x + rq.x) * (k.x + rk.x + tp.x)
                 + (q.y + rq.y) * (k.y + rk.y + tp.y)
                 + (q.z + rq.z) * (k.z + rk.z + tp.z)
                 + (q.w + rq.w) * (k.w + rk.w + tp.w);
        float dp = xs.x * xd.x + xs.y * xd.y + xs.z * xd.z + xs.w * xd.w;
        ep += __shfl_xor(ep, 1); ep += __shfl_xor(ep, 2);
        dp += __shfl_xor(dp, 1); dp += __shfl_xor(dp, 2); dp += __shfl_xor(dp, 4);
        dp += __shfl_xor(dp, 8); dp += __shfl_xor(dp, 16);
        float man2 = fmaxf(U[src] + U[dst] - 2.0f * T[src] * T[dst] * dp, 0.0f);
        float man = sqrtf(man2);
        float dec = Dec[elocal][h];
        float eu = ep * 0.25f * dec;                 // / sqrt(16) then * decay
        float hyp = -beta * man * dec;
        float lg = alpha * eu + (1.0f - alpha) * hyp;
        if ((ll & 3) == 0) LOG[(long long)pos * 8 + h] = lg;   // sorted-position layout
    }
}

// ---------------- segmented softmax + V aggregation: one wave per dst node ----------------
__global__ __launch_bounds__(256) void k_agg2(const int* __restrict__ rp, const int* __restrict__ src_s,
                                              const int* __restrict__ et_s,
                                              const float* __restrict__ V, const float* __restrict__ rel_v,
                                              const float* __restrict__ LOG, float* __restrict__ AGG) {
    int wid = threadIdx.x >> 6, lane = threadIdx.x & 63;
    int node = blockIdx.x * 4 + wid;
    if (node >= NN) return;
    int beg = rp[node], end = rp[node + 1];
    int d = lane * 2;
    int h = lane >> 3;
    float mx = -3.0e38f;
    for (int i = beg; i < end; ++i) {
        mx = fmaxf(mx, LOG[(long long)i * 8 + h]);
    }
    float den = 0.0f;
    float ax = 0.0f, ay = 0.0f;
    for (int i = beg; i < end; ++i) {
        int src = src_s[i];
        int et = et_s[i];
        float ex = expf(LOG[(long long)i * 8 + h] - mx);
        den += ex;
        float2 v  = *(const float2*)&V[(long long)src * 128 + d];
        float2 rv = *(const float2*)&rel_v[et * 128 + d];
        ax += (v.x + rv.x) * ex;
        ay += (v.y + rv.y) * ex;
    }
    float sc = (end > beg) ? (1.0f / den) : 0.0f;
    *(float2*)&AGG[(long long)node * 128 + d] = make_float2(ax * sc, ay * sc);
}

// ---------------- split Wf1/Wf2 into bf16 hi/lo in MFMA fragment order ----------------
__global__ __launch_bounds__(256) void k_cvt(const float* __restrict__ Wf1, const float* __restrict__ Wf2,
                                             unsigned short* __restrict__ W1h, unsigned short* __restrict__ W1l,
                                             unsigned short* __restrict__ W2h, unsigned short* __restrict__ W2l) {
    int idx = blockIdx.x * 256 + threadIdx.x;   // 0..65535
    {   // Wf1: 128x512, tiles=32 (N), ksteps=4
        int tile = idx >> 11, rem = idx & 2047;
        int ks = rem >> 9, rem2 = rem & 511;
        int l = rem2 >> 3, j = rem2 & 7;
        int k = ks * 32 + ((l >> 4) << 3) + j;
        int n = (tile << 4) + (l & 15);
        unsigned short hb, lb;
        bsplit1(Wf1[k * 512 + n], hb, lb);
        W1h[idx] = hb; W1l[idx] = lb;
    }
    {   // Wf2: 512x128, tiles=8 (N), ksteps=16
        int tile = idx >> 13;
        int ks = (idx >> 9) & 15;
        int l = (idx >> 3) & 63, j = idx & 7;
        int k = ks * 32 + ((l >> 4) << 3) + j;
        int n = (tile << 4) + (l & 15);
        unsigned short hb, lb;
        bsplit1(Wf2[k * 128 + n], hb, lb);
        W2h[idx] = hb; W2l[idx] = lb;
    }
}

// ---------------- out = agg@Wo + bo; y1 = LN(x+out). AGG and Y1 alias in d_out ----------------
__global__ __launch_bounds__(256) void k_out_ln1(float* AGGY1,          // in: AGG (normalized), out: Y1
                                                 const float* __restrict__ Wo,
                                                 const float* __restrict__ bo, const float* __restrict__ x,
                                                 const float* __restrict__ g1, const float* __restrict__ be1) {
    __shared__ float Ast[32][40];
    __shared__ float Bs[32][136];
    int tid = threadIdx.x;
    int row0 = blockIdx.x * 32;
    int tx = tid & 31, ty = tid >> 5;
    float acc[4][4] = {};
    for (int k0 = 0; k0 < 128; k0 += 32) {
        {
            int r = tid >> 3, c = (tid & 7) * 4;     // r 0..31
            float4 v = *(const float4*)&AGGY1[(long long)(row0 + r) * 128 + k0 + c];
            Ast[c + 0][r] = v.x; Ast[c + 1][r] = v.y; Ast[c + 2][r] = v.z; Ast[c + 3][r] = v.w;
            int kk = tid >> 5, cc = (tid & 31) * 4;  // kk 0..7
            #pragma unroll
            for (int k2 = 0; k2 < 4; ++k2) {
                int kr = kk + k2 * 8;
                *(float4*)&Bs[kr][cc] = *(const float4*)&Wo[(k0 + kr) * 128 + cc];
            }
        }
        __syncthreads();
        #pragma unroll
        for (int kk = 0; kk < 32; ++kk) {
            float4 a = *(const float4*)&Ast[kk][ty * 4];
            float4 b = *(const float4*)&Bs[kk][tx * 4];
            float av[4] = {a.x, a.y, a.z, a.w};
            float bv[4] = {b.x, b.y, b.z, b.w};
            #pragma unroll
            for (int i = 0; i < 4; ++i)
                #pragma unroll
                for (int j = 0; j < 4; ++j) acc[i][j] += av[i] * bv[j];
        }
        __syncthreads();
    }
    float4 bov = *(const float4*)&bo[tx * 4];
    float4 g = *(const float4*)&g1[tx * 4];
    float4 bb = *(const float4*)&be1[tx * 4];
    #pragma unroll
    for (int i = 0; i < 4; ++i) {
        int row = row0 + ty * 4 + i;
        float4 xv = *(const float4*)&x[(long long)row * 128 + tx * 4];
        float v0 = xv.x + acc[i][0] + bov.x;
        float v1 = xv.y + acc[i][1] + bov.y;
        float v2 = xv.z + acc[i][2] + bov.z;
        float v3 = xv.w + acc[i][3] + bov.w;
        float sum = v0 + v1 + v2 + v3;
        for (int m = 1; m < 32; m <<= 1) sum += __shfl_xor(sum, m);
        float mu = sum * (1.0f / 128.0f);
        float d0 = v0 - mu, d1 = v1 - mu, d2 = v2 - mu, d3 = v3 - mu;
        float ss = d0 * d0 + d1 * d1 + d2 * d2 + d3 * d3;
        for (int m = 1; m < 32; m <<= 1) ss += __shfl_xor(ss, m);
        float var = ss * (1.0f / 128.0f);
        float rs = 1.0f / sqrtf(var + 1e-5f);
        float4 o;
        o.x = d0 * rs * g.x + bb.x;
        o.y = d1 * rs * g.y + bb.y;
        o.z = d2 * rs * g.z + bb.z;
        o.w = d3 * rs * g.w + bb.w;
        *(float4*)&AGGY1[(long long)row * 128 + tx * 4] = o;
    }
}

// ---------------- FFN (128->512->128) + LN2 via split-bf16 MFMA ----------------
__global__ __launch_bounds__(256) void k_ffn_ln2(float* IO,
        const unsigned short* __restrict__ W1h, const unsigned short* __restrict__ W1l,
        const unsigned short* __restrict__ W2h, const unsigned short* __restrict__ W2l,
        const float* __restrict__ bf1, const float* __restrict__ bf2,
        const float* __restrict__ g2, const float* __restrict__ be2) {
    __shared__ __align__(16) float Ys[16][132];      // 8448 B
    __shared__ __align__(16) short Yfrag[2][2048];   // 8192 B (hi,lo) — Os overlays later
    __shared__ __align__(16) float Hs[16][516];      // 33024 B
    __shared__ __align__(16) short Hfrag[2][4096];   // 16384 B (one K-half at a time)
    int tid = threadIdx.x;
    int row0 = blockIdx.x * 16;
    int wave = tid >> 6, l = tid & 63;
    // ---- stage Y tile ----
    {
        int r = tid >> 4, c = (tid & 15) * 8;
        float4 a = *(const float4*)&IO[(long long)(row0 + r) * 128 + c];
        float4 b = *(const float4*)&IO[(long long)(row0 + r) * 128 + c + 4];
        *(float4*)&Ys[r][c] = a;
        *(float4*)&Ys[r][c + 4] = b;
    }
    __syncthreads();
    // ---- Y frag pass ----
    {
        int ks = tid >> 6, ll = tid & 63;
        int rr = ll & 15, kb = ks * 32 + ((ll >> 4) << 3);
        float4 p0 = *(const float4*)&Ys[rr][kb];
        float4 p1 = *(const float4*)&Ys[rr][kb + 4];
        float av[8] = {p0.x, p0.y, p0.z, p0.w, p1.x, p1.y, p1.z, p1.w};
        s16x8 vh, vl;
        #pragma unroll
        for (int j = 0; j < 8; ++j) {
            unsigned short hb, lb;
            bsplit1(av[j], hb, lb);
            vh[j] = (short)hb; vl[j] = (short)lb;
        }
        *(s16x8*)&Yfrag[0][(ks * 64 + ll) * 8] = vh;
        *(s16x8*)&Yfrag[1][(ks * 64 + ll) * 8] = vl;
    }
    __syncthreads();
    // ---- GEMM1: Hs = gelu(Y @ Wf1 + bf1) ----
    {
        f32x4 zero = {0.0f, 0.0f, 0.0f, 0.0f};
        f32x4 acc[8];
        #pragma unroll
        for (int t = 0; t < 8; ++t) acc[t] = zero;
        #pragma unroll
        for (int ks = 0; ks < 4; ++ks) {
            s16x8 ah = *(const s16x8*)&Yfrag[0][(ks * 64 + l) * 8];
            s16x8 al = *(const s16x8*)&Yfrag[1][(ks * 64 + l) * 8];
            #pragma unroll
            for (int t = 0; t < 8; ++t) {
                int idx = (((wave * 8 + t) * 4 + ks) * 64 + l) * 8;
                s16x8 bh = *(const s16x8*)&W1h[idx];
                s16x8 bl = *(const s16x8*)&W1l[idx];
                acc[t] = __builtin_amdgcn_mfma_f32_16x16x32_bf16(ah, bh, acc[t], 0, 0, 0);
                acc[t] = __builtin_amdgcn_mfma_f32_16x16x32_bf16(ah, bl, acc[t], 0, 0, 0);
                acc[t] = __builtin_amdgcn_mfma_f32_16x16x32_bf16(al, bh, acc[t], 0, 0, 0);
            }
        }
        int rb = (l >> 4) * 4, cl = l & 15;
        #pragma unroll
        for (int t = 0; t < 8; ++t) {
            int col = (wave * 8 + t) * 16 + cl;
            float bb = bf1[col];
            #pragma unroll
            for (int r = 0; r < 4; ++r)
                Hs[rb + r][col] = gelu_exact(acc[t][r] + bb);
        }
    }
    __syncthreads();
    // ---- GEMM2: Os = Hs @ Wf2, two K-halves ----
    f32x4 acc2[2];
    acc2[0] = (f32x4){0.0f, 0.0f, 0.0f, 0.0f};
    acc2[1] = (f32x4){0.0f, 0.0f, 0.0f, 0.0f};
    #pragma unroll
    for (int halfk = 0; halfk < 2; ++halfk) {
        {
            int ksh = tid >> 5, lg = tid & 31;
            #pragma unroll
            for (int q = 0; q < 2; ++q) {
                int l2 = lg * 2 + q;
                int rr = l2 & 15, kb = (halfk * 8 + ksh) * 32 + ((l2 >> 4) << 3);
                float4 p0 = *(const float4*)&Hs[rr][kb];
                float4 p1 = *(const float4*)&Hs[rr][kb + 4];
                float av[8] = {p0.x, p0.y, p0.z, p0.w, p1.x, p1.y, p1.z, p1.w};
                s16x8 vh, vl;
                #pragma unroll
                for (int j = 0; j < 8; ++j) {
                    unsigned short hb, lb;
                    bsplit1(av[j], hb, lb);
                    vh[j] = (short)hb; vl[j] = (short)lb;
                }
                *(s16x8*)&Hfrag[0][(ksh * 64 + l2) * 8] = vh;
                *(s16x8*)&Hfrag[1][(ksh * 64 + l2) * 8] = vl;
            }
        }
        __syncthreads();
        #pragma unroll
        for (int ksl = 0; ksl < 8; ++ksl) {
            int ks = halfk * 8 + ksl;
            s16x8 ah = *(const s16x8*)&Hfrag[0][(ksl * 64 + l) * 8];
            s16x8 al = *(const s16x8*)&Hfrag[1][(ksl * 64 + l) * 8];
            #pragma unroll
            for (int t = 0; t < 2; ++t) {
                int idx = (((wave * 2 + t) * 16 + ks) * 64 + l) * 8;
                s16x8 bh = *(const s16x8*)&W2h[idx];
                s16x8 bl = *(const s16x8*)&W2l[idx];
                acc2[t] = __builtin_amdgcn_mfma_f32_16x16x32_bf16(ah, bh, acc2[t], 0, 0, 0);
                acc2[t] = __builtin_amdgcn_mfma_f32_16x16x32_bf16(ah, bl, acc2[t], 0, 0, 0);
                acc2[t] = __builtin_amdgcn_mfma_f32_16x16x32_bf16(al, bh, acc2[t], 0, 0, 0);
            }
        }
        __syncthreads();
    }
    // ---- write GEMM2 result (Os overlays Yfrag) ----
    float* Os = (float*)&Yfrag[0][0];   // [16][128]
    {
        int rb = (l >> 4) * 4, cl = l & 15;
        #pragma unroll
        for (int t = 0; t < 2; ++t) {
            int col = (wave * 2 + t) * 16 + cl;
            #pragma unroll
            for (int r = 0; r < 4; ++r)
                Os[(rb + r) * 128 + col] = acc2[t][r];
        }
    }
    __syncthreads();
    // ---- LN epilogue: out = LN(Ys + Os + bf2) ----
    {
        int cg = (tid & 31) * 4;
        int rp_ = (tid >> 5) * 2;
        float4 b2 = *(const float4*)&bf2[cg];
        float4 g = *(const float4*)&g2[cg];
        float4 bb = *(const float4*)&be2[cg];
        #pragma unroll
        for (int r = 0; r < 2; ++r) {
            int rr = rp_ + r;
            int row = row0 + rr;
            float v0 = Ys[rr][cg + 0] + Os[rr * 128 + cg + 0] + b2.x;
            float v1 = Ys[rr][cg + 1] + Os[rr * 128 + cg + 1] + b2.y;
            float v2 = Ys[rr][cg + 2] + Os[rr * 128 + cg + 2] + b2.z;
            float v3 = Ys[rr][cg + 3] + Os[rr * 128 + cg + 3] + b2.w;
            float sum = v0 + v1 + v2 + v3;
            for (int m = 1; m < 32; m <<= 1) sum += __shfl_xor(sum, m);
            float mu = sum * (1.0f / 128.0f);
            float d0 = v0 - mu, d1 = v1 - mu, d2 = v2 - mu, d3 = v3 - mu;
            float ss = d0 * d0 + d1 * d1 + d2 * d2 + d3 * d3;
            for (int m = 1; m < 32; m <<= 1) ss += __shfl_xor(ss, m);
            float var = ss * (1.0f / 128.0f);
            float rs = 1.0f / sqrtf(var + 1e-5f);
            float4 o;
            o.x = d0 * rs * g.x + bb.x;
            o.y = d1 * rs * g.y + bb.y;
            o.z = d2 * rs * g.z + bb.z;
            o.w = d3 * rs * g.w + bb.w;
            *(float4*)&IO[(long long)row * 128 + cg] = o;
        }
    }
}

extern "C" void kernel_launch(void* const* d_in, const int* in_sizes, int n_in,
                              void* d_out, int out_size, void* d_ws, size_t ws_size,
                              hipStream_t stream) {
    const float* x       = (const float*)d_in[0];
    const int*   eidx    = (const int*)d_in[1];
    const float* temb    = (const float*)d_in[2];
    const int*   etype   = (const int*)d_in[3];
    const float* etime   = (const float*)d_in[4];
    const float* Wq      = (const float*)d_in[5];
    const float* Wk      = (const float*)d_in[6];
    const float* Wv      = (const float*)d_in[7];
    const float* rel_q   = (const float*)d_in[8];
    const float* rel_k   = (const float*)d_in[9];
    const float* rel_v   = (const float*)d_in[10];
    const float* Wt      = (const float*)d_in[11];
    const float* bt      = (const float*)d_in[12];
    const float* Wd1     = (const float*)d_in[13];
    const float* bd1     = (const float*)d_in[14];
    const float* Wd2     = (const float*)d_in[15];
    const float* bd2     = (const float*)d_in[16];
    const float* dscale  = (const float*)d_in[17];
    const float* c_mag   = (const float*)d_in[18];
    const float* hbeta   = (const float*)d_in[19];
    const float* lalpha  = (const float*)d_in[20];
    const float* Wo      = (const float*)d_in[21];
    const float* bo      = (const float*)d_in[22];
    const float* g1      = (const float*)d_in[23];
    const float* be1     = (const float*)d_in[24];
    const float* g2      = (const float*)d_in[25];
    const float* be2     = (const float*)d_in[26];
    const float* Wf1     = (const float*)d_in[27];
    const float* bf1     = (const float*)d_in[28];
    const float* Wf2     = (const float*)d_in[29];
    const float* bf2     = (const float*)d_in[30];

    float* ws = (float*)d_ws;
    float*    Q    = ws + OFF_Q;
    float*    K    = ws + OFF_K;
    float*    V    = ws + OFF_V;
    float*    LOG  = ws + OFF_LOG;
    float*    T    = ws + OFF_T;
    float*    U    = ws + OFF_U;
    int*      ETM  = (int*)(ws + OFF_ETM);
    int*      CNT  = (int*)(ws + OFF_CNT);
    int*      CUR  = (int*)(ws + OFF_CUR);
    int*      RP   = (int*)(ws + OFF_RP);
    int*      ES   = (int*)(ws + OFF_ES);
    int*      SRCS = (int*)(ws + OFF_SRCS);
    int*      DSTS = (int*)(ws + OFF_DSTS);
    int*      ETS  = (int*)(ws + OFF_ETS);
    int*      BS   = (int*)(ws + OFF_BS);
    unsigned short* WQKVh = (unsigned short*)(ws + OFF_WQKVF);
    unsigned short* WQKVl = WQKVh + 49152;
    unsigned short* WTh   = (unsigned short*)(ws + OFF_WTF);
    unsigned short* WTl   = WTh + 4096;
    float*    AGG  = (float*)d_out;   // normalized aggregation, then Y1/out in-place
    float*    IO   = (float*)d_out;
    // split-bf16 FFN weight arrays overlay the V region (V dead after k_agg2)
    unsigned short* W1h = (unsigned short*)(ws + OFF_V);
    unsigned short* W1l = W1h + 65536;
    unsigned short* W2h = W1l + 65536;
    unsigned short* W2l = W2h + 65536;

    k_zero<<<512, 256, 0, stream>>>(CNT, CUR, ETM);
    k_cvt_pre<<<208, 256, 0, stream>>>(Wq, Wk, Wv, Wt, WQKVh, WQKVl, WTh, WTl);
    k_etmax<<<512, 256, 0, stream>>>(etype, ETM);
    k_hist<<<(EE + 255) / 256, 256, 0, stream>>>(eidx, CNT);
    k_scan1<<<NB, 256, 0, stream>>>(CNT, BS);
    k_scan2<<<1, 512, 0, stream>>>(BS);
    k_scan3<<<NB, 256, 0, stream>>>(CNT, BS, RP);
    k_scatter<<<(EE + 255) / 256, 256, 0, stream>>>(eidx, etype, RP, CUR, ES, SRCS, DSTS, ETS);
    k_qkv<<<dim3(1563, 3), 256, 0, stream>>>(x, WQKVh, WQKVl, Q, K, V);
    k_tu<<<25000, 256, 0, stream>>>(x, c_mag, T, U);
    k_logits<<<EE / 32, 256, 0, stream>>>(Q, K, x, T, U, temb, ES, SRCS, DSTS, ETS, etime,
                                          rel_q, rel_k, WTh, WTl, bt, Wd1, bd1, Wd2, bd2,
                                          dscale, ETM, hbeta, lalpha, LOG);
    k_agg2<<<25000, 256, 0, stream>>>(RP, SRCS, ETS, V, rel_v, LOG, AGG);
    k_cvt<<<256, 256, 0, stream>>>(Wf1, Wf2, W1h, W1l, W2h, W2l);   // after k_agg2 (V dead)
    k_out_ln1<<<NN / 32, 256, 0, stream>>>(AGG, Wo, bo, x, g1, be1);
    k_ffn_ln2<<<NN / 16, 256, 0, stream>>>(IO, W1h, W1l, W2h, W2l, bf1, bf2, g2, be2);
}